// Round 6
// baseline (6077.898 us; speedup 1.0000x reference)
//
#include <hip/hip_runtime.h>
#include <hip/hip_bf16.h>

// Problem constants (fixed by the reference)
#define E_EDGES 200000
#define T_TRIP  2000000
#define N_NODES 20000
#define H_DIM   128
#define INT_DIM 64
#define BAS     8
#define OUT_EMB 256
#define NRAD    6
#define SBF_D   42
#define NB      4

// epilogue flags
#define F_BIAS 1
#define F_SILU 2
#define F_RES  4
#define F_GATE 8

typedef __attribute__((ext_vector_type(8))) __bf16 bf16x8;
typedef __attribute__((ext_vector_type(4))) float f32x4;
typedef unsigned short u16;

__device__ __forceinline__ float silu_f(float v) { return v / (1.0f + __expf(-v)); }

__device__ __forceinline__ u16 f2bf(float f) {
    unsigned int u = __float_as_uint(f);
    u += 0x7FFF + ((u >> 16) & 1);   // RNE
    return (u16)(u >> 16);
}
__device__ __forceinline__ float bf2f(u16 h) {
    return __uint_as_float(((unsigned int)h) << 16);
}

__device__ __forceinline__ void st_split(char* H, char* L, int row, int col, int stride, float v) {
    u16 hh = f2bf(v);
    u16 ll = f2bf(v - bf2f(hh));
    int off = (row * stride + col * 2) ^ ((row & 7) << 4);
    *reinterpret_cast<u16*>(H + off) = hh;
    *reinterpret_cast<u16*>(L + off) = ll;
}
__device__ __forceinline__ float ld_split(const char* H, const char* L, int row, int col, int stride) {
    int off = (row * stride + col * 2) ^ ((row & 7) << 4);
    return bf2f(*reinterpret_cast<const u16*>(H + off))
         + bf2f(*reinterpret_cast<const u16*>(L + off));
}

// 8-wave GEMM: LDS A [64][128] split (stride 256B); wave tile 16 rows x 64 cols.
// rowbase = wm*16; acc[4] over n. 3-term split MFMA.
__device__ __forceinline__ void mm128_r16(
    const char* AH, const char* AL, const u16* Bh, const u16* Bl,
    int rowbase, int wn, int l15, int khalf, f32x4 acc[4])
{
    const int row = rowbase + l15;
    #pragma unroll
    for (int k0 = 0; k0 < 128; k0 += 32) {
        bf16x8 bh[4], bl[4];
        #pragma unroll
        for (int n = 0; n < 4; ++n) {
            size_t bo = (size_t)(wn * 64 + n * 16 + l15) * 128 + k0 + khalf;
            bh[n] = *reinterpret_cast<const bf16x8*>(Bh + bo);
            bl[n] = *reinterpret_cast<const bf16x8*>(Bl + bo);
        }
        int off = (row * 256 + (k0 + khalf) * 2) ^ ((row & 7) << 4);
        bf16x8 ah = *reinterpret_cast<const bf16x8*>(AH + off);
        bf16x8 al = *reinterpret_cast<const bf16x8*>(AL + off);
        #pragma unroll
        for (int n = 0; n < 4; ++n) {
            acc[n] = __builtin_amdgcn_mfma_f32_16x16x32_bf16(ah, bh[n], acc[n], 0, 0, 0);
            acc[n] = __builtin_amdgcn_mfma_f32_16x16x32_bf16(al, bh[n], acc[n], 0, 0, 0);
            acc[n] = __builtin_amdgcn_mfma_f32_16x16x32_bf16(ah, bl[n], acc[n], 0, 0, 0);
        }
    }
}

// K=64 variant: LDS A [64][64] split (stride 128B).
__device__ __forceinline__ void mm64_r16(
    const char* AH, const char* AL, const u16* Bh, const u16* Bl,
    int rowbase, int wn, int l15, int khalf, f32x4 acc[4])
{
    const int row = rowbase + l15;
    #pragma unroll
    for (int k0 = 0; k0 < 64; k0 += 32) {
        bf16x8 bh[4], bl[4];
        #pragma unroll
        for (int n = 0; n < 4; ++n) {
            size_t bo = (size_t)(wn * 64 + n * 16 + l15) * 64 + k0 + khalf;
            bh[n] = *reinterpret_cast<const bf16x8*>(Bh + bo);
            bl[n] = *reinterpret_cast<const bf16x8*>(Bl + bo);
        }
        int off = (row * 128 + (k0 + khalf) * 2) ^ ((row & 7) << 4);
        bf16x8 ah = *reinterpret_cast<const bf16x8*>(AH + off);
        bf16x8 al = *reinterpret_cast<const bf16x8*>(AL + off);
        #pragma unroll
        for (int n = 0; n < 4; ++n) {
            acc[n] = __builtin_amdgcn_mfma_f32_16x16x32_bf16(ah, bh[n], acc[n], 0, 0, 0);
            acc[n] = __builtin_amdgcn_mfma_f32_16x16x32_bf16(al, bh[n], acc[n], 0, 0, 0);
            acc[n] = __builtin_amdgcn_mfma_f32_16x16x32_bf16(ah, bl[n], acc[n], 0, 0, 0);
        }
    }
}

// ---------------------------------------------------------------------------
// Weight prep: src [cnt][K][N] f32 row-major -> hi/lo [cnt][N][K] split-bf16
// ---------------------------------------------------------------------------
__global__ __launch_bounds__(256) void wprep(
    const float* __restrict__ src, u16* __restrict__ hi,
    u16* __restrict__ lo, int K, int N)
{
    int e = blockIdx.x * 256 + threadIdx.x;
    int total = K * N;
    if (e >= total) return;
    size_t base = (size_t)blockIdx.y * total;
    float a = src[base + e];
    int k = e / N, n = e - k * N;
    u16 h = f2bf(a);
    u16 l = f2bf(a - bf2f(h));
    hi[base + (size_t)n * K + k] = h;
    lo[base + (size_t)n * K + k] = l;
}

// ---------------------------------------------------------------------------
// Generic split-bf16 MFMA GEMM (used by output blocks)
// ---------------------------------------------------------------------------
__global__ __launch_bounds__(256) void mfma_gemm(
    const float* __restrict__ A,
    const u16* __restrict__ Bhi, const u16* __restrict__ Blo,
    const float* __restrict__ bias, const float* __restrict__ res,
    const float* __restrict__ rbf8v, const float* __restrict__ Wr2,
    float* __restrict__ C, int M, int N, int K, int flags)
{
    __shared__ u16 AsH[128 * 32];
    __shared__ u16 AsL[128 * 32];

    const int tid  = threadIdx.x;
    const int lane = tid & 63;
    const int w    = tid >> 6;
    const int wm   = w >> 1, wn = w & 1;
    const int bm   = blockIdx.y * 128;
    const int bn   = blockIdx.x * 64;
    const int l15  = lane & 15;
    const int khalf = (lane >> 4) * 8;

    const int sr = tid >> 1;
    const int sc = (tid & 1) * 16;
    int grow = bm + sr; if (grow >= M) grow = M - 1;
    const float* gA = &A[(size_t)grow * K + sc];

    int bcol[2];
    #pragma unroll
    for (int n = 0; n < 2; ++n) bcol[n] = bn + wn * 32 + n * 16 + l15;

    f32x4 acc[4][2] = {};

    for (int k0 = 0; k0 < K; k0 += 32) {
        __syncthreads();
        {
            const float* p = gA + k0;
            float4 f0 = *reinterpret_cast<const float4*>(p);
            float4 f1 = *reinterpret_cast<const float4*>(p + 4);
            float4 f2 = *reinterpret_cast<const float4*>(p + 8);
            float4 f3 = *reinterpret_cast<const float4*>(p + 12);
            float vv[16] = {f0.x,f0.y,f0.z,f0.w, f1.x,f1.y,f1.z,f1.w,
                            f2.x,f2.y,f2.z,f2.w, f3.x,f3.y,f3.z,f3.w};
            const int swz = (sr & 7) << 4;
            #pragma unroll
            for (int q = 0; q < 4; ++q) {
                u16 h[4], l[4];
                #pragma unroll
                for (int j = 0; j < 4; ++j) {
                    float a = vv[q * 4 + j];
                    h[j] = f2bf(a);
                    l[j] = f2bf(a - bf2f(h[j]));
                }
                int off = (sr * 64 + (sc / 4 + q) * 8) ^ swz;
                *reinterpret_cast<ushort4*>((char*)AsH + off) = make_ushort4(h[0], h[1], h[2], h[3]);
                *reinterpret_cast<ushort4*>((char*)AsL + off) = make_ushort4(l[0], l[1], l[2], l[3]);
            }
        }
        __syncthreads();

        bf16x8 bh[2], bl[2];
        #pragma unroll
        for (int n = 0; n < 2; ++n) {
            size_t bo = (size_t)bcol[n] * K + k0 + khalf;
            bh[n] = *reinterpret_cast<const bf16x8*>(Bhi + bo);
            bl[n] = *reinterpret_cast<const bf16x8*>(Blo + bo);
        }

        #pragma unroll
        for (int m = 0; m < 4; ++m) {
            int ri  = wm * 64 + m * 16 + l15;
            int off = (ri * 64 + khalf * 2) ^ ((ri & 7) << 4);
            bf16x8 ah = *reinterpret_cast<const bf16x8*>((const char*)AsH + off);
            bf16x8 al = *reinterpret_cast<const bf16x8*>((const char*)AsL + off);
            #pragma unroll
            for (int n = 0; n < 2; ++n) {
                acc[m][n] = __builtin_amdgcn_mfma_f32_16x16x32_bf16(ah, bh[n], acc[m][n], 0, 0, 0);
                acc[m][n] = __builtin_amdgcn_mfma_f32_16x16x32_bf16(al, bh[n], acc[m][n], 0, 0, 0);
                acc[m][n] = __builtin_amdgcn_mfma_f32_16x16x32_bf16(ah, bl[n], acc[m][n], 0, 0, 0);
            }
        }
    }

    const int r4 = (lane >> 4) * 4;
    #pragma unroll
    for (int m = 0; m < 4; ++m) {
        #pragma unroll
        for (int r = 0; r < 4; ++r) {
            int row = bm + wm * 64 + m * 16 + r4 + r;
            if (row >= M) continue;
            #pragma unroll
            for (int n = 0; n < 2; ++n) {
                int col = bn + wn * 32 + n * 16 + l15;
                float v = acc[m][n][r];
                if (flags & F_BIAS) v += bias[col];
                if (flags & F_SILU) v = silu_f(v);
                if (flags & F_GATE) {
                    float g = 0.f;
                    #pragma unroll
                    for (int j = 0; j < 8; ++j)
                        g = fmaf(rbf8v[(size_t)row * 8 + j], Wr2[j * N + col], g);
                    v *= g;
                }
                if (flags & F_RES) v += res[(size_t)row * N + col];
                C[(size_t)row * N + col] = v;
            }
        }
    }
}

// ---------------------------------------------------------------------------
// pre_fuse (512 threads, 8 waves, wave tile 16x64):
//   E1 = silu(X@Wji + bji)
//   I  = silu(X@Wkj + bkj) * (R8 @ Wr2)   (LDS)
//   C1 = silu(I@Wdn)                       (N=64)
// ---------------------------------------------------------------------------
__global__ __launch_bounds__(512, 4) void pre_fuse(
    const float* __restrict__ X, const float* __restrict__ R8,
    const u16* __restrict__ Wjih, const u16* __restrict__ Wjil, const float* __restrict__ bji,
    const u16* __restrict__ Wkjh, const u16* __restrict__ Wkjl, const float* __restrict__ bkj,
    const float* __restrict__ Wr2,
    const u16* __restrict__ Wdnh, const u16* __restrict__ Wdnl,
    float* __restrict__ E1, float* __restrict__ C1)
{
    __shared__ u16 XH[64 * 128], XL[64 * 128];
    __shared__ u16 IH[64 * 128], IL[64 * 128];

    const int tid  = threadIdx.x;
    const int lane = tid & 63;
    const int w    = tid >> 6;          // 0..7
    const int wm   = w >> 1, wn = w & 1;
    const int bm   = blockIdx.x * 64;
    const int l15  = lane & 15;
    const int khalf = (lane >> 4) * 8;
    const int r4   = (lane >> 4) * 4;
    const int rowbase = wm * 16;

    // stage X [64][128]: 512 threads x 16 floats
    {
        int r  = tid >> 3;
        int c0 = (tid & 7) * 16;
        const float* p = &X[(size_t)(bm + r) * H_DIM + c0];
        const int swz = (r & 7) << 4;
        #pragma unroll
        for (int q = 0; q < 4; ++q) {
            float4 f = *reinterpret_cast<const float4*>(p + q * 4);
            float vv[4] = {f.x, f.y, f.z, f.w};
            u16 h[4], l[4];
            #pragma unroll
            for (int j = 0; j < 4; ++j) {
                h[j] = f2bf(vv[j]);
                l[j] = f2bf(vv[j] - bf2f(h[j]));
            }
            int off = (r * 256 + c0 * 2 + q * 8) ^ swz;
            *reinterpret_cast<ushort4*>((char*)XH + off) = make_ushort4(h[0], h[1], h[2], h[3]);
            *reinterpret_cast<ushort4*>((char*)XL + off) = make_ushort4(l[0], l[1], l[2], l[3]);
        }
    }
    __syncthreads();

    // JI -> E1
    {
        f32x4 acc[4] = {};
        mm128_r16((char*)XH, (char*)XL, Wjih, Wjil, rowbase, wn, l15, khalf, acc);
        #pragma unroll
        for (int n = 0; n < 4; ++n) {
            int col = wn * 64 + n * 16 + l15;
            float bv = bji[col];
            #pragma unroll
            for (int r = 0; r < 4; ++r) {
                int row = rowbase + r4 + r;
                E1[(size_t)(bm + row) * H_DIM + col] = silu_f(acc[n][r] + bv);
            }
        }
    }
    // KJ * gate -> I (LDS)
    {
        f32x4 acc[4] = {};
        mm128_r16((char*)XH, (char*)XL, Wkjh, Wkjl, rowbase, wn, l15, khalf, acc);
        #pragma unroll
        for (int n = 0; n < 4; ++n) {
            int col = wn * 64 + n * 16 + l15;
            float bv = bkj[col];
            #pragma unroll
            for (int r = 0; r < 4; ++r) {
                int row = rowbase + r4 + r;
                float v = silu_f(acc[n][r] + bv);
                float g = 0.f;
                #pragma unroll
                for (int j = 0; j < 8; ++j)
                    g = fmaf(R8[(size_t)(bm + row) * 8 + j], Wr2[j * H_DIM + col], g);
                st_split((char*)IH, (char*)IL, row, col, 256, v * g);
            }
        }
    }
    __syncthreads();

    // DOWN (N=64) -> C1
    {
        const int row = rowbase + l15;
        f32x4 acc[2] = {};
        #pragma unroll
        for (int k0 = 0; k0 < 128; k0 += 32) {
            bf16x8 bh[2], bl[2];
            #pragma unroll
            for (int n = 0; n < 2; ++n) {
                size_t bo = (size_t)(wn * 32 + n * 16 + l15) * 128 + k0 + khalf;
                bh[n] = *reinterpret_cast<const bf16x8*>(Wdnh + bo);
                bl[n] = *reinterpret_cast<const bf16x8*>(Wdnl + bo);
            }
            int off = (row * 256 + (k0 + khalf) * 2) ^ ((row & 7) << 4);
            bf16x8 ah = *reinterpret_cast<const bf16x8*>((const char*)IH + off);
            bf16x8 al = *reinterpret_cast<const bf16x8*>((const char*)IL + off);
            #pragma unroll
            for (int n = 0; n < 2; ++n) {
                acc[n] = __builtin_amdgcn_mfma_f32_16x16x32_bf16(ah, bh[n], acc[n], 0, 0, 0);
                acc[n] = __builtin_amdgcn_mfma_f32_16x16x32_bf16(al, bh[n], acc[n], 0, 0, 0);
                acc[n] = __builtin_amdgcn_mfma_f32_16x16x32_bf16(ah, bl[n], acc[n], 0, 0, 0);
            }
        }
        #pragma unroll
        for (int n = 0; n < 2; ++n) {
            int col = wn * 32 + n * 16 + l15;
            #pragma unroll
            for (int r = 0; r < 4; ++r) {
                int rr = rowbase + r4 + r;
                C1[(size_t)(bm + rr) * INT_DIM + col] = silu_f(acc[n][r]);
            }
        }
    }
}

// ---------------------------------------------------------------------------
// post_chain (512 threads, 8 waves, wave tile 16x64)
// ---------------------------------------------------------------------------
struct ChainP {
    const u16 *uph, *upl;
    const u16 *b0h, *b0l, *b1h, *b1l;
    const u16 *lnh, *lnl;
    const u16 *a0h, *a0l, *a1h, *a1l, *a2h, *a2l, *a3h, *a3l;
    const float *bb0, *bb1, *blin, *ba0, *ba1, *ba2, *ba3;
};

__global__ __launch_bounds__(512, 4) void post_chain(
    const float* __restrict__ AGG, const float* __restrict__ E1,
    const float* __restrict__ X, ChainP p, float* __restrict__ OUT)
{
    __shared__ u16 GH[64 * 64],  GL[64 * 64];
    __shared__ u16 P0H[64 * 128], P0L[64 * 128];
    __shared__ u16 P1H[64 * 128], P1L[64 * 128];

    const int tid  = threadIdx.x;
    const int lane = tid & 63;
    const int w    = tid >> 6;          // 0..7
    const int wm   = w >> 1, wn = w & 1;
    const int bm   = blockIdx.x * 64;
    const int l15  = lane & 15;
    const int khalf = (lane >> 4) * 8;
    const int r4   = (lane >> 4) * 4;
    const int rowbase = wm * 16;

    // stage AGG [64][64]: 512 threads x 8 floats
    {
        int r  = tid >> 3;
        int c0 = (tid & 7) * 8;
        const float* pg = &AGG[(size_t)(bm + r) * INT_DIM + c0];
        const int swz = (r & 7) << 4;
        #pragma unroll
        for (int q = 0; q < 2; ++q) {
            float4 f = *reinterpret_cast<const float4*>(pg + q * 4);
            float vv[4] = {f.x, f.y, f.z, f.w};
            u16 h[4], l[4];
            #pragma unroll
            for (int j = 0; j < 4; ++j) {
                h[j] = f2bf(vv[j]);
                l[j] = f2bf(vv[j] - bf2f(h[j]));
            }
            int off = (r * 128 + c0 * 2 + q * 8) ^ swz;
            *reinterpret_cast<ushort4*>((char*)GH + off) = make_ushort4(h[0], h[1], h[2], h[3]);
            *reinterpret_cast<ushort4*>((char*)GL + off) = make_ushort4(l[0], l[1], l[2], l[3]);
        }
    }
    __syncthreads();

    f32x4 acc[4];

    // S1: UP (K=64), h0 = E1 + silu(acc) -> P0
    #pragma unroll
    for (int n = 0; n < 4; ++n) acc[n] = f32x4{0.f, 0.f, 0.f, 0.f};
    mm64_r16((char*)GH, (char*)GL, p.uph, p.upl, rowbase, wn, l15, khalf, acc);
    #pragma unroll
    for (int n = 0; n < 4; ++n) {
        int col = wn * 64 + n * 16 + l15;
        #pragma unroll
        for (int r = 0; r < 4; ++r) {
            int row = rowbase + r4 + r;
            float v = E1[(size_t)(bm + row) * H_DIM + col] + silu_f(acc[n][r]);
            st_split((char*)P0H, (char*)P0L, row, col, 256, v);
        }
    }
    __syncthreads();

    #define STAGE_PLAIN(SRC_H, SRC_L, WH, WL, BIAS, DST_H, DST_L)                       \
    {                                                                                   \
        _Pragma("unroll")                                                               \
        for (int n = 0; n < 4; ++n) acc[n] = f32x4{0.f, 0.f, 0.f, 0.f};                 \
        mm128_r16((char*)SRC_H, (char*)SRC_L, WH, WL, rowbase, wn, l15, khalf, acc);    \
        _Pragma("unroll")                                                               \
        for (int n = 0; n < 4; ++n) {                                                   \
            int col = wn * 64 + n * 16 + l15;                                           \
            float bv = BIAS[col];                                                       \
            _Pragma("unroll")                                                           \
            for (int r = 0; r < 4; ++r) {                                               \
                int row = rowbase + r4 + r;                                             \
                st_split((char*)DST_H, (char*)DST_L, row, col, 256,                     \
                         silu_f(acc[n][r] + bv));                                       \
            }                                                                           \
        }                                                                               \
        __syncthreads();                                                                \
    }

    #define STAGE_RES(SRC_H, SRC_L, WH, WL, BIAS, RES_H, RES_L)                         \
    {                                                                                   \
        _Pragma("unroll")                                                               \
        for (int n = 0; n < 4; ++n) acc[n] = f32x4{0.f, 0.f, 0.f, 0.f};                 \
        mm128_r16((char*)SRC_H, (char*)SRC_L, WH, WL, rowbase, wn, l15, khalf, acc);    \
        _Pragma("unroll")                                                               \
        for (int n = 0; n < 4; ++n) {                                                   \
            int col = wn * 64 + n * 16 + l15;                                           \
            float bv = BIAS[col];                                                       \
            _Pragma("unroll")                                                           \
            for (int r = 0; r < 4; ++r) {                                               \
                int row = rowbase + r4 + r;                                             \
                float v = ld_split((char*)RES_H, (char*)RES_L, row, col, 256)           \
                        + silu_f(acc[n][r] + bv);                                       \
                st_split((char*)RES_H, (char*)RES_L, row, col, 256, v);                 \
            }                                                                           \
        }                                                                               \
        __syncthreads();                                                                \
    }

    // S2: P1 = silu(P0@Wb0+bb0)
    STAGE_PLAIN(P0H, P0L, p.b0h, p.b0l, p.bb0, P1H, P1L)
    // S3: P0 += silu(P1@Wb1+bb1)
    STAGE_RES(P1H, P1L, p.b1h, p.b1l, p.bb1, P0H, P0L)

    // S4: x1 = silu(P0@Wlin+blin) + X -> P1
    {
        #pragma unroll
        for (int n = 0; n < 4; ++n) acc[n] = f32x4{0.f, 0.f, 0.f, 0.f};
        mm128_r16((char*)P0H, (char*)P0L, p.lnh, p.lnl, rowbase, wn, l15, khalf, acc);
        #pragma unroll
        for (int n = 0; n < 4; ++n) {
            int col = wn * 64 + n * 16 + l15;
            float bv = p.blin[col];
            #pragma unroll
            for (int r = 0; r < 4; ++r) {
                int row = rowbase + r4 + r;
                float v = silu_f(acc[n][r] + bv) + X[(size_t)(bm + row) * H_DIM + col];
                st_split((char*)P1H, (char*)P1L, row, col, 256, v);
            }
        }
        __syncthreads();
    }

    // S5: P0 = silu(P1@Wa0+ba0)
    STAGE_PLAIN(P1H, P1L, p.a0h, p.a0l, p.ba0, P0H, P0L)
    // S6: P1 += silu(P0@Wa1+ba1)
    STAGE_RES(P0H, P0L, p.a1h, p.a1l, p.ba1, P1H, P1L)
    // S7: P0 = silu(P1@Wa2+ba2)
    STAGE_PLAIN(P1H, P1L, p.a2h, p.a2l, p.ba2, P0H, P0L)

    // S8: OUT = P1 + silu(P0@Wa3+ba3)
    {
        #pragma unroll
        for (int n = 0; n < 4; ++n) acc[n] = f32x4{0.f, 0.f, 0.f, 0.f};
        mm128_r16((char*)P0H, (char*)P0L, p.a3h, p.a3l, rowbase, wn, l15, khalf, acc);
        #pragma unroll
        for (int n = 0; n < 4; ++n) {
            int col = wn * 64 + n * 16 + l15;
            float bv = p.ba3[col];
            #pragma unroll
            for (int r = 0; r < 4; ++r) {
                int row = rowbase + r4 + r;
                float v = ld_split((char*)P1H, (char*)P1L, row, col, 256)
                        + silu_f(acc[n][r] + bv);
                OUT[(size_t)(bm + row) * H_DIM + col] = v;
            }
        }
    }
    #undef STAGE_PLAIN
    #undef STAGE_RES
}

// rbf8[e][j] = rbf[e] @ W_rbf1[b]   [E,8]
__global__ __launch_bounds__(256) void rbf8_kernel(
    const float* __restrict__ rbf, const float* __restrict__ W1,
    float* __restrict__ r8, int Ecount)
{
    int e = blockIdx.x * blockDim.x + threadIdx.x;
    if (e >= Ecount) return;
    float rv[NRAD];
    #pragma unroll
    for (int k = 0; k < NRAD; ++k) rv[k] = rbf[(size_t)e * NRAD + k];
    float acc[BAS] = {};
    #pragma unroll
    for (int k = 0; k < NRAD; ++k)
        #pragma unroll
        for (int j = 0; j < BAS; ++j)
            acc[j] = fmaf(rv[k], W1[k * BAS + j], acc[j]);
    float4* o = reinterpret_cast<float4*>(&r8[(size_t)e * BAS]);
    o[0] = make_float4(acc[0], acc[1], acc[2], acc[3]);
    o[1] = make_float4(acc[4], acc[5], acc[6], acc[7]);
}

// ---------------------------------------------------------------------------
// CSR build kernels
// ---------------------------------------------------------------------------
__global__ __launch_bounds__(256) void csr_count(
    const int* __restrict__ idx, int* __restrict__ cnt, int n)
{
    int i = blockIdx.x * 256 + threadIdx.x;
    if (i < n) atomicAdd(&cnt[idx[i]], 1);
}

__global__ __launch_bounds__(256) void scan_block(
    const int* __restrict__ cnt, int* __restrict__ ptr, int* __restrict__ bsum, int n)
{
    __shared__ int s[256];
    int i = blockIdx.x * 256 + threadIdx.x;
    int v = (i < n) ? cnt[i] : 0;
    s[threadIdx.x] = v;
    __syncthreads();
    #pragma unroll
    for (int off = 1; off < 256; off <<= 1) {
        int t = (threadIdx.x >= off) ? s[threadIdx.x - off] : 0;
        __syncthreads();
        s[threadIdx.x] += t;
        __syncthreads();
    }
    if (i < n) ptr[i] = s[threadIdx.x] - v;   // exclusive
    if (threadIdx.x == 255) bsum[blockIdx.x] = s[255];
}

__global__ __launch_bounds__(1024) void scan_aux(int* __restrict__ bsum, int nb)
{
    __shared__ int s[1024];
    int v = (threadIdx.x < nb) ? bsum[threadIdx.x] : 0;
    s[threadIdx.x] = v;
    __syncthreads();
    #pragma unroll
    for (int off = 1; off < 1024; off <<= 1) {
        int t = (threadIdx.x >= off) ? s[threadIdx.x - off] : 0;
        __syncthreads();
        s[threadIdx.x] += t;
        __syncthreads();
    }
    if (threadIdx.x < nb) bsum[threadIdx.x] = s[threadIdx.x] - v;
}

__global__ __launch_bounds__(256) void scan_add(
    int* __restrict__ ptr, const int* __restrict__ bsum, int n)
{
    int i = blockIdx.x * 256 + threadIdx.x;
    if (i < n) ptr[i] += bsum[blockIdx.x];
}

__global__ __launch_bounds__(256) void csr_fill(
    const int* __restrict__ idx, int* __restrict__ cursor,
    int* __restrict__ perm, int n)
{
    int i = blockIdx.x * 256 + threadIdx.x;
    if (i >= n) return;
    int pos = atomicAdd(&cursor[idx[i]], 1);
    perm[pos] = i;
}

// ---------------------------------------------------------------------------
// One-time: permuted sbf basis for ALL blocks + permuted idx_kj.
// ---------------------------------------------------------------------------
__global__ __launch_bounds__(256) void permute_s8(
    const float* __restrict__ sbf, const float* __restrict__ W1all,
    const int* __restrict__ idx_kj, const int* __restrict__ tperm,
    u16* __restrict__ ps8, int* __restrict__ pkj, int Tcount)
{
    __shared__ float Ws[NB * SBF_D * BAS];
    for (int i = threadIdx.x; i < NB * SBF_D * BAS; i += 256) Ws[i] = W1all[i];
    __syncthreads();
    int i = blockIdx.x * 256 + threadIdx.x;
    if (i >= Tcount) return;
    int t = tperm[i];
    pkj[i] = idx_kj[t];
    float s[SBF_D];
    {
        const float2* p2 = reinterpret_cast<const float2*>(&sbf[(size_t)t * SBF_D]);
        #pragma unroll
        for (int k = 0; k < SBF_D / 2; ++k) {
            float2 v = p2[k];
            s[2 * k] = v.x; s[2 * k + 1] = v.y;
        }
    }
    #pragma unroll
    for (int b = 0; b < NB; ++b) {
        const float* Wb_ = &Ws[b * SBF_D * BAS];
        float acc[BAS] = {};
        for (int k = 0; k < SBF_D; ++k) {
            float sv = s[k];
            #pragma unroll
            for (int j = 0; j < BAS; ++j)
                acc[j] = fmaf(sv, Wb_[k * BAS + j], acc[j]);
        }
        ushort4 o0 = make_ushort4(f2bf(acc[0]), f2bf(acc[1]), f2bf(acc[2]), f2bf(acc[3]));
        ushort4 o1 = make_ushort4(f2bf(acc[4]), f2bf(acc[5]), f2bf(acc[6]), f2bf(acc[7]));
        u16* op = &ps8[((size_t)b * Tcount + i) * BAS];
        *reinterpret_cast<ushort4*>(op) = o0;
        *reinterpret_cast<ushort4*>(op + 4) = o1;
    }
}

// ---------------------------------------------------------------------------
// Triplet aggregation, permuted sequential stream
// ---------------------------------------------------------------------------
__device__ __forceinline__ float dot8_bf(uint4 r, const float* w2) {
    float s;
    s  = bf2f((u16)(r.x)) * w2[0] + bf2f((u16)(r.x >> 16)) * w2[1];
    s += bf2f((u16)(r.y)) * w2[2] + bf2f((u16)(r.y >> 16)) * w2[3];
    s += bf2f((u16)(r.z)) * w2[4] + bf2f((u16)(r.z >> 16)) * w2[5];
    s += bf2f((u16)(r.w)) * w2[6] + bf2f((u16)(r.w >> 16)) * w2[7];
    return s;
}

__global__ __launch_bounds__(256) void triplet_gather2(
    const u16* __restrict__ ps8b, const float* __restrict__ Wsb2,
    const float* __restrict__ xkj, const int* __restrict__ pkj,
    const int* __restrict__ tptr, const int* __restrict__ tcnt,
    float* __restrict__ agg, int Ecount)
{
    const int lane = threadIdx.x & 63;
    int wid = (blockIdx.x * blockDim.x + threadIdx.x) >> 6;
    const int nw = (gridDim.x * blockDim.x) >> 6;
    float w2[BAS];
    #pragma unroll
    for (int j = 0; j < BAS; ++j) w2[j] = Wsb2[j * INT_DIM + lane];

    for (int e = wid; e < Ecount; e += nw) {
        int start = tptr[e];
        int end   = start + tcnt[e];
        float acc0 = 0.f, acc1 = 0.f;
        int i = start;
        for (; i + 1 < end; i += 2) {
            uint4 ra = *reinterpret_cast<const uint4*>(&ps8b[(size_t)i * BAS]);
            uint4 rb = *reinterpret_cast<const uint4*>(&ps8b[(size_t)(i + 1) * BAS]);
            int e0 = pkj[i], e1 = pkj[i + 1];
            float s0 = dot8_bf(ra, w2);
            float s1 = dot8_bf(rb, w2);
            acc0 = fmaf(xkj[(size_t)e0 * INT_DIM + lane], s0, acc0);
            acc1 = fmaf(xkj[(size_t)e1 * INT_DIM + lane], s1, acc1);
        }
        if (i < end) {
            uint4 ra = *reinterpret_cast<const uint4*>(&ps8b[(size_t)i * BAS]);
            int e0 = pkj[i];
            acc0 = fmaf(xkj[(size_t)e0 * INT_DIM + lane], dot8_bf(ra, w2), acc0);
        }
        agg[(size_t)e * INT_DIM + lane] = acc0 + acc1;
    }
}

// ---------------------------------------------------------------------------
// Output-block node gather
// ---------------------------------------------------------------------------
__global__ __launch_bounds__(256) void out_gather(
    const float* __restrict__ rbf, const float* __restrict__ Wor,
    const float* __restrict__ x,
    const int* __restrict__ eptr, const int* __restrict__ ecnt,
    const int* __restrict__ eperm, float* __restrict__ tN, int Nn)
{
    const int lane = threadIdx.x & 63;
    int wid = (blockIdx.x * blockDim.x + threadIdx.x) >> 6;
    const int nw = (gridDim.x * blockDim.x) >> 6;
    float wr0[NRAD], wr1[NRAD];
    #pragma unroll
    for (int k = 0; k < NRAD; ++k) {
        wr0[k] = Wor[k * H_DIM + lane];
        wr1[k] = Wor[k * H_DIM + lane + 64];
    }
    for (int n = wid; n < Nn; n += nw) {
        int start = eptr[n];
        int end   = start + ecnt[n];
        float a0 = 0.f, a1 = 0.f;
        for (int i = start; i < end; ++i) {
            int e = eperm[i];
            const float2* rp = reinterpret_cast<const float2*>(&rbf[(size_t)e * NRAD]);
            float2 r0 = rp[0], r1 = rp[1], r2 = rp[2];
            float rA = r0.x*wr0[0] + r0.y*wr0[1] + r1.x*wr0[2]
                     + r1.y*wr0[3] + r2.x*wr0[4] + r2.y*wr0[5];
            float rB = r0.x*wr1[0] + r0.y*wr1[1] + r1.x*wr1[2]
                     + r1.y*wr1[3] + r2.x*wr1[4] + r2.y*wr1[5];
            a0 = fmaf(rA, x[(size_t)e * H_DIM + lane], a0);
            a1 = fmaf(rB, x[(size_t)e * H_DIM + lane + 64], a1);
        }
        tN[(size_t)n * H_DIM + lane] = a0;
        tN[(size_t)n * H_DIM + lane + 64] = a1;
    }
}

// P[n] += dot(Tb[n][:256], Wo[:256]) — one wave per node
__global__ __launch_bounds__(256) void out_final(
    const float* __restrict__ Tb, const float* __restrict__ Wo,
    float* __restrict__ P, int Nn)
{
    const int lane = threadIdx.x & 63;
    int node = (blockIdx.x * blockDim.x + threadIdx.x) >> 6;
    if (node >= Nn) return;
    float s = 0.f;
    #pragma unroll
    for (int i = 0; i < 4; ++i) {
        int c = lane + i * 64;
        s = fmaf(Tb[(size_t)node * OUT_EMB + c], Wo[c], s);
    }
    #pragma unroll
    for (int o = 32; o > 0; o >>= 1) s += __shfl_xor(s, o);
    if (lane == 0) P[node] += s;
}

// ---------------------------------------------------------------------------
extern "C" void kernel_launch(void* const* d_in, const int* in_sizes, int n_in,
                              void* d_out, int out_size, void* d_ws, size_t ws_size,
                              hipStream_t stream)
{
    const float* x_in    = (const float*)d_in[0];
    const float* rbf     = (const float*)d_in[1];
    const float* sbf     = (const float*)d_in[2];
    const float* W_rbf1  = (const float*)d_in[3];
    const float* W_rbf2  = (const float*)d_in[4];
    const float* W_sbf1  = (const float*)d_in[5];
    const float* W_sbf2  = (const float*)d_in[6];
    const float* W_kj    = (const float*)d_in[7];
    const float* b_kj    = (const float*)d_in[8];
    const float* W_ji    = (const float*)d_in[9];
    const float* b_ji    = (const float*)d_in[10];
    const float* W_down  = (const float*)d_in[11];
    const float* W_up    = (const float*)d_in[12];
    const float* Wb      = (const float*)d_in[13];
    const float* bb      = (const float*)d_in[14];
    const float* Wa      = (const float*)d_in[15];
    const float* ba      = (const float*)d_in[16];
    const float* W_lin   = (const float*)d_in[17];
    const float* b_lin   = (const float*)d_in[18];
    const float* Wo_rbf  = (const float*)d_in[19];
    const float* Wo_up   = (const float*)d_in[20];
    const float* bo_up   = (const float*)d_in[21];
    const float* Wo_lins = (const float*)d_in[22];
    const float* bo_lins = (const float*)d_in[23];
    const float* Wo_out  = (const float*)d_in[24];
    const int*   idx_kj  = (const int*)d_in[25];
    const int*   idx_ji  = (const int*)d_in[26];
    const int*   idx_i   = (const int*)d_in[27];

    // workspace carve-up
    char* ws = (char*)d_ws;
    size_t off = 0;
    auto alloc = [&](size_t bytes) -> void* {
        void* p = (void*)(ws + off);
        off += (bytes + 255) & ~(size_t)255;
        return p;
    };
    float* XA = (float*)alloc((size_t)E_EDGES * H_DIM * 4);
    float* XB = (float*)alloc((size_t)E_EDGES * H_DIM * 4);
    float* E1 = (float*)alloc((size_t)E_EDGES * H_DIM * 4);
    float* C1 = (float*)alloc((size_t)E_EDGES * INT_DIM * 4);
    float* C2 = (float*)alloc((size_t)E_EDGES * INT_DIM * 4);
    float* R8 = (float*)alloc((size_t)E_EDGES * BAS * 4);
    float* TN = (float*)alloc((size_t)N_NODES * H_DIM * 4);
    float* T1 = (float*)alloc((size_t)N_NODES * OUT_EMB * 4);
    float* T2 = (float*)alloc((size_t)N_NODES * OUT_EMB * 4);
    // split-bf16 transposed weights
    u16* HKJ = (u16*)alloc(4  * 16384 * 2); u16* LKJ = (u16*)alloc(4  * 16384 * 2);
    u16* HJI = (u16*)alloc(4  * 16384 * 2); u16* LJI = (u16*)alloc(4  * 16384 * 2);
    u16* HDN = (u16*)alloc(4  * 8192  * 2); u16* LDN = (u16*)alloc(4  * 8192  * 2);
    u16* HUP = (u16*)alloc(4  * 8192  * 2); u16* LUP = (u16*)alloc(4  * 8192  * 2);
    u16* HWB = (u16*)alloc(8  * 16384 * 2); u16* LWB = (u16*)alloc(8  * 16384 * 2);
    u16* HWA = (u16*)alloc(16 * 16384 * 2); u16* LWA = (u16*)alloc(16 * 16384 * 2);
    u16* HLN = (u16*)alloc(4  * 16384 * 2); u16* LLN = (u16*)alloc(4  * 16384 * 2);
    u16* HOU = (u16*)alloc(5  * 32768 * 2); u16* LOU = (u16*)alloc(5  * 32768 * 2);
    u16* HOL = (u16*)alloc(15 * 65536 * 2); u16* LOL = (u16*)alloc(15 * 65536 * 2);
    // CSR structures
    int* tcnt  = (int*)alloc((size_t)E_EDGES * 4);
    int* tptr  = (int*)alloc((size_t)E_EDGES * 4);
    int* tcur  = (int*)alloc((size_t)E_EDGES * 4);
    int* tperm = (int*)alloc((size_t)T_TRIP * 4);
    int* tbsum = (int*)alloc(1024 * 4);
    int* ecnt  = (int*)alloc((size_t)N_NODES * 4);
    int* eptr  = (int*)alloc((size_t)N_NODES * 4);
    int* ecur  = (int*)alloc((size_t)N_NODES * 4);
    int* eperm = (int*)alloc((size_t)E_EDGES * 4);
    int* ebsum = (int*)alloc(1024 * 4);
    // permuted triplet stream
    u16* PS8 = (u16*)alloc((size_t)NB * T_TRIP * BAS * 2);
    int* PKJ = (int*)alloc((size_t)T_TRIP * 4);
    (void)ws_size;

    auto prep = [&](const float* src, u16* hi, u16* lo, int K, int N, int cnt) {
        dim3 g((K * N + 255) / 256, cnt);
        hipLaunchKernelGGL(wprep, g, dim3(256), 0, stream, src, hi, lo, K, N);
    };
    prep(W_kj,    HKJ, LKJ, 128, 128, 4);
    prep(W_ji,    HJI, LJI, 128, 128, 4);
    prep(W_down,  HDN, LDN, 128, 64,  4);
    prep(W_up,    HUP, LUP, 64,  128, 4);
    prep(Wb,      HWB, LWB, 128, 128, 8);
    prep(Wa,      HWA, LWA, 128, 128, 16);
    prep(W_lin,   HLN, LLN, 128, 128, 4);
    prep(Wo_up,   HOU, LOU, 128, 256, 5);
    prep(Wo_lins, HOL, LOL, 256, 256, 15);

    // ---- build triplet CSR (idx_ji: T entries -> E buckets)
    {
        const int nbT = (E_EDGES + 255) / 256;
        hipMemsetAsync(tcnt, 0, (size_t)E_EDGES * 4, stream);
        hipLaunchKernelGGL(csr_count, dim3((T_TRIP + 255) / 256), dim3(256), 0, stream,
                           idx_ji, tcnt, T_TRIP);
        hipLaunchKernelGGL(scan_block, dim3(nbT), dim3(256), 0, stream, tcnt, tptr, tbsum, E_EDGES);
        hipLaunchKernelGGL(scan_aux, dim3(1), dim3(1024), 0, stream, tbsum, nbT);
        hipLaunchKernelGGL(scan_add, dim3(nbT), dim3(256), 0, stream, tptr, tbsum, E_EDGES);
        hipMemcpyAsync(tcur, tptr, (size_t)E_EDGES * 4, hipMemcpyDeviceToDevice, stream);
        hipLaunchKernelGGL(csr_fill, dim3((T_TRIP + 255) / 256), dim3(256), 0, stream,
                           idx_ji, tcur, tperm, T_TRIP);
    }
    // ---- build node CSR (idx_i: E entries -> N buckets)
    {
        const int nbN = (N_NODES + 255) / 256;
        hipMemsetAsync(ecnt, 0, (size_t)N_NODES * 4, stream);
        hipLaunchKernelGGL(csr_count, dim3((E_EDGES + 255) / 256), dim3(256), 0, stream,
                           idx_i, ecnt, E_EDGES);
        hipLaunchKernelGGL(scan_block, dim3(nbN), dim3(256), 0, stream, ecnt, eptr, ebsum, N_NODES);
        hipLaunchKernelGGL(scan_aux, dim3(1), dim3(1024), 0, stream, ebsum, nbN);
        hipLaunchKernelGGL(scan_add, dim3(nbN), dim3(256), 0, stream, eptr, ebsum, N_NODES);
        hipMemcpyAsync(ecur, eptr, (size_t)N_NODES * 4, hipMemcpyDeviceToDevice, stream);
        hipLaunchKernelGGL(csr_fill, dim3((E_EDGES + 255) / 256), dim3(256), 0, stream,
                           idx_i, ecur, eperm, E_EDGES);
    }
    // ---- one-time permuted sbf basis for all blocks
    hipLaunchKernelGGL(permute_s8, dim3((T_TRIP + 255) / 256), dim3(256), 0, stream,
                       sbf, W_sbf1, idx_kj, tperm, PS8, PKJ, T_TRIP);

    auto gemm = [&](const float* A, const u16* Bh, const u16* Bl, const float* bias,
                    const float* res, const float* r8, const float* Wr2f,
                    float* C, int M, int N, int K, int flags) {
        dim3 g(N / 64, (M + 127) / 128), b(256);
        hipLaunchKernelGGL(mfma_gemm, g, b, 0, stream,
                           A, Bh, Bl, bias, res, r8, Wr2f, C, M, N, K, flags);
    };

    float* P = (float*)d_out;
    hipMemsetAsync(P, 0, (size_t)N_NODES * sizeof(float), stream);

    auto out_block = [&](int ob, const float* xcur) {
        hipLaunchKernelGGL(out_gather, dim3(2048), dim3(256), 0, stream,
                           rbf, Wo_rbf + (size_t)ob * NRAD * H_DIM, xcur,
                           eptr, ecnt, eperm, TN, N_NODES);
        gemm(TN, HOU + (size_t)ob * 32768, LOU + (size_t)ob * 32768,
             bo_up + (size_t)ob * OUT_EMB, nullptr, nullptr, nullptr,
             T1, N_NODES, OUT_EMB, H_DIM, F_BIAS);
        float* src = T1; float* dst = T2;
        for (int l = 0; l < 3; ++l) {
            gemm(src, HOL + (size_t)(ob * 3 + l) * 65536, LOL + (size_t)(ob * 3 + l) * 65536,
                 bo_lins + (size_t)(ob * 3 + l) * OUT_EMB, nullptr, nullptr, nullptr,
                 dst, N_NODES, OUT_EMB, OUT_EMB, F_BIAS | F_SILU);
            float* tmp = src; src = dst; dst = tmp;
        }
        hipLaunchKernelGGL(out_final, dim3((N_NODES * 64 + 255) / 256), dim3(256), 0, stream,
                           src, Wo_out + (size_t)ob * OUT_EMB, P, N_NODES);
    };

    out_block(0, x_in);

    const float* xcur = x_in;
    const int EB = E_EDGES / 64;  // 3125
    for (int b = 0; b < NB; ++b) {
        float* xnext = (b % 2 == 0) ? XB : XA;
        hipLaunchKernelGGL(rbf8_kernel, dim3((E_EDGES + 255) / 256), dim3(256), 0, stream,
                           rbf, W_rbf1 + (size_t)b * NRAD * BAS, R8, E_EDGES);
        // fused: E1 = silu(x@Wji+bji); C1 = silu((silu(x@Wkj+bkj)*gate)@Wdn)
        hipLaunchKernelGGL(pre_fuse, dim3(EB), dim3(512), 0, stream,
                           xcur, R8,
                           HJI + (size_t)b * 16384, LJI + (size_t)b * 16384, b_ji + (size_t)b * H_DIM,
                           HKJ + (size_t)b * 16384, LKJ + (size_t)b * 16384, b_kj + (size_t)b * H_DIM,
                           W_rbf2 + (size_t)b * BAS * H_DIM,
                           HDN + (size_t)b * 8192, LDN + (size_t)b * 8192,
                           E1, C1);
        // triplet aggregation (permuted stream, atomic-free)
        hipLaunchKernelGGL(triplet_gather2, dim3(2048), dim3(256), 0, stream,
                           PS8 + (size_t)b * T_TRIP * BAS, W_sbf2 + (size_t)b * BAS * INT_DIM,
                           C1, PKJ, tptr, tcnt, C2, E_EDGES);
        // fused chain: UP + pair(Wb) + LIN + pair(Wa0/1) + pair(Wa2/3)
        ChainP cp;
        cp.uph = HUP + (size_t)b * 8192;  cp.upl = LUP + (size_t)b * 8192;
        cp.b0h = HWB + (size_t)(b * 2 + 0) * 16384; cp.b0l = LWB + (size_t)(b * 2 + 0) * 16384;
        cp.b1h = HWB + (size_t)(b * 2 + 1) * 16384; cp.b1l = LWB + (size_t)(b * 2 + 1) * 16384;
        cp.lnh = HLN + (size_t)b * 16384; cp.lnl = LLN + (size_t)b * 16384;
        cp.a0h = HWA + (size_t)(b * 4 + 0) * 16384; cp.a0l = LWA + (size_t)(b * 4 + 0) * 16384;
        cp.a1h = HWA + (size_t)(b * 4 + 1) * 16384; cp.a1l = LWA + (size_t)(b * 4 + 1) * 16384;
        cp.a2h = HWA + (size_t)(b * 4 + 2) * 16384; cp.a2l = LWA + (size_t)(b * 4 + 2) * 16384;
        cp.a3h = HWA + (size_t)(b * 4 + 3) * 16384; cp.a3l = LWA + (size_t)(b * 4 + 3) * 16384;
        cp.bb0 = bb + (size_t)(b * 2 + 0) * H_DIM;
        cp.bb1 = bb + (size_t)(b * 2 + 1) * H_DIM;
        cp.blin = b_lin + (size_t)b * H_DIM;
        cp.ba0 = ba + (size_t)(b * 4 + 0) * H_DIM;
        cp.ba1 = ba + (size_t)(b * 4 + 1) * H_DIM;
        cp.ba2 = ba + (size_t)(b * 4 + 2) * H_DIM;
        cp.ba3 = ba + (size_t)(b * 4 + 3) * H_DIM;
        hipLaunchKernelGGL(post_chain, dim3(EB), dim3(512), 0, stream,
                           C2, E1, xcur, cp, xnext);
        xcur = xnext;
        out_block(b + 1, xcur);
    }
}

// Round 7
// 4618.398 us; speedup vs baseline: 1.3160x; 1.3160x over previous
//
#include <hip/hip_runtime.h>
#include <hip/hip_bf16.h>

// Problem constants (fixed by the reference)
#define E_EDGES 200000
#define T_TRIP  2000000
#define N_NODES 20000
#define H_DIM   128
#define INT_DIM 64
#define BAS     8
#define OUT_EMB 256
#define NRAD    6
#define SBF_D   42
#define NB      4

// epilogue flags
#define F_BIAS 1
#define F_SILU 2
#define F_RES  4
#define F_GATE 8

typedef __attribute__((ext_vector_type(8))) __bf16 bf16x8;
typedef __attribute__((ext_vector_type(4))) float f32x4;
typedef unsigned short u16;

__device__ __forceinline__ float silu_f(float v) { return v / (1.0f + __expf(-v)); }

__device__ __forceinline__ u16 f2bf(float f) {
    unsigned int u = __float_as_uint(f);
    u += 0x7FFF + ((u >> 16) & 1);   // RNE
    return (u16)(u >> 16);
}
__device__ __forceinline__ float bf2f(u16 h) {
    return __uint_as_float(((unsigned int)h) << 16);
}

__device__ __forceinline__ void st_split(char* H, char* L, int row, int col, int stride, float v) {
    u16 hh = f2bf(v);
    u16 ll = f2bf(v - bf2f(hh));
    int off = (row * stride + col * 2) ^ ((row & 7) << 4);
    *reinterpret_cast<u16*>(H + off) = hh;
    *reinterpret_cast<u16*>(L + off) = ll;
}
__device__ __forceinline__ float ld_split(const char* H, const char* L, int row, int col, int stride) {
    int off = (row * stride + col * 2) ^ ((row & 7) << 4);
    return bf2f(*reinterpret_cast<const u16*>(H + off))
         + bf2f(*reinterpret_cast<const u16*>(L + off));
}

// ---- B-fragment register block: 4 n-tiles (hi+lo), 64 VGPR worth ----
struct BF8x4 { bf16x8 h[4]; bf16x8 l[4]; };

__device__ __forceinline__ BF8x4 loadB128f(const u16* __restrict__ Bh, const u16* __restrict__ Bl,
                                           int k0, int wn, int l15, int khalf)
{
    BF8x4 f;
    #pragma unroll
    for (int n = 0; n < 4; ++n) {
        size_t bo = (size_t)(wn * 64 + n * 16 + l15) * 128 + k0 + khalf;
        f.h[n] = *reinterpret_cast<const bf16x8*>(Bh + bo);
        f.l[n] = *reinterpret_cast<const bf16x8*>(Bl + bo);
    }
    return f;
}
// K=64 weight layout (stride 64)
__device__ __forceinline__ BF8x4 loadB64f(const u16* __restrict__ Bh, const u16* __restrict__ Bl,
                                          int k0, int wn, int l15, int khalf)
{
    BF8x4 f;
    #pragma unroll
    for (int n = 0; n < 4; ++n) {
        size_t bo = (size_t)(wn * 64 + n * 16 + l15) * 64 + k0 + khalf;
        f.h[n] = *reinterpret_cast<const bf16x8*>(Bh + bo);
        f.l[n] = *reinterpret_cast<const bf16x8*>(Bl + bo);
    }
    return f;
}

// one k-slice of MFMAs: A from LDS [64][128] split (stride 256B), wave tile 32x64
__device__ __forceinline__ void mfma_cluster(
    const char* AH, const char* AL, int k0, int wm, int l15, int khalf,
    const BF8x4& b, f32x4 acc[2][4])
{
    #pragma unroll
    for (int m = 0; m < 2; ++m) {
        int row = wm * 32 + m * 16 + l15;
        int off = (row * 256 + (k0 + khalf) * 2) ^ ((row & 7) << 4);
        bf16x8 ah = *reinterpret_cast<const bf16x8*>(AH + off);
        bf16x8 al = *reinterpret_cast<const bf16x8*>(AL + off);
        #pragma unroll
        for (int n = 0; n < 4; ++n) {
            acc[m][n] = __builtin_amdgcn_mfma_f32_16x16x32_bf16(ah, b.h[n], acc[m][n], 0, 0, 0);
            acc[m][n] = __builtin_amdgcn_mfma_f32_16x16x32_bf16(al, b.h[n], acc[m][n], 0, 0, 0);
            acc[m][n] = __builtin_amdgcn_mfma_f32_16x16x32_bf16(ah, b.l[n], acc[m][n], 0, 0, 0);
        }
    }
}
// A from LDS [64][64] split (stride 128B)
__device__ __forceinline__ void mfma_cluster64(
    const char* AH, const char* AL, int k0, int wm, int l15, int khalf,
    const BF8x4& b, f32x4 acc[2][4])
{
    #pragma unroll
    for (int m = 0; m < 2; ++m) {
        int row = wm * 32 + m * 16 + l15;
        int off = (row * 128 + (k0 + khalf) * 2) ^ ((row & 7) << 4);
        bf16x8 ah = *reinterpret_cast<const bf16x8*>(AH + off);
        bf16x8 al = *reinterpret_cast<const bf16x8*>(AL + off);
        #pragma unroll
        for (int n = 0; n < 4; ++n) {
            acc[m][n] = __builtin_amdgcn_mfma_f32_16x16x32_bf16(ah, b.h[n], acc[m][n], 0, 0, 0);
            acc[m][n] = __builtin_amdgcn_mfma_f32_16x16x32_bf16(al, b.h[n], acc[m][n], 0, 0, 0);
            acc[m][n] = __builtin_amdgcn_mfma_f32_16x16x32_bf16(ah, b.l[n], acc[m][n], 0, 0, 0);
        }
    }
}

// Pipelined K=128 GEMM: `pre` holds this stage's k0=0 frag; on exit `pre`
// holds NEXT stage's k0=0 frag (loads issued before epilogue/barrier).
__device__ __forceinline__ void mm128_pipe(
    const char* AH, const char* AL,
    const u16* __restrict__ Bh, const u16* __restrict__ Bl, BF8x4& pre,
    const u16* __restrict__ nBh, const u16* __restrict__ nBl,
    int wm, int wn, int l15, int khalf, f32x4 acc[2][4])
{
    BF8x4 c0 = pre;
    BF8x4 c1 = loadB128f(Bh, Bl, 32, wn, l15, khalf);
    mfma_cluster(AH, AL, 0, wm, l15, khalf, c0, acc);
    BF8x4 c2 = loadB128f(Bh, Bl, 64, wn, l15, khalf);
    mfma_cluster(AH, AL, 32, wm, l15, khalf, c1, acc);
    BF8x4 c3 = loadB128f(Bh, Bl, 96, wn, l15, khalf);
    mfma_cluster(AH, AL, 64, wm, l15, khalf, c2, acc);
    if (nBh) pre = loadB128f(nBh, nBl, 0, wn, l15, khalf);
    mfma_cluster(AH, AL, 96, wm, l15, khalf, c3, acc);
}
// Pipelined K=64 GEMM (A stride 128B); prefetches next (K=128) stage.
__device__ __forceinline__ void mm64_pipe(
    const char* AH, const char* AL,
    const u16* __restrict__ Bh, const u16* __restrict__ Bl, BF8x4& pre,
    const u16* __restrict__ nBh, const u16* __restrict__ nBl,
    int wm, int wn, int l15, int khalf, f32x4 acc[2][4])
{
    BF8x4 c0 = pre;
    BF8x4 c1 = loadB64f(Bh, Bl, 32, wn, l15, khalf);
    mfma_cluster64(AH, AL, 0, wm, l15, khalf, c0, acc);
    if (nBh) pre = loadB128f(nBh, nBl, 0, wn, l15, khalf);
    mfma_cluster64(AH, AL, 32, wm, l15, khalf, c1, acc);
}

// ---------------------------------------------------------------------------
// Weight prep: src [cnt][K][N] f32 row-major -> hi/lo [cnt][N][K] split-bf16
// ---------------------------------------------------------------------------
__global__ __launch_bounds__(256) void wprep(
    const float* __restrict__ src, u16* __restrict__ hi,
    u16* __restrict__ lo, int K, int N)
{
    int e = blockIdx.x * 256 + threadIdx.x;
    int total = K * N;
    if (e >= total) return;
    size_t base = (size_t)blockIdx.y * total;
    float a = src[base + e];
    int k = e / N, n = e - k * N;
    u16 h = f2bf(a);
    u16 l = f2bf(a - bf2f(h));
    hi[base + (size_t)n * K + k] = h;
    lo[base + (size_t)n * K + k] = l;
}

// ---------------------------------------------------------------------------
// Generic split-bf16 MFMA GEMM (used by output blocks)
// ---------------------------------------------------------------------------
__global__ __launch_bounds__(256) void mfma_gemm(
    const float* __restrict__ A,
    const u16* __restrict__ Bhi, const u16* __restrict__ Blo,
    const float* __restrict__ bias, const float* __restrict__ res,
    const float* __restrict__ rbf8v, const float* __restrict__ Wr2,
    float* __restrict__ C, int M, int N, int K, int flags)
{
    __shared__ u16 AsH[128 * 32];
    __shared__ u16 AsL[128 * 32];

    const int tid  = threadIdx.x;
    const int lane = tid & 63;
    const int w    = tid >> 6;
    const int wm   = w >> 1, wn = w & 1;
    const int bm   = blockIdx.y * 128;
    const int bn   = blockIdx.x * 64;
    const int l15  = lane & 15;
    const int khalf = (lane >> 4) * 8;

    const int sr = tid >> 1;
    const int sc = (tid & 1) * 16;
    int grow = bm + sr; if (grow >= M) grow = M - 1;
    const float* gA = &A[(size_t)grow * K + sc];

    int bcol[2];
    #pragma unroll
    for (int n = 0; n < 2; ++n) bcol[n] = bn + wn * 32 + n * 16 + l15;

    f32x4 acc[4][2] = {};

    for (int k0 = 0; k0 < K; k0 += 32) {
        __syncthreads();
        {
            const float* p = gA + k0;
            float4 f0 = *reinterpret_cast<const float4*>(p);
            float4 f1 = *reinterpret_cast<const float4*>(p + 4);
            float4 f2 = *reinterpret_cast<const float4*>(p + 8);
            float4 f3 = *reinterpret_cast<const float4*>(p + 12);
            float vv[16] = {f0.x,f0.y,f0.z,f0.w, f1.x,f1.y,f1.z,f1.w,
                            f2.x,f2.y,f2.z,f2.w, f3.x,f3.y,f3.z,f3.w};
            const int swz = (sr & 7) << 4;
            #pragma unroll
            for (int q = 0; q < 4; ++q) {
                u16 h[4], l[4];
                #pragma unroll
                for (int j = 0; j < 4; ++j) {
                    float a = vv[q * 4 + j];
                    h[j] = f2bf(a);
                    l[j] = f2bf(a - bf2f(h[j]));
                }
                int off = (sr * 64 + (sc / 4 + q) * 8) ^ swz;
                *reinterpret_cast<ushort4*>((char*)AsH + off) = make_ushort4(h[0], h[1], h[2], h[3]);
                *reinterpret_cast<ushort4*>((char*)AsL + off) = make_ushort4(l[0], l[1], l[2], l[3]);
            }
        }
        __syncthreads();

        bf16x8 bh[2], bl[2];
        #pragma unroll
        for (int n = 0; n < 2; ++n) {
            size_t bo = (size_t)bcol[n] * K + k0 + khalf;
            bh[n] = *reinterpret_cast<const bf16x8*>(Bhi + bo);
            bl[n] = *reinterpret_cast<const bf16x8*>(Blo + bo);
        }

        #pragma unroll
        for (int m = 0; m < 4; ++m) {
            int ri  = wm * 64 + m * 16 + l15;
            int off = (ri * 64 + khalf * 2) ^ ((ri & 7) << 4);
            bf16x8 ah = *reinterpret_cast<const bf16x8*>((const char*)AsH + off);
            bf16x8 al = *reinterpret_cast<const bf16x8*>((const char*)AsL + off);
            #pragma unroll
            for (int n = 0; n < 2; ++n) {
                acc[m][n] = __builtin_amdgcn_mfma_f32_16x16x32_bf16(ah, bh[n], acc[m][n], 0, 0, 0);
                acc[m][n] = __builtin_amdgcn_mfma_f32_16x16x32_bf16(al, bh[n], acc[m][n], 0, 0, 0);
                acc[m][n] = __builtin_amdgcn_mfma_f32_16x16x32_bf16(ah, bl[n], acc[m][n], 0, 0, 0);
            }
        }
    }

    const int r4 = (lane >> 4) * 4;
    #pragma unroll
    for (int m = 0; m < 4; ++m) {
        #pragma unroll
        for (int r = 0; r < 4; ++r) {
            int row = bm + wm * 64 + m * 16 + r4 + r;
            if (row >= M) continue;
            #pragma unroll
            for (int n = 0; n < 2; ++n) {
                int col = bn + wn * 32 + n * 16 + l15;
                float v = acc[m][n][r];
                if (flags & F_BIAS) v += bias[col];
                if (flags & F_SILU) v = silu_f(v);
                if (flags & F_GATE) {
                    float g = 0.f;
                    #pragma unroll
                    for (int j = 0; j < 8; ++j)
                        g = fmaf(rbf8v[(size_t)row * 8 + j], Wr2[j * N + col], g);
                    v *= g;
                }
                if (flags & F_RES) v += res[(size_t)row * N + col];
                C[(size_t)row * N + col] = v;
            }
        }
    }
}

// ---------------------------------------------------------------------------
// pre_fuse (256 threads, 4 waves, wave tile 32x64), weight-prefetch pipelined
// ---------------------------------------------------------------------------
__global__ __launch_bounds__(256, 2) void pre_fuse(
    const float* __restrict__ X, const float* __restrict__ R8,
    const u16* __restrict__ Wjih, const u16* __restrict__ Wjil, const float* __restrict__ bji,
    const u16* __restrict__ Wkjh, const u16* __restrict__ Wkjl, const float* __restrict__ bkj,
    const float* __restrict__ Wr2,
    const u16* __restrict__ Wdnh, const u16* __restrict__ Wdnl,
    float* __restrict__ E1, float* __restrict__ C1)
{
    __shared__ u16 XH[64 * 128], XL[64 * 128];
    __shared__ u16 IH[64 * 128], IL[64 * 128];

    const int tid  = threadIdx.x;
    const int lane = tid & 63;
    const int w    = tid >> 6;
    const int wm   = w >> 1, wn = w & 1;
    const int bm   = blockIdx.x * 64;
    const int l15  = lane & 15;
    const int khalf = (lane >> 4) * 8;
    const int r4   = (lane >> 4) * 4;

    // prologue: prefetch JI k0=0 weights (overlaps X staging)
    BF8x4 pre = loadB128f(Wjih, Wjil, 0, wn, l15, khalf);

    // stage X [64][128]
    {
        int r  = tid >> 2;
        int c0 = (tid & 3) * 32;
        const float* p = &X[(size_t)(bm + r) * H_DIM + c0];
        const int swz = (r & 7) << 4;
        #pragma unroll
        for (int q = 0; q < 8; ++q) {
            float4 f = *reinterpret_cast<const float4*>(p + q * 4);
            float vv[4] = {f.x, f.y, f.z, f.w};
            u16 h[4], l[4];
            #pragma unroll
            for (int j = 0; j < 4; ++j) {
                h[j] = f2bf(vv[j]);
                l[j] = f2bf(vv[j] - bf2f(h[j]));
            }
            int off = (r * 256 + c0 * 2 + q * 8) ^ swz;
            *reinterpret_cast<ushort4*>((char*)XH + off) = make_ushort4(h[0], h[1], h[2], h[3]);
            *reinterpret_cast<ushort4*>((char*)XL + off) = make_ushort4(l[0], l[1], l[2], l[3]);
        }
    }
    __syncthreads();

    // JI -> E1  (prefetches KJ k0=0 into pre)
    {
        f32x4 acc[2][4] = {};
        mm128_pipe((char*)XH, (char*)XL, Wjih, Wjil, pre, Wkjh, Wkjl,
                   wm, wn, l15, khalf, acc);
        #pragma unroll
        for (int n = 0; n < 4; ++n) {
            int col = wn * 64 + n * 16 + l15;
            float bv = bji[col];
            #pragma unroll
            for (int m = 0; m < 2; ++m)
                #pragma unroll
                for (int r = 0; r < 4; ++r) {
                    int row = wm * 32 + m * 16 + r4 + r;
                    E1[(size_t)(bm + row) * H_DIM + col] = silu_f(acc[m][n][r] + bv);
                }
        }
    }
    // KJ * gate -> I (LDS)
    {
        f32x4 acc[2][4] = {};
        mm128_pipe((char*)XH, (char*)XL, Wkjh, Wkjl, pre, nullptr, nullptr,
                   wm, wn, l15, khalf, acc);
        #pragma unroll
        for (int n = 0; n < 4; ++n) {
            int col = wn * 64 + n * 16 + l15;
            float bv = bkj[col];
            #pragma unroll
            for (int m = 0; m < 2; ++m)
                #pragma unroll
                for (int r = 0; r < 4; ++r) {
                    int row = wm * 32 + m * 16 + r4 + r;
                    float v = silu_f(acc[m][n][r] + bv);
                    float g = 0.f;
                    #pragma unroll
                    for (int j = 0; j < 8; ++j)
                        g = fmaf(R8[(size_t)(bm + row) * 8 + j], Wr2[j * H_DIM + col], g);
                    st_split((char*)IH, (char*)IL, row, col, 256, v * g);
                }
        }
    }
    __syncthreads();

    // DOWN (N=64) -> C1
    {
        f32x4 acc[2][2] = {};
        #pragma unroll
        for (int k0 = 0; k0 < 128; k0 += 32) {
            bf16x8 bh[2], bl[2];
            #pragma unroll
            for (int n = 0; n < 2; ++n) {
                size_t bo = (size_t)(wn * 32 + n * 16 + l15) * 128 + k0 + khalf;
                bh[n] = *reinterpret_cast<const bf16x8*>(Wdnh + bo);
                bl[n] = *reinterpret_cast<const bf16x8*>(Wdnl + bo);
            }
            #pragma unroll
            for (int m = 0; m < 2; ++m) {
                int row = wm * 32 + m * 16 + l15;
                int off = (row * 256 + (k0 + khalf) * 2) ^ ((row & 7) << 4);
                bf16x8 ah = *reinterpret_cast<const bf16x8*>((const char*)IH + off);
                bf16x8 al = *reinterpret_cast<const bf16x8*>((const char*)IL + off);
                #pragma unroll
                for (int n = 0; n < 2; ++n) {
                    acc[m][n] = __builtin_amdgcn_mfma_f32_16x16x32_bf16(ah, bh[n], acc[m][n], 0, 0, 0);
                    acc[m][n] = __builtin_amdgcn_mfma_f32_16x16x32_bf16(al, bh[n], acc[m][n], 0, 0, 0);
                    acc[m][n] = __builtin_amdgcn_mfma_f32_16x16x32_bf16(ah, bl[n], acc[m][n], 0, 0, 0);
                }
            }
        }
        #pragma unroll
        for (int n = 0; n < 2; ++n) {
            int col = wn * 32 + n * 16 + l15;
            #pragma unroll
            for (int m = 0; m < 2; ++m)
                #pragma unroll
                for (int r = 0; r < 4; ++r) {
                    int row = wm * 32 + m * 16 + r4 + r;
                    C1[(size_t)(bm + row) * INT_DIM + col] = silu_f(acc[m][n][r]);
                }
        }
    }
}

// ---------------------------------------------------------------------------
// post_chain (256 threads, 4 waves, wave tile 32x64), weight-prefetch pipelined
// ---------------------------------------------------------------------------
struct ChainP {
    const u16 *uph, *upl;
    const u16 *b0h, *b0l, *b1h, *b1l;
    const u16 *lnh, *lnl;
    const u16 *a0h, *a0l, *a1h, *a1l, *a2h, *a2l, *a3h, *a3l;
    const float *bb0, *bb1, *blin, *ba0, *ba1, *ba2, *ba3;
};

__global__ __launch_bounds__(256, 2) void post_chain(
    const float* __restrict__ AGG, const float* __restrict__ E1,
    const float* __restrict__ X, ChainP p, float* __restrict__ OUT)
{
    __shared__ u16 GH[64 * 64],  GL[64 * 64];
    __shared__ u16 P0H[64 * 128], P0L[64 * 128];
    __shared__ u16 P1H[64 * 128], P1L[64 * 128];

    const int tid  = threadIdx.x;
    const int lane = tid & 63;
    const int w    = tid >> 6;
    const int wm   = w >> 1, wn = w & 1;
    const int bm   = blockIdx.x * 64;
    const int l15  = lane & 15;
    const int khalf = (lane >> 4) * 8;
    const int r4   = (lane >> 4) * 4;

    // prologue: prefetch UP k0=0 weights (overlaps AGG staging)
    BF8x4 pre = loadB64f(p.uph, p.upl, 0, wn, l15, khalf);

    // stage AGG [64][64]
    {
        int r  = tid >> 2;
        int c0 = (tid & 3) * 16;
        const float* pg = &AGG[(size_t)(bm + r) * INT_DIM + c0];
        const int swz = (r & 7) << 4;
        #pragma unroll
        for (int q = 0; q < 4; ++q) {
            float4 f = *reinterpret_cast<const float4*>(pg + q * 4);
            float vv[4] = {f.x, f.y, f.z, f.w};
            u16 h[4], l[4];
            #pragma unroll
            for (int j = 0; j < 4; ++j) {
                h[j] = f2bf(vv[j]);
                l[j] = f2bf(vv[j] - bf2f(h[j]));
            }
            int off = (r * 128 + c0 * 2 + q * 8) ^ swz;
            *reinterpret_cast<ushort4*>((char*)GH + off) = make_ushort4(h[0], h[1], h[2], h[3]);
            *reinterpret_cast<ushort4*>((char*)GL + off) = make_ushort4(l[0], l[1], l[2], l[3]);
        }
    }
    __syncthreads();

    f32x4 acc[2][4];

    // S1: UP (K=64), h0 = E1 + silu(acc) -> P0 ; prefetch Wb0
    #pragma unroll
    for (int m = 0; m < 2; ++m)
        #pragma unroll
        for (int n = 0; n < 4; ++n) acc[m][n] = f32x4{0.f, 0.f, 0.f, 0.f};
    mm64_pipe((char*)GH, (char*)GL, p.uph, p.upl, pre, p.b0h, p.b0l,
              wm, wn, l15, khalf, acc);
    #pragma unroll
    for (int n = 0; n < 4; ++n) {
        int col = wn * 64 + n * 16 + l15;
        #pragma unroll
        for (int m = 0; m < 2; ++m)
            #pragma unroll
            for (int r = 0; r < 4; ++r) {
                int row = wm * 32 + m * 16 + r4 + r;
                float v = E1[(size_t)(bm + row) * H_DIM + col] + silu_f(acc[m][n][r]);
                st_split((char*)P0H, (char*)P0L, row, col, 256, v);
            }
    }
    __syncthreads();

    #define STAGE_PLAIN(SRC_H, SRC_L, WH, WL, BIAS, DST_H, DST_L, NWH, NWL)             \
    {                                                                                   \
        _Pragma("unroll")                                                               \
        for (int m = 0; m < 2; ++m)                                                     \
            _Pragma("unroll")                                                           \
            for (int n = 0; n < 4; ++n) acc[m][n] = f32x4{0.f, 0.f, 0.f, 0.f};          \
        mm128_pipe((char*)SRC_H, (char*)SRC_L, WH, WL, pre, NWH, NWL,                   \
                   wm, wn, l15, khalf, acc);                                            \
        _Pragma("unroll")                                                               \
        for (int n = 0; n < 4; ++n) {                                                   \
            int col = wn * 64 + n * 16 + l15;                                           \
            float bv = BIAS[col];                                                       \
            _Pragma("unroll")                                                           \
            for (int m = 0; m < 2; ++m)                                                 \
                _Pragma("unroll")                                                       \
                for (int r = 0; r < 4; ++r) {                                           \
                    int row = wm * 32 + m * 16 + r4 + r;                                \
                    st_split((char*)DST_H, (char*)DST_L, row, col, 256,                 \
                             silu_f(acc[m][n][r] + bv));                                \
                }                                                                       \
        }                                                                               \
        __syncthreads();                                                                \
    }

    #define STAGE_RES(SRC_H, SRC_L, WH, WL, BIAS, RES_H, RES_L, NWH, NWL)               \
    {                                                                                   \
        _Pragma("unroll")                                                               \
        for (int m = 0; m < 2; ++m)                                                     \
            _Pragma("unroll")                                                           \
            for (int n = 0; n < 4; ++n) acc[m][n] = f32x4{0.f, 0.f, 0.f, 0.f};          \
        mm128_pipe((char*)SRC_H, (char*)SRC_L, WH, WL, pre, NWH, NWL,                   \
                   wm, wn, l15, khalf, acc);                                            \
        _Pragma("unroll")                                                               \
        for (int n = 0; n < 4; ++n) {                                                   \
            int col = wn * 64 + n * 16 + l15;                                           \
            float bv = BIAS[col];                                                       \
            _Pragma("unroll")                                                           \
            for (int m = 0; m < 2; ++m)                                                 \
                _Pragma("unroll")                                                       \
                for (int r = 0; r < 4; ++r) {                                           \
                    int row = wm * 32 + m * 16 + r4 + r;                                \
                    float v = ld_split((char*)RES_H, (char*)RES_L, row, col, 256)       \
                            + silu_f(acc[m][n][r] + bv);                                \
                    st_split((char*)RES_H, (char*)RES_L, row, col, 256, v);             \
                }                                                                       \
        }                                                                               \
        __syncthreads();                                                                \
    }

    // S2: P1 = silu(P0@Wb0+bb0)                 ; prefetch Wb1
    STAGE_PLAIN(P0H, P0L, p.b0h, p.b0l, p.bb0, P1H, P1L, p.b1h, p.b1l)
    // S3: P0 += silu(P1@Wb1+bb1)                ; prefetch Wlin
    STAGE_RES(P1H, P1L, p.b1h, p.b1l, p.bb1, P0H, P0L, p.lnh, p.lnl)

    // S4: x1 = silu(P0@Wlin+blin) + X -> P1     ; prefetch Wa0
    {
        #pragma unroll
        for (int m = 0; m < 2; ++m)
            #pragma unroll
            for (int n = 0; n < 4; ++n) acc[m][n] = f32x4{0.f, 0.f, 0.f, 0.f};
        mm128_pipe((char*)P0H, (char*)P0L, p.lnh, p.lnl, pre, p.a0h, p.a0l,
                   wm, wn, l15, khalf, acc);
        #pragma unroll
        for (int n = 0; n < 4; ++n) {
            int col = wn * 64 + n * 16 + l15;
            float bv = p.blin[col];
            #pragma unroll
            for (int m = 0; m < 2; ++m)
                #pragma unroll
                for (int r = 0; r < 4; ++r) {
                    int row = wm * 32 + m * 16 + r4 + r;
                    float v = silu_f(acc[m][n][r] + bv) + X[(size_t)(bm + row) * H_DIM + col];
                    st_split((char*)P1H, (char*)P1L, row, col, 256, v);
                }
        }
        __syncthreads();
    }

    // S5: P0 = silu(P1@Wa0+ba0)                 ; prefetch Wa1
    STAGE_PLAIN(P1H, P1L, p.a0h, p.a0l, p.ba0, P0H, P0L, p.a1h, p.a1l)
    // S6: P1 += silu(P0@Wa1+ba1)                ; prefetch Wa2
    STAGE_RES(P0H, P0L, p.a1h, p.a1l, p.ba1, P1H, P1L, p.a2h, p.a2l)
    // S7: P0 = silu(P1@Wa2+ba2)                 ; prefetch Wa3
    STAGE_PLAIN(P1H, P1L, p.a2h, p.a2l, p.ba2, P0H, P0L, p.a3h, p.a3l)

    // S8: OUT = P1 + silu(P0@Wa3+ba3)
    {
        #pragma unroll
        for (int m = 0; m < 2; ++m)
            #pragma unroll
            for (int n = 0; n < 4; ++n) acc[m][n] = f32x4{0.f, 0.f, 0.f, 0.f};
        mm128_pipe((char*)P0H, (char*)P0L, p.a3h, p.a3l, pre, nullptr, nullptr,
                   wm, wn, l15, khalf, acc);
        #pragma unroll
        for (int n = 0; n < 4; ++n) {
            int col = wn * 64 + n * 16 + l15;
            float bv = p.ba3[col];
            #pragma unroll
            for (int m = 0; m < 2; ++m)
                #pragma unroll
                for (int r = 0; r < 4; ++r) {
                    int row = wm * 32 + m * 16 + r4 + r;
                    float v = ld_split((char*)P1H, (char*)P1L, row, col, 256)
                            + silu_f(acc[m][n][r] + bv);
                    OUT[(size_t)(bm + row) * H_DIM + col] = v;
                }
        }
    }
    #undef STAGE_PLAIN
    #undef STAGE_RES
}

// rbf8[e][j] = rbf[e] @ W_rbf1[b]   [E,8]
__global__ __launch_bounds__(256) void rbf8_kernel(
    const float* __restrict__ rbf, const float* __restrict__ W1,
    float* __restrict__ r8, int Ecount)
{
    int e = blockIdx.x * blockDim.x + threadIdx.x;
    if (e >= Ecount) return;
    float rv[NRAD];
    #pragma unroll
    for (int k = 0; k < NRAD; ++k) rv[k] = rbf[(size_t)e * NRAD + k];
    float acc[BAS] = {};
    #pragma unroll
    for (int k = 0; k < NRAD; ++k)
        #pragma unroll
        for (int j = 0; j < BAS; ++j)
            acc[j] = fmaf(rv[k], W1[k * BAS + j], acc[j]);
    float4* o = reinterpret_cast<float4*>(&r8[(size_t)e * BAS]);
    o[0] = make_float4(acc[0], acc[1], acc[2], acc[3]);
    o[1] = make_float4(acc[4], acc[5], acc[6], acc[7]);
}

// ---------------------------------------------------------------------------
// CSR build kernels
// ---------------------------------------------------------------------------
__global__ __launch_bounds__(256) void csr_count(
    const int* __restrict__ idx, int* __restrict__ cnt, int n)
{
    int i = blockIdx.x * 256 + threadIdx.x;
    if (i < n) atomicAdd(&cnt[idx[i]], 1);
}

__global__ __launch_bounds__(256) void scan_block(
    const int* __restrict__ cnt, int* __restrict__ ptr, int* __restrict__ bsum, int n)
{
    __shared__ int s[256];
    int i = blockIdx.x * 256 + threadIdx.x;
    int v = (i < n) ? cnt[i] : 0;
    s[threadIdx.x] = v;
    __syncthreads();
    #pragma unroll
    for (int off = 1; off < 256; off <<= 1) {
        int t = (threadIdx.x >= off) ? s[threadIdx.x - off] : 0;
        __syncthreads();
        s[threadIdx.x] += t;
        __syncthreads();
    }
    if (i < n) ptr[i] = s[threadIdx.x] - v;   // exclusive
    if (threadIdx.x == 255) bsum[blockIdx.x] = s[255];
}

__global__ __launch_bounds__(1024) void scan_aux(int* __restrict__ bsum, int nb)
{
    __shared__ int s[1024];
    int v = (threadIdx.x < nb) ? bsum[threadIdx.x] : 0;
    s[threadIdx.x] = v;
    __syncthreads();
    #pragma unroll
    for (int off = 1; off < 1024; off <<= 1) {
        int t = (threadIdx.x >= off) ? s[threadIdx.x - off] : 0;
        __syncthreads();
        s[threadIdx.x] += t;
        __syncthreads();
    }
    if (threadIdx.x < nb) bsum[threadIdx.x] = s[threadIdx.x] - v;
}

__global__ __launch_bounds__(256) void scan_add(
    int* __restrict__ ptr, const int* __restrict__ bsum, int n)
{
    int i = blockIdx.x * 256 + threadIdx.x;
    if (i < n) ptr[i] += bsum[blockIdx.x];
}

__global__ __launch_bounds__(256) void csr_fill(
    const int* __restrict__ idx, int* __restrict__ cursor,
    int* __restrict__ perm, int n)
{
    int i = blockIdx.x * 256 + threadIdx.x;
    if (i >= n) return;
    int pos = atomicAdd(&cursor[idx[i]], 1);
    perm[pos] = i;
}

// ---------------------------------------------------------------------------
// One-time: permuted sbf basis for ALL blocks + permuted idx_kj.
// ---------------------------------------------------------------------------
__global__ __launch_bounds__(256) void permute_s8(
    const float* __restrict__ sbf, const float* __restrict__ W1all,
    const int* __restrict__ idx_kj, const int* __restrict__ tperm,
    u16* __restrict__ ps8, int* __restrict__ pkj, int Tcount)
{
    __shared__ float Ws[NB * SBF_D * BAS];
    for (int i = threadIdx.x; i < NB * SBF_D * BAS; i += 256) Ws[i] = W1all[i];
    __syncthreads();
    int i = blockIdx.x * 256 + threadIdx.x;
    if (i >= Tcount) return;
    int t = tperm[i];
    pkj[i] = idx_kj[t];
    float s[SBF_D];
    {
        const float2* p2 = reinterpret_cast<const float2*>(&sbf[(size_t)t * SBF_D]);
        #pragma unroll
        for (int k = 0; k < SBF_D / 2; ++k) {
            float2 v = p2[k];
            s[2 * k] = v.x; s[2 * k + 1] = v.y;
        }
    }
    #pragma unroll
    for (int b = 0; b < NB; ++b) {
        const float* Wb_ = &Ws[b * SBF_D * BAS];
        float acc[BAS] = {};
        for (int k = 0; k < SBF_D; ++k) {
            float sv = s[k];
            #pragma unroll
            for (int j = 0; j < BAS; ++j)
                acc[j] = fmaf(sv, Wb_[k * BAS + j], acc[j]);
        }
        ushort4 o0 = make_ushort4(f2bf(acc[0]), f2bf(acc[1]), f2bf(acc[2]), f2bf(acc[3]));
        ushort4 o1 = make_ushort4(f2bf(acc[4]), f2bf(acc[5]), f2bf(acc[6]), f2bf(acc[7]));
        u16* op = &ps8[((size_t)b * Tcount + i) * BAS];
        *reinterpret_cast<ushort4*>(op) = o0;
        *reinterpret_cast<ushort4*>(op + 4) = o1;
    }
}

// ---------------------------------------------------------------------------
// Triplet aggregation, permuted sequential stream
// ---------------------------------------------------------------------------
__device__ __forceinline__ float dot8_bf(uint4 r, const float* w2) {
    float s;
    s  = bf2f((u16)(r.x)) * w2[0] + bf2f((u16)(r.x >> 16)) * w2[1];
    s += bf2f((u16)(r.y)) * w2[2] + bf2f((u16)(r.y >> 16)) * w2[3];
    s += bf2f((u16)(r.z)) * w2[4] + bf2f((u16)(r.z >> 16)) * w2[5];
    s += bf2f((u16)(r.w)) * w2[6] + bf2f((u16)(r.w >> 16)) * w2[7];
    return s;
}

__global__ __launch_bounds__(256) void triplet_gather2(
    const u16* __restrict__ ps8b, const float* __restrict__ Wsb2,
    const float* __restrict__ xkj, const int* __restrict__ pkj,
    const int* __restrict__ tptr, const int* __restrict__ tcnt,
    float* __restrict__ agg, int Ecount)
{
    const int lane = threadIdx.x & 63;
    int wid = (blockIdx.x * blockDim.x + threadIdx.x) >> 6;
    const int nw = (gridDim.x * blockDim.x) >> 6;
    float w2[BAS];
    #pragma unroll
    for (int j = 0; j < BAS; ++j) w2[j] = Wsb2[j * INT_DIM + lane];

    for (int e = wid; e < Ecount; e += nw) {
        int start = tptr[e];
        int end   = start + tcnt[e];
        float acc0 = 0.f, acc1 = 0.f;
        int i = start;
        for (; i + 1 < end; i += 2) {
            uint4 ra = *reinterpret_cast<const uint4*>(&ps8b[(size_t)i * BAS]);
            uint4 rb = *reinterpret_cast<const uint4*>(&ps8b[(size_t)(i + 1) * BAS]);
            int e0 = pkj[i], e1 = pkj[i + 1];
            float s0 = dot8_bf(ra, w2);
            float s1 = dot8_bf(rb, w2);
            acc0 = fmaf(xkj[(size_t)e0 * INT_DIM + lane], s0, acc0);
            acc1 = fmaf(xkj[(size_t)e1 * INT_DIM + lane], s1, acc1);
        }
        if (i < end) {
            uint4 ra = *reinterpret_cast<const uint4*>(&ps8b[(size_t)i * BAS]);
            int e0 = pkj[i];
            acc0 = fmaf(xkj[(size_t)e0 * INT_DIM + lane], dot8_bf(ra, w2), acc0);
        }
        agg[(size_t)e * INT_DIM + lane] = acc0 + acc1;
    }
}

// ---------------------------------------------------------------------------
// Output-block node gather
// ---------------------------------------------------------------------------
__global__ __launch_bounds__(256) void out_gather(
    const float* __restrict__ rbf, const float* __restrict__ Wor,
    const float* __restrict__ x,
    const int* __restrict__ eptr, const int* __restrict__ ecnt,
    const int* __restrict__ eperm, float* __restrict__ tN, int Nn)
{
    const int lane = threadIdx.x & 63;
    int wid = (blockIdx.x * blockDim.x + threadIdx.x) >> 6;
    const int nw = (gridDim.x * blockDim.x) >> 6;
    float wr0[NRAD], wr1[NRAD];
    #pragma unroll
    for (int k = 0; k < NRAD; ++k) {
        wr0[k] = Wor[k * H_DIM + lane];
        wr1[k] = Wor[k * H_DIM + lane + 64];
    }
    for (int n = wid; n < Nn; n += nw) {
        int start = eptr[n];
        int end   = start + ecnt[n];
        float a0 = 0.f, a1 = 0.f;
        for (int i = start; i < end; ++i) {
            int e = eperm[i];
            const float2* rp = reinterpret_cast<const float2*>(&rbf[(size_t)e * NRAD]);
            float2 r0 = rp[0], r1 = rp[1], r2 = rp[2];
            float rA = r0.x*wr0[0] + r0.y*wr0[1] + r1.x*wr0[2]
                     + r1.y*wr0[3] + r2.x*wr0[4] + r2.y*wr0[5];
            float rB = r0.x*wr1[0] + r0.y*wr1[1] + r1.x*wr1[2]
                     + r1.y*wr1[3] + r2.x*wr1[4] + r2.y*wr1[5];
            a0 = fmaf(rA, x[(size_t)e * H_DIM + lane], a0);
            a1 = fmaf(rB, x[(size_t)e * H_DIM + lane + 64], a1);
        }
        tN[(size_t)n * H_DIM + lane] = a0;
        tN[(size_t)n * H_DIM + lane + 64] = a1;
    }
}

// P[n] += dot(Tb[n][:256], Wo[:256]) — one wave per node
__global__ __launch_bounds__(256) void out_final(
    const float* __restrict__ Tb, const float* __restrict__ Wo,
    float* __restrict__ P, int Nn)
{
    const int lane = threadIdx.x & 63;
    int node = (blockIdx.x * blockDim.x + threadIdx.x) >> 6;
    if (node >= Nn) return;
    float s = 0.f;
    #pragma unroll
    for (int i = 0; i < 4; ++i) {
        int c = lane + i * 64;
        s = fmaf(Tb[(size_t)node * OUT_EMB + c], Wo[c], s);
    }
    #pragma unroll
    for (int o = 32; o > 0; o >>= 1) s += __shfl_xor(s, o);
    if (lane == 0) P[node] += s;
}

// ---------------------------------------------------------------------------
extern "C" void kernel_launch(void* const* d_in, const int* in_sizes, int n_in,
                              void* d_out, int out_size, void* d_ws, size_t ws_size,
                              hipStream_t stream)
{
    const float* x_in    = (const float*)d_in[0];
    const float* rbf     = (const float*)d_in[1];
    const float* sbf     = (const float*)d_in[2];
    const float* W_rbf1  = (const float*)d_in[3];
    const float* W_rbf2  = (const float*)d_in[4];
    const float* W_sbf1  = (const float*)d_in[5];
    const float* W_sbf2  = (const float*)d_in[6];
    const float* W_kj    = (const float*)d_in[7];
    const float* b_kj    = (const float*)d_in[8];
    const float* W_ji    = (const float*)d_in[9];
    const float* b_ji    = (const float*)d_in[10];
    const float* W_down  = (const float*)d_in[11];
    const float* W_up    = (const float*)d_in[12];
    const float* Wb      = (const float*)d_in[13];
    const float* bb      = (const float*)d_in[14];
    const float* Wa      = (const float*)d_in[15];
    const float* ba      = (const float*)d_in[16];
    const float* W_lin   = (const float*)d_in[17];
    const float* b_lin   = (const float*)d_in[18];
    const float* Wo_rbf  = (const float*)d_in[19];
    const float* Wo_up   = (const float*)d_in[20];
    const float* bo_up   = (const float*)d_in[21];
    const float* Wo_lins = (const float*)d_in[22];
    const float* bo_lins = (const float*)d_in[23];
    const float* Wo_out  = (const float*)d_in[24];
    const int*   idx_kj  = (const int*)d_in[25];
    const int*   idx_ji  = (const int*)d_in[26];
    const int*   idx_i   = (const int*)d_in[27];

    // workspace carve-up
    char* ws = (char*)d_ws;
    size_t off = 0;
    auto alloc = [&](size_t bytes) -> void* {
        void* p = (void*)(ws + off);
        off += (bytes + 255) & ~(size_t)255;
        return p;
    };
    float* XA = (float*)alloc((size_t)E_EDGES * H_DIM * 4);
    float* XB = (float*)alloc((size_t)E_EDGES * H_DIM * 4);
    float* E1 = (float*)alloc((size_t)E_EDGES * H_DIM * 4);
    float* C1 = (float*)alloc((size_t)E_EDGES * INT_DIM * 4);
    float* C2 = (float*)alloc((size_t)E_EDGES * INT_DIM * 4);
    float* R8 = (float*)alloc((size_t)E_EDGES * BAS * 4);
    float* TN = (float*)alloc((size_t)N_NODES * H_DIM * 4);
    float* T1 = (float*)alloc((size_t)N_NODES * OUT_EMB * 4);
    float* T2 = (float*)alloc((size_t)N_NODES * OUT_EMB * 4);
    // split-bf16 transposed weights
    u16* HKJ = (u16*)alloc(4  * 16384 * 2); u16* LKJ = (u16*)alloc(4  * 16384 * 2);
    u16* HJI = (u16*)alloc(4  * 16384 * 2); u16* LJI = (u16*)alloc(4  * 16384 * 2);
    u16* HDN = (u16*)alloc(4  * 8192  * 2); u16* LDN = (u16*)alloc(4  * 8192  * 2);
    u16* HUP = (u16*)alloc(4  * 8192  * 2); u16* LUP = (u16*)alloc(4  * 8192  * 2);
    u16* HWB = (u16*)alloc(8  * 16384 * 2); u16* LWB = (u16*)alloc(8  * 16384 * 2);
    u16* HWA = (u16*)alloc(16 * 16384 * 2); u16* LWA = (u16*)alloc(16 * 16384 * 2);
    u16* HLN = (u16*)alloc(4  * 16384 * 2); u16* LLN = (u16*)alloc(4  * 16384 * 2);
    u16* HOU = (u16*)alloc(5  * 32768 * 2); u16* LOU = (u16*)alloc(5  * 32768 * 2);
    u16* HOL = (u16*)alloc(15 * 65536 * 2); u16* LOL = (u16*)alloc(15 * 65536 * 2);
    // CSR structures
    int* tcnt  = (int*)alloc((size_t)E_EDGES * 4);
    int* tptr  = (int*)alloc((size_t)E_EDGES * 4);
    int* tcur  = (int*)alloc((size_t)E_EDGES * 4);
    int* tperm = (int*)alloc((size_t)T_TRIP * 4);
    int* tbsum = (int*)alloc(1024 * 4);
    int* ecnt  = (int*)alloc((size_t)N_NODES * 4);
    int* eptr  = (int*)alloc((size_t)N_NODES * 4);
    int* ecur  = (int*)alloc((size_t)N_NODES * 4);
    int* eperm = (int*)alloc((size_t)E_EDGES * 4);
    int* ebsum = (int*)alloc(1024 * 4);
    // permuted triplet stream
    u16* PS8 = (u16*)alloc((size_t)NB * T_TRIP * BAS * 2);
    int* PKJ = (int*)alloc((size_t)T_TRIP * 4);
    (void)ws_size;

    auto prep = [&](const float* src, u16* hi, u16* lo, int K, int N, int cnt) {
        dim3 g((K * N + 255) / 256, cnt);
        hipLaunchKernelGGL(wprep, g, dim3(256), 0, stream, src, hi, lo, K, N);
    };
    prep(W_kj,    HKJ, LKJ, 128, 128, 4);
    prep(W_ji,    HJI, LJI, 128, 128, 4);
    prep(W_down,  HDN, LDN, 128, 64,  4);
    prep(W_up,    HUP, LUP, 64,  128, 4);
    prep(Wb,      HWB, LWB, 128, 128, 8);
    prep(Wa,      HWA, LWA, 128, 128, 16);
    prep(W_lin,   HLN, LLN, 128, 128, 4);
    prep(Wo_up,   HOU, LOU, 128, 256, 5);
    prep(Wo_lins, HOL, LOL, 256, 256, 15);

    // ---- build triplet CSR (idx_ji: T entries -> E buckets)
    {
        const int nbT = (E_EDGES + 255) / 256;
        hipMemsetAsync(tcnt, 0, (size_t)E_EDGES * 4, stream);
        hipLaunchKernelGGL(csr_count, dim3((T_TRIP + 255) / 256), dim3(256), 0, stream,
                           idx_ji, tcnt, T_TRIP);
        hipLaunchKernelGGL(scan_block, dim3(nbT), dim3(256), 0, stream, tcnt, tptr, tbsum, E_EDGES);
        hipLaunchKernelGGL(scan_aux, dim3(1), dim3(1024), 0, stream, tbsum, nbT);
        hipLaunchKernelGGL(scan_add, dim3(nbT), dim3(256), 0, stream, tptr, tbsum, E_EDGES);
        hipMemcpyAsync(tcur, tptr, (size_t)E_EDGES * 4, hipMemcpyDeviceToDevice, stream);
        hipLaunchKernelGGL(csr_fill, dim3((T_TRIP + 255) / 256), dim3(256), 0, stream,
                           idx_ji, tcur, tperm, T_TRIP);
    }
    // ---- build node CSR (idx_i: E entries -> N buckets)
    {
        const int nbN = (N_NODES + 255) / 256;
        hipMemsetAsync(ecnt, 0, (size_t)N_NODES * 4, stream);
        hipLaunchKernelGGL(csr_count, dim3((E_EDGES + 255) / 256), dim3(256), 0, stream,
                           idx_i, ecnt, E_EDGES);
        hipLaunchKernelGGL(scan_block, dim3(nbN), dim3(256), 0, stream, ecnt, eptr, ebsum, N_NODES);
        hipLaunchKernelGGL(scan_aux, dim3(1), dim3(1024), 0, stream, ebsum, nbN);
        hipLaunchKernelGGL(scan_add, dim3(nbN), dim3(256), 0, stream, eptr, ebsum, N_NODES);
        hipMemcpyAsync(ecur, eptr, (size_t)N_NODES * 4, hipMemcpyDeviceToDevice, stream);
        hipLaunchKernelGGL(csr_fill, dim3((E_EDGES + 255) / 256), dim3(256), 0, stream,
                           idx_i, ecur, eperm, E_EDGES);
    }
    // ---- one-time permuted sbf basis for all blocks
    hipLaunchKernelGGL(permute_s8, dim3((T_TRIP + 255) / 256), dim3(256), 0, stream,
                       sbf, W_sbf1, idx_kj, tperm, PS8, PKJ, T_TRIP);

    auto gemm = [&](const float* A, const u16* Bh, const u16* Bl, const float* bias,
                    const float* res, const float* r8, const float* Wr2f,
                    float* C, int M, int N, int K, int flags) {
        dim3 g(N / 64, (M + 127) / 128), b(256);
        hipLaunchKernelGGL(mfma_gemm, g, b, 0, stream,
                           A, Bh, Bl, bias, res, r8, Wr2f, C, M, N, K, flags);
    };

    float* P = (float*)d_out;
    hipMemsetAsync(P, 0, (size_t)N_NODES * sizeof(float), stream);

    auto out_block = [&](int ob, const float* xcur) {
        hipLaunchKernelGGL(out_gather, dim3(2048), dim3(256), 0, stream,
                           rbf, Wo_rbf + (size_t)ob * NRAD * H_DIM, xcur,
                           eptr, ecnt, eperm, TN, N_NODES);
        gemm(TN, HOU + (size_t)ob * 32768, LOU + (size_t)ob * 32768,
             bo_up + (size_t)ob * OUT_EMB, nullptr, nullptr, nullptr,
             T1, N_NODES, OUT_EMB, H_DIM, F_BIAS);
        float* src = T1; float* dst = T2;
        for (int l = 0; l < 3; ++l) {
            gemm(src, HOL + (size_t)(ob * 3 + l) * 65536, LOL + (size_t)(ob * 3 + l) * 65536,
                 bo_lins + (size_t)(ob * 3 + l) * OUT_EMB, nullptr, nullptr, nullptr,
                 dst, N_NODES, OUT_EMB, OUT_EMB, F_BIAS | F_SILU);
            float* tmp = src; src = dst; dst = tmp;
        }
        hipLaunchKernelGGL(out_final, dim3((N_NODES * 64 + 255) / 256), dim3(256), 0, stream,
                           src, Wo_out + (size_t)ob * OUT_EMB, P, N_NODES);
    };

    out_block(0, x_in);

    const float* xcur = x_in;
    const int EB = E_EDGES / 64;  // 3125
    for (int b = 0; b < NB; ++b) {
        float* xnext = (b % 2 == 0) ? XB : XA;
        hipLaunchKernelGGL(rbf8_kernel, dim3((E_EDGES + 255) / 256), dim3(256), 0, stream,
                           rbf, W_rbf1 + (size_t)b * NRAD * BAS, R8, E_EDGES);
        // fused: E1 = silu(x@Wji+bji); C1 = silu((silu(x@Wkj+bkj)*gate)@Wdn)
        hipLaunchKernelGGL(pre_fuse, dim3(EB), dim3(256), 0, stream,
                           xcur, R8,
                           HJI + (size_t)b * 16384, LJI + (size_t)b * 16384, b_ji + (size_t)b * H_DIM,
                           HKJ + (size_t)b * 16384, LKJ + (size_t)b * 16384, b_kj + (size_t)b * H_DIM,
                           W_rbf2 + (size_t)b * BAS * H_DIM,
                           HDN + (size_t)b * 8192, LDN + (size_t)b * 8192,
                           E1, C1);
        // triplet aggregation (permuted stream, atomic-free)
        hipLaunchKernelGGL(triplet_gather2, dim3(2048), dim3(256), 0, stream,
                           PS8 + (size_t)b * T_TRIP * BAS, W_sbf2 + (size_t)b * BAS * INT_DIM,
                           C1, PKJ, tptr, tcnt, C2, E_EDGES);
        // fused chain: UP + pair(Wb) + LIN + pair(Wa0/1) + pair(Wa2/3)
        ChainP cp;
        cp.uph = HUP + (size_t)b * 8192;  cp.upl = LUP + (size_t)b * 8192;
        cp.b0h = HWB + (size_t)(b * 2 + 0) * 16384; cp.b0l = LWB + (size_t)(b * 2 + 0) * 16384;
        cp.b1h = HWB + (size_t)(b * 2 + 1) * 16384; cp.b1l = LWB + (size_t)(b * 2 + 1) * 16384;
        cp.lnh = HLN + (size_t)b * 16384; cp.lnl = LLN + (size_t)b * 16384;
        cp.a0h = HWA + (size_t)(b * 4 + 0) * 16384; cp.a0l = LWA + (size_t)(b * 4 + 0) * 16384;
        cp.a1h = HWA + (size_t)(b * 4 + 1) * 16384; cp.a1l = LWA + (size_t)(b * 4 + 1) * 16384;
        cp.a2h = HWA + (size_t)(b * 4 + 2) * 16384; cp.a2l = LWA + (size_t)(b * 4 + 2) * 16384;
        cp.a3h = HWA + (size_t)(b * 4 + 3) * 16384; cp.a3l = LWA + (size_t)(b * 4 + 3) * 16384;
        cp.bb0 = bb + (size_t)(b * 2 + 0) * H_DIM;
        cp.bb1 = bb + (size_t)(b * 2 + 1) * H_DIM;
        cp.blin = b_lin + (size_t)b * H_DIM;
        cp.ba0 = ba + (size_t)(b * 4 + 0) * H_DIM;
        cp.ba1 = ba + (size_t)(b * 4 + 1) * H_DIM;
        cp.ba2 = ba + (size_t)(b * 4 + 2) * H_DIM;
        cp.ba3 = ba + (size_t)(b * 4 + 3) * H_DIM;
        hipLaunchKernelGGL(post_chain, dim3(EB), dim3(256), 0, stream,
                           C2, E1, xcur, cp, xnext);
        xcur = xnext;
        out_block(b + 1, xcur);
    }
}

// Round 8
// 4437.812 us; speedup vs baseline: 1.3696x; 1.0407x over previous
//
#include <hip/hip_runtime.h>
#include <hip/hip_bf16.h>

// Problem constants (fixed by the reference)
#define E_EDGES 200000
#define T_TRIP  2000000
#define N_NODES 20000
#define H_DIM   128
#define INT_DIM 64
#define BAS     8
#define OUT_EMB 256
#define NRAD    6
#define SBF_D   42
#define NB      4

typedef __attribute__((ext_vector_type(8))) __bf16 bf16x8;
typedef __attribute__((ext_vector_type(4))) float f32x4;
typedef unsigned short u16;

__device__ __forceinline__ float silu_f(float v) { return v / (1.0f + __expf(-v)); }

__device__ __forceinline__ u16 f2bf(float f) {
    unsigned int u = __float_as_uint(f);
    u += 0x7FFF + ((u >> 16) & 1);   // RNE
    return (u16)(u >> 16);
}
__device__ __forceinline__ float bf2f(u16 h) {
    return __uint_as_float(((unsigned int)h) << 16);
}

__device__ __forceinline__ void st_split(char* H, char* L, int row, int col, int stride, float v) {
    u16 hh = f2bf(v);
    u16 ll = f2bf(v - bf2f(hh));
    int off = (row * stride + col * 2) ^ ((row & 7) << 4);
    *reinterpret_cast<u16*>(H + off) = hh;
    *reinterpret_cast<u16*>(L + off) = ll;
}
__device__ __forceinline__ float ld_split(const char* H, const char* L, int row, int col, int stride) {
    int off = (row * stride + col * 2) ^ ((row & 7) << 4);
    return bf2f(*reinterpret_cast<const u16*>(H + off))
         + bf2f(*reinterpret_cast<const u16*>(L + off));
}

// ---- B-fragment register block: 4 n-tiles (hi+lo) ----
struct BF8x4 { bf16x8 h[4]; bf16x8 l[4]; };

__device__ __forceinline__ BF8x4 loadB128f(const u16* __restrict__ Bh, const u16* __restrict__ Bl,
                                           int k0, int wn, int l15, int khalf)
{
    BF8x4 f;
    #pragma unroll
    for (int n = 0; n < 4; ++n) {
        size_t bo = (size_t)(wn * 64 + n * 16 + l15) * 128 + k0 + khalf;
        f.h[n] = *reinterpret_cast<const bf16x8*>(Bh + bo);
        f.l[n] = *reinterpret_cast<const bf16x8*>(Bl + bo);
    }
    return f;
}
__device__ __forceinline__ BF8x4 loadB64f(const u16* __restrict__ Bh, const u16* __restrict__ Bl,
                                          int k0, int wn, int l15, int khalf)
{
    BF8x4 f;
    #pragma unroll
    for (int n = 0; n < 4; ++n) {
        size_t bo = (size_t)(wn * 64 + n * 16 + l15) * 64 + k0 + khalf;
        f.h[n] = *reinterpret_cast<const bf16x8*>(Bh + bo);
        f.l[n] = *reinterpret_cast<const bf16x8*>(Bl + bo);
    }
    return f;
}
__device__ __forceinline__ BF8x4 loadB256f(const u16* __restrict__ Bh, const u16* __restrict__ Bl,
                                           int k0, int wn, int l15, int khalf)
{
    BF8x4 f;
    #pragma unroll
    for (int n = 0; n < 4; ++n) {
        size_t bo = (size_t)(wn * 64 + n * 16 + l15) * 256 + k0 + khalf;
        f.h[n] = *reinterpret_cast<const bf16x8*>(Bh + bo);
        f.l[n] = *reinterpret_cast<const bf16x8*>(Bl + bo);
    }
    return f;
}

// one k-slice of MFMAs: A from LDS [64][128] split (stride 256B), wave tile 32x64
__device__ __forceinline__ void mfma_cluster(
    const char* AH, const char* AL, int k0, int wm, int l15, int khalf,
    const BF8x4& b, f32x4 acc[2][4])
{
    __builtin_amdgcn_s_setprio(1);
    #pragma unroll
    for (int m = 0; m < 2; ++m) {
        int row = wm * 32 + m * 16 + l15;
        int off = (row * 256 + (k0 + khalf) * 2) ^ ((row & 7) << 4);
        bf16x8 ah = *reinterpret_cast<const bf16x8*>(AH + off);
        bf16x8 al = *reinterpret_cast<const bf16x8*>(AL + off);
        #pragma unroll
        for (int n = 0; n < 4; ++n) {
            acc[m][n] = __builtin_amdgcn_mfma_f32_16x16x32_bf16(ah, b.h[n], acc[m][n], 0, 0, 0);
            acc[m][n] = __builtin_amdgcn_mfma_f32_16x16x32_bf16(al, b.h[n], acc[m][n], 0, 0, 0);
            acc[m][n] = __builtin_amdgcn_mfma_f32_16x16x32_bf16(ah, b.l[n], acc[m][n], 0, 0, 0);
        }
    }
    __builtin_amdgcn_s_setprio(0);
}
// A from LDS [64][64] split (stride 128B)
__device__ __forceinline__ void mfma_cluster64(
    const char* AH, const char* AL, int k0, int wm, int l15, int khalf,
    const BF8x4& b, f32x4 acc[2][4])
{
    __builtin_amdgcn_s_setprio(1);
    #pragma unroll
    for (int m = 0; m < 2; ++m) {
        int row = wm * 32 + m * 16 + l15;
        int off = (row * 128 + (k0 + khalf) * 2) ^ ((row & 7) << 4);
        bf16x8 ah = *reinterpret_cast<const bf16x8*>(AH + off);
        bf16x8 al = *reinterpret_cast<const bf16x8*>(AL + off);
        #pragma unroll
        for (int n = 0; n < 4; ++n) {
            acc[m][n] = __builtin_amdgcn_mfma_f32_16x16x32_bf16(ah, b.h[n], acc[m][n], 0, 0, 0);
            acc[m][n] = __builtin_amdgcn_mfma_f32_16x16x32_bf16(al, b.h[n], acc[m][n], 0, 0, 0);
            acc[m][n] = __builtin_amdgcn_mfma_f32_16x16x32_bf16(ah, b.l[n], acc[m][n], 0, 0, 0);
        }
    }
    __builtin_amdgcn_s_setprio(0);
}
// A from LDS [32][256] split (stride 512B), rows 0..31
__device__ __forceinline__ void mfma_cluster512(
    const char* AH, const char* AL, int k0, int l15, int khalf,
    const BF8x4& b, f32x4 acc[2][4])
{
    __builtin_amdgcn_s_setprio(1);
    #pragma unroll
    for (int m = 0; m < 2; ++m) {
        int row = m * 16 + l15;
        int off = (row * 512 + (k0 + khalf) * 2) ^ ((row & 7) << 4);
        bf16x8 ah = *reinterpret_cast<const bf16x8*>(AH + off);
        bf16x8 al = *reinterpret_cast<const bf16x8*>(AL + off);
        #pragma unroll
        for (int n = 0; n < 4; ++n) {
            acc[m][n] = __builtin_amdgcn_mfma_f32_16x16x32_bf16(ah, b.h[n], acc[m][n], 0, 0, 0);
            acc[m][n] = __builtin_amdgcn_mfma_f32_16x16x32_bf16(al, b.h[n], acc[m][n], 0, 0, 0);
            acc[m][n] = __builtin_amdgcn_mfma_f32_16x16x32_bf16(ah, b.l[n], acc[m][n], 0, 0, 0);
        }
    }
    __builtin_amdgcn_s_setprio(0);
}

// Pipelined K=128 GEMM: `pre` holds this stage's k0=0 frag; on exit `pre`
// holds NEXT stage's k0=0 frag.
__device__ __forceinline__ void mm128_pipe(
    const char* AH, const char* AL,
    const u16* __restrict__ Bh, const u16* __restrict__ Bl, BF8x4& pre,
    const u16* __restrict__ nBh, const u16* __restrict__ nBl,
    int wm, int wn, int l15, int khalf, f32x4 acc[2][4])
{
    BF8x4 c0 = pre;
    BF8x4 c1 = loadB128f(Bh, Bl, 32, wn, l15, khalf);
    mfma_cluster(AH, AL, 0, wm, l15, khalf, c0, acc);
    BF8x4 c2 = loadB128f(Bh, Bl, 64, wn, l15, khalf);
    mfma_cluster(AH, AL, 32, wm, l15, khalf, c1, acc);
    BF8x4 c3 = loadB128f(Bh, Bl, 96, wn, l15, khalf);
    mfma_cluster(AH, AL, 64, wm, l15, khalf, c2, acc);
    if (nBh) pre = loadB128f(nBh, nBl, 0, wn, l15, khalf);
    mfma_cluster(AH, AL, 96, wm, l15, khalf, c3, acc);
}
__device__ __forceinline__ void mm64_pipe(
    const char* AH, const char* AL,
    const u16* __restrict__ Bh, const u16* __restrict__ Bl, BF8x4& pre,
    const u16* __restrict__ nBh, const u16* __restrict__ nBl,
    int wm, int wn, int l15, int khalf, f32x4 acc[2][4])
{
    BF8x4 c0 = pre;
    BF8x4 c1 = loadB64f(Bh, Bl, 32, wn, l15, khalf);
    mfma_cluster64(AH, AL, 0, wm, l15, khalf, c0, acc);
    if (nBh) pre = loadB128f(nBh, nBl, 0, wn, l15, khalf);
    mfma_cluster64(AH, AL, 32, wm, l15, khalf, c1, acc);
}

// ---------------------------------------------------------------------------
// Weight prep: src [cnt][K][N] f32 row-major -> hi/lo [cnt][N][K] split-bf16
// ---------------------------------------------------------------------------
__global__ __launch_bounds__(256) void wprep(
    const float* __restrict__ src, u16* __restrict__ hi,
    u16* __restrict__ lo, int K, int N)
{
    int e = blockIdx.x * 256 + threadIdx.x;
    int total = K * N;
    if (e >= total) return;
    size_t base = (size_t)blockIdx.y * total;
    float a = src[base + e];
    int k = e / N, n = e - k * N;
    u16 h = f2bf(a);
    u16 l = f2bf(a - bf2f(h));
    hi[base + (size_t)n * K + k] = h;
    lo[base + (size_t)n * K + k] = l;
}

// ---------------------------------------------------------------------------
// pre_fuse (256 threads, 4 waves, wave tile 32x64), weight-prefetch pipelined
// ---------------------------------------------------------------------------
__global__ __launch_bounds__(256, 2) void pre_fuse(
    const float* __restrict__ X, const float* __restrict__ R8,
    const u16* __restrict__ Wjih, const u16* __restrict__ Wjil, const float* __restrict__ bji,
    const u16* __restrict__ Wkjh, const u16* __restrict__ Wkjl, const float* __restrict__ bkj,
    const float* __restrict__ Wr2,
    const u16* __restrict__ Wdnh, const u16* __restrict__ Wdnl,
    float* __restrict__ E1, float* __restrict__ C1)
{
    __shared__ u16 XH[64 * 128], XL[64 * 128];
    __shared__ u16 IH[64 * 128], IL[64 * 128];

    const int tid  = threadIdx.x;
    const int lane = tid & 63;
    const int w    = tid >> 6;
    const int wm   = w >> 1, wn = w & 1;
    const int bm   = blockIdx.x * 64;
    const int l15  = lane & 15;
    const int khalf = (lane >> 4) * 8;
    const int r4   = (lane >> 4) * 4;

    BF8x4 pre = loadB128f(Wjih, Wjil, 0, wn, l15, khalf);

    // stage X [64][128]
    {
        int r  = tid >> 2;
        int c0 = (tid & 3) * 32;
        const float* p = &X[(size_t)(bm + r) * H_DIM + c0];
        const int swz = (r & 7) << 4;
        #pragma unroll
        for (int q = 0; q < 8; ++q) {
            float4 f = *reinterpret_cast<const float4*>(p + q * 4);
            float vv[4] = {f.x, f.y, f.z, f.w};
            u16 h[4], l[4];
            #pragma unroll
            for (int j = 0; j < 4; ++j) {
                h[j] = f2bf(vv[j]);
                l[j] = f2bf(vv[j] - bf2f(h[j]));
            }
            int off = (r * 256 + c0 * 2 + q * 8) ^ swz;
            *reinterpret_cast<ushort4*>((char*)XH + off) = make_ushort4(h[0], h[1], h[2], h[3]);
            *reinterpret_cast<ushort4*>((char*)XL + off) = make_ushort4(l[0], l[1], l[2], l[3]);
        }
    }
    __syncthreads();

    // JI -> E1  (prefetches KJ k0=0 into pre)
    {
        f32x4 acc[2][4] = {};
        mm128_pipe((char*)XH, (char*)XL, Wjih, Wjil, pre, Wkjh, Wkjl,
                   wm, wn, l15, khalf, acc);
        #pragma unroll
        for (int n = 0; n < 4; ++n) {
            int col = wn * 64 + n * 16 + l15;
            float bv = bji[col];
            #pragma unroll
            for (int m = 0; m < 2; ++m)
                #pragma unroll
                for (int r = 0; r < 4; ++r) {
                    int row = wm * 32 + m * 16 + r4 + r;
                    E1[(size_t)(bm + row) * H_DIM + col] = silu_f(acc[m][n][r] + bv);
                }
        }
    }
    // KJ * gate -> I (LDS)
    {
        f32x4 acc[2][4] = {};
        mm128_pipe((char*)XH, (char*)XL, Wkjh, Wkjl, pre, nullptr, nullptr,
                   wm, wn, l15, khalf, acc);
        #pragma unroll
        for (int n = 0; n < 4; ++n) {
            int col = wn * 64 + n * 16 + l15;
            float bv = bkj[col];
            #pragma unroll
            for (int m = 0; m < 2; ++m)
                #pragma unroll
                for (int r = 0; r < 4; ++r) {
                    int row = wm * 32 + m * 16 + r4 + r;
                    float v = silu_f(acc[m][n][r] + bv);
                    float g = 0.f;
                    #pragma unroll
                    for (int j = 0; j < 8; ++j)
                        g = fmaf(R8[(size_t)(bm + row) * 8 + j], Wr2[j * H_DIM + col], g);
                    st_split((char*)IH, (char*)IL, row, col, 256, v * g);
                }
        }
    }
    __syncthreads();

    // DOWN (N=64) -> C1
    {
        f32x4 acc[2][2] = {};
        #pragma unroll
        for (int k0 = 0; k0 < 128; k0 += 32) {
            bf16x8 bh[2], bl[2];
            #pragma unroll
            for (int n = 0; n < 2; ++n) {
                size_t bo = (size_t)(wn * 32 + n * 16 + l15) * 128 + k0 + khalf;
                bh[n] = *reinterpret_cast<const bf16x8*>(Wdnh + bo);
                bl[n] = *reinterpret_cast<const bf16x8*>(Wdnl + bo);
            }
            __builtin_amdgcn_s_setprio(1);
            #pragma unroll
            for (int m = 0; m < 2; ++m) {
                int row = wm * 32 + m * 16 + l15;
                int off = (row * 256 + (k0 + khalf) * 2) ^ ((row & 7) << 4);
                bf16x8 ah = *reinterpret_cast<const bf16x8*>((const char*)IH + off);
                bf16x8 al = *reinterpret_cast<const bf16x8*>((const char*)IL + off);
                #pragma unroll
                for (int n = 0; n < 2; ++n) {
                    acc[m][n] = __builtin_amdgcn_mfma_f32_16x16x32_bf16(ah, bh[n], acc[m][n], 0, 0, 0);
                    acc[m][n] = __builtin_amdgcn_mfma_f32_16x16x32_bf16(al, bh[n], acc[m][n], 0, 0, 0);
                    acc[m][n] = __builtin_amdgcn_mfma_f32_16x16x32_bf16(ah, bl[n], acc[m][n], 0, 0, 0);
                }
            }
            __builtin_amdgcn_s_setprio(0);
        }
        #pragma unroll
        for (int n = 0; n < 2; ++n) {
            int col = wn * 32 + n * 16 + l15;
            #pragma unroll
            for (int m = 0; m < 2; ++m)
                #pragma unroll
                for (int r = 0; r < 4; ++r) {
                    int row = wm * 32 + m * 16 + r4 + r;
                    C1[(size_t)(bm + row) * INT_DIM + col] = silu_f(acc[m][n][r]);
                }
        }
    }
}

// ---------------------------------------------------------------------------
// post_chain (256 threads, 4 waves, wave tile 32x64), weight-prefetch pipelined
// ---------------------------------------------------------------------------
struct ChainP {
    const u16 *uph, *upl;
    const u16 *b0h, *b0l, *b1h, *b1l;
    const u16 *lnh, *lnl;
    const u16 *a0h, *a0l, *a1h, *a1l, *a2h, *a2l, *a3h, *a3l;
    const float *bb0, *bb1, *blin, *ba0, *ba1, *ba2, *ba3;
};

__global__ __launch_bounds__(256, 2) void post_chain(
    const float* __restrict__ AGG, const float* __restrict__ E1,
    const float* __restrict__ X, ChainP p, float* __restrict__ OUT)
{
    __shared__ u16 GH[64 * 64],  GL[64 * 64];
    __shared__ u16 P0H[64 * 128], P0L[64 * 128];
    __shared__ u16 P1H[64 * 128], P1L[64 * 128];

    const int tid  = threadIdx.x;
    const int lane = tid & 63;
    const int w    = tid >> 6;
    const int wm   = w >> 1, wn = w & 1;
    const int bm   = blockIdx.x * 64;
    const int l15  = lane & 15;
    const int khalf = (lane >> 4) * 8;
    const int r4   = (lane >> 4) * 4;

    BF8x4 pre = loadB64f(p.uph, p.upl, 0, wn, l15, khalf);

    // stage AGG [64][64]
    {
        int r  = tid >> 2;
        int c0 = (tid & 3) * 16;
        const float* pg = &AGG[(size_t)(bm + r) * INT_DIM + c0];
        const int swz = (r & 7) << 4;
        #pragma unroll
        for (int q = 0; q < 4; ++q) {
            float4 f = *reinterpret_cast<const float4*>(pg + q * 4);
            float vv[4] = {f.x, f.y, f.z, f.w};
            u16 h[4], l[4];
            #pragma unroll
            for (int j = 0; j < 4; ++j) {
                h[j] = f2bf(vv[j]);
                l[j] = f2bf(vv[j] - bf2f(h[j]));
            }
            int off = (r * 128 + c0 * 2 + q * 8) ^ swz;
            *reinterpret_cast<ushort4*>((char*)GH + off) = make_ushort4(h[0], h[1], h[2], h[3]);
            *reinterpret_cast<ushort4*>((char*)GL + off) = make_ushort4(l[0], l[1], l[2], l[3]);
        }
    }
    __syncthreads();

    f32x4 acc[2][4];

    // S1: UP (K=64), h0 = E1 + silu(acc) -> P0 ; prefetch Wb0
    #pragma unroll
    for (int m = 0; m < 2; ++m)
        #pragma unroll
        for (int n = 0; n < 4; ++n) acc[m][n] = f32x4{0.f, 0.f, 0.f, 0.f};
    mm64_pipe((char*)GH, (char*)GL, p.uph, p.upl, pre, p.b0h, p.b0l,
              wm, wn, l15, khalf, acc);
    #pragma unroll
    for (int n = 0; n < 4; ++n) {
        int col = wn * 64 + n * 16 + l15;
        #pragma unroll
        for (int m = 0; m < 2; ++m)
            #pragma unroll
            for (int r = 0; r < 4; ++r) {
                int row = wm * 32 + m * 16 + r4 + r;
                float v = E1[(size_t)(bm + row) * H_DIM + col] + silu_f(acc[m][n][r]);
                st_split((char*)P0H, (char*)P0L, row, col, 256, v);
            }
    }
    __syncthreads();

    #define STAGE_PLAIN(SRC_H, SRC_L, WH, WL, BIAS, DST_H, DST_L, NWH, NWL)             \
    {                                                                                   \
        _Pragma("unroll")                                                               \
        for (int m = 0; m < 2; ++m)                                                     \
            _Pragma("unroll")                                                           \
            for (int n = 0; n < 4; ++n) acc[m][n] = f32x4{0.f, 0.f, 0.f, 0.f};          \
        mm128_pipe((char*)SRC_H, (char*)SRC_L, WH, WL, pre, NWH, NWL,                   \
                   wm, wn, l15, khalf, acc);                                            \
        _Pragma("unroll")                                                               \
        for (int n = 0; n < 4; ++n) {                                                   \
            int col = wn * 64 + n * 16 + l15;                                           \
            float bv = BIAS[col];                                                       \
            _Pragma("unroll")                                                           \
            for (int m = 0; m < 2; ++m)                                                 \
                _Pragma("unroll")                                                       \
                for (int r = 0; r < 4; ++r) {                                           \
                    int row = wm * 32 + m * 16 + r4 + r;                                \
                    st_split((char*)DST_H, (char*)DST_L, row, col, 256,                 \
                             silu_f(acc[m][n][r] + bv));                                \
                }                                                                       \
        }                                                                               \
        __syncthreads();                                                                \
    }

    #define STAGE_RES(SRC_H, SRC_L, WH, WL, BIAS, RES_H, RES_L, NWH, NWL)               \
    {                                                                                   \
        _Pragma("unroll")                                                               \
        for (int m = 0; m < 2; ++m)                                                     \
            _Pragma("unroll")                                                           \
            for (int n = 0; n < 4; ++n) acc[m][n] = f32x4{0.f, 0.f, 0.f, 0.f};          \
        mm128_pipe((char*)SRC_H, (char*)SRC_L, WH, WL, pre, NWH, NWL,                   \
                   wm, wn, l15, khalf, acc);                                            \
        _Pragma("unroll")                                                               \
        for (int n = 0; n < 4; ++n) {                                                   \
            int col = wn * 64 + n * 16 + l15;                                           \
            float bv = BIAS[col];                                                       \
            _Pragma("unroll")                                                           \
            for (int m = 0; m < 2; ++m)                                                 \
                _Pragma("unroll")                                                       \
                for (int r = 0; r < 4; ++r) {                                           \
                    int row = wm * 32 + m * 16 + r4 + r;                                \
                    float v = ld_split((char*)RES_H, (char*)RES_L, row, col, 256)       \
                            + silu_f(acc[m][n][r] + bv);                                \
                    st_split((char*)RES_H, (char*)RES_L, row, col, 256, v);             \
                }                                                                       \
        }                                                                               \
        __syncthreads();                                                                \
    }

    // S2..S3
    STAGE_PLAIN(P0H, P0L, p.b0h, p.b0l, p.bb0, P1H, P1L, p.b1h, p.b1l)
    STAGE_RES(P1H, P1L, p.b1h, p.b1l, p.bb1, P0H, P0L, p.lnh, p.lnl)

    // S4: x1 = silu(P0@Wlin+blin) + X -> P1 ; prefetch Wa0
    {
        #pragma unroll
        for (int m = 0; m < 2; ++m)
            #pragma unroll
            for (int n = 0; n < 4; ++n) acc[m][n] = f32x4{0.f, 0.f, 0.f, 0.f};
        mm128_pipe((char*)P0H, (char*)P0L, p.lnh, p.lnl, pre, p.a0h, p.a0l,
                   wm, wn, l15, khalf, acc);
        #pragma unroll
        for (int n = 0; n < 4; ++n) {
            int col = wn * 64 + n * 16 + l15;
            float bv = p.blin[col];
            #pragma unroll
            for (int m = 0; m < 2; ++m)
                #pragma unroll
                for (int r = 0; r < 4; ++r) {
                    int row = wm * 32 + m * 16 + r4 + r;
                    float v = silu_f(acc[m][n][r] + bv) + X[(size_t)(bm + row) * H_DIM + col];
                    st_split((char*)P1H, (char*)P1L, row, col, 256, v);
                }
        }
        __syncthreads();
    }

    STAGE_PLAIN(P1H, P1L, p.a0h, p.a0l, p.ba0, P0H, P0L, p.a1h, p.a1l)
    STAGE_RES(P0H, P0L, p.a1h, p.a1l, p.ba1, P1H, P1L, p.a2h, p.a2l)
    STAGE_PLAIN(P1H, P1L, p.a2h, p.a2l, p.ba2, P0H, P0L, p.a3h, p.a3l)

    // S8: OUT = P1 + silu(P0@Wa3+ba3)
    {
        #pragma unroll
        for (int m = 0; m < 2; ++m)
            #pragma unroll
            for (int n = 0; n < 4; ++n) acc[m][n] = f32x4{0.f, 0.f, 0.f, 0.f};
        mm128_pipe((char*)P0H, (char*)P0L, p.a3h, p.a3l, pre, nullptr, nullptr,
                   wm, wn, l15, khalf, acc);
        #pragma unroll
        for (int n = 0; n < 4; ++n) {
            int col = wn * 64 + n * 16 + l15;
            float bv = p.ba3[col];
            #pragma unroll
            for (int m = 0; m < 2; ++m)
                #pragma unroll
                for (int r = 0; r < 4; ++r) {
                    int row = wm * 32 + m * 16 + r4 + r;
                    float v = ld_split((char*)P1H, (char*)P1L, row, col, 256)
                            + silu_f(acc[m][n][r] + bv);
                    OUT[(size_t)(bm + row) * H_DIM + col] = v;
                }
        }
    }
    #undef STAGE_PLAIN
    #undef STAGE_RES
}

// ---------------------------------------------------------------------------
// out_chain (256 threads, 4 waves; 32 rows/block, wave covers 64 cols):
//   T = TN@Wo_up + bo_up ; T = silu(T@L0+b0); silu(T@L1+b1); silu(T@L2+b2)
//   P[n] += dot(T[n], Wo_out)
// ---------------------------------------------------------------------------
__global__ __launch_bounds__(256, 2) void out_chain(
    const float* __restrict__ TN,
    const u16* __restrict__ Uh, const u16* __restrict__ Ul, const float* __restrict__ bu,
    const u16* __restrict__ L0h, const u16* __restrict__ L0l, const float* __restrict__ b0,
    const u16* __restrict__ L1h, const u16* __restrict__ L1l, const float* __restrict__ b1,
    const u16* __restrict__ L2h, const u16* __restrict__ L2l, const float* __restrict__ b2,
    const float* __restrict__ Wo, float* __restrict__ P)
{
    __shared__ u16 XH[32 * 128], XL[32 * 128];
    __shared__ u16 T0H[32 * 256], T0L[32 * 256];
    __shared__ u16 T1H[32 * 256], T1L[32 * 256];

    const int tid  = threadIdx.x;
    const int lane = tid & 63;
    const int wn   = tid >> 6;      // 0..3, wave covers cols wn*64..+64
    const int bm   = blockIdx.x * 32;
    const int l15  = lane & 15;
    const int khalf = (lane >> 4) * 8;
    const int r4   = (lane >> 4) * 4;

    // stage TN tile [32][128] f32 -> split LDS (stride 256B)
    {
        int r  = tid >> 3;
        int c0 = (tid & 7) * 16;
        const float* p = &TN[(size_t)(bm + r) * H_DIM + c0];
        const int swz = (r & 7) << 4;
        #pragma unroll
        for (int q = 0; q < 4; ++q) {
            float4 f = *reinterpret_cast<const float4*>(p + q * 4);
            float vv[4] = {f.x, f.y, f.z, f.w};
            u16 h[4], l[4];
            #pragma unroll
            for (int j = 0; j < 4; ++j) {
                h[j] = f2bf(vv[j]);
                l[j] = f2bf(vv[j] - bf2f(h[j]));
            }
            int off = (r * 256 + c0 * 2 + q * 8) ^ swz;
            *reinterpret_cast<ushort4*>((char*)XH + off) = make_ushort4(h[0], h[1], h[2], h[3]);
            *reinterpret_cast<ushort4*>((char*)XL + off) = make_ushort4(l[0], l[1], l[2], l[3]);
        }
    }
    __syncthreads();

    f32x4 acc[2][4];

    // up: K=128, bias only -> T0
    {
        #pragma unroll
        for (int m = 0; m < 2; ++m)
            #pragma unroll
            for (int n = 0; n < 4; ++n) acc[m][n] = f32x4{0.f, 0.f, 0.f, 0.f};
        BF8x4 cur = loadB128f(Uh, Ul, 0, wn, l15, khalf);
        #pragma unroll
        for (int k = 0; k < 4; ++k) {
            BF8x4 nxt;
            if (k < 3) nxt = loadB128f(Uh, Ul, 32 * (k + 1), wn, l15, khalf);
            mfma_cluster((char*)XH, (char*)XL, 32 * k, 0, l15, khalf, cur, acc);
            if (k < 3) cur = nxt;
        }
        #pragma unroll
        for (int n = 0; n < 4; ++n) {
            int col = wn * 64 + n * 16 + l15;
            float bv = bu[col];
            #pragma unroll
            for (int m = 0; m < 2; ++m)
                #pragma unroll
                for (int r = 0; r < 4; ++r) {
                    int row = m * 16 + r4 + r;
                    st_split((char*)T0H, (char*)T0L, row, col, 512, acc[m][n][r] + bv);
                }
        }
        __syncthreads();
    }

    #define OLIN(SRC_H, SRC_L, WH, WL, BIAS, DST_H, DST_L)                              \
    {                                                                                   \
        _Pragma("unroll")                                                               \
        for (int m = 0; m < 2; ++m)                                                     \
            _Pragma("unroll")                                                           \
            for (int n = 0; n < 4; ++n) acc[m][n] = f32x4{0.f, 0.f, 0.f, 0.f};          \
        BF8x4 cur = loadB256f(WH, WL, 0, wn, l15, khalf);                               \
        _Pragma("unroll")                                                               \
        for (int k = 0; k < 8; ++k) {                                                   \
            BF8x4 nxt;                                                                  \
            if (k < 7) nxt = loadB256f(WH, WL, 32 * (k + 1), wn, l15, khalf);           \
            mfma_cluster512((char*)SRC_H, (char*)SRC_L, 32 * k, l15, khalf, cur, acc);  \
            if (k < 7) cur = nxt;                                                       \
        }                                                                               \
        _Pragma("unroll")                                                               \
        for (int n = 0; n < 4; ++n) {                                                   \
            int col = wn * 64 + n * 16 + l15;                                           \
            float bv = BIAS[col];                                                       \
            _Pragma("unroll")                                                           \
            for (int m = 0; m < 2; ++m)                                                 \
                _Pragma("unroll")                                                       \
                for (int r = 0; r < 4; ++r) {                                           \
                    int row = m * 16 + r4 + r;                                          \
                    st_split((char*)DST_H, (char*)DST_L, row, col, 512,                 \
                             silu_f(acc[m][n][r] + bv));                                \
                }                                                                       \
        }                                                                               \
        __syncthreads();                                                                \
    }

    OLIN(T0H, T0L, L0h, L0l, b0, T1H, T1L)
    OLIN(T1H, T1L, L1h, L1l, b1, T0H, T0L)
    OLIN(T0H, T0L, L2h, L2l, b2, T1H, T1L)
    #undef OLIN

    // final: P[bm+row] += dot(T1[row][:256], Wo[:256]); 8 threads per row
    {
        int row  = tid >> 3;
        int part = tid & 7;
        float s = 0.f;
        int cbase = part * 32;
        #pragma unroll
        for (int c = 0; c < 32; ++c)
            s = fmaf(ld_split((char*)T1H, (char*)T1L, row, cbase + c, 512), Wo[cbase + c], s);
        s += __shfl_xor(s, 1);
        s += __shfl_xor(s, 2);
        s += __shfl_xor(s, 4);
        if (part == 0) P[bm + row] += s;
    }
}

// rbf8[e][j] = rbf[e] @ W_rbf1[b]   [E,8]
__global__ __launch_bounds__(256) void rbf8_kernel(
    const float* __restrict__ rbf, const float* __restrict__ W1,
    float* __restrict__ r8, int Ecount)
{
    int e = blockIdx.x * blockDim.x + threadIdx.x;
    if (e >= Ecount) return;
    float rv[NRAD];
    #pragma unroll
    for (int k = 0; k < NRAD; ++k) rv[k] = rbf[(size_t)e * NRAD + k];
    float acc[BAS] = {};
    #pragma unroll
    for (int k = 0; k < NRAD; ++k)
        #pragma unroll
        for (int j = 0; j < BAS; ++j)
            acc[j] = fmaf(rv[k], W1[k * BAS + j], acc[j]);
    float4* o = reinterpret_cast<float4*>(&r8[(size_t)e * BAS]);
    o[0] = make_float4(acc[0], acc[1], acc[2], acc[3]);
    o[1] = make_float4(acc[4], acc[5], acc[6], acc[7]);
}

// ---------------------------------------------------------------------------
// CSR build kernels
// ---------------------------------------------------------------------------
__global__ __launch_bounds__(256) void csr_count(
    const int* __restrict__ idx, int* __restrict__ cnt, int n)
{
    int i = blockIdx.x * 256 + threadIdx.x;
    if (i < n) atomicAdd(&cnt[idx[i]], 1);
}

__global__ __launch_bounds__(256) void scan_block(
    const int* __restrict__ cnt, int* __restrict__ ptr, int* __restrict__ bsum, int n)
{
    __shared__ int s[256];
    int i = blockIdx.x * 256 + threadIdx.x;
    int v = (i < n) ? cnt[i] : 0;
    s[threadIdx.x] = v;
    __syncthreads();
    #pragma unroll
    for (int off = 1; off < 256; off <<= 1) {
        int t = (threadIdx.x >= off) ? s[threadIdx.x - off] : 0;
        __syncthreads();
        s[threadIdx.x] += t;
        __syncthreads();
    }
    if (i < n) ptr[i] = s[threadIdx.x] - v;   // exclusive
    if (threadIdx.x == 255) bsum[blockIdx.x] = s[255];
}

__global__ __launch_bounds__(1024) void scan_aux(int* __restrict__ bsum, int nb)
{
    __shared__ int s[1024];
    int v = (threadIdx.x < nb) ? bsum[threadIdx.x] : 0;
    s[threadIdx.x] = v;
    __syncthreads();
    #pragma unroll
    for (int off = 1; off < 1024; off <<= 1) {
        int t = (threadIdx.x >= off) ? s[threadIdx.x - off] : 0;
        __syncthreads();
        s[threadIdx.x] += t;
        __syncthreads();
    }
    if (threadIdx.x < nb) bsum[threadIdx.x] = s[threadIdx.x] - v;
}

__global__ __launch_bounds__(256) void scan_add(
    int* __restrict__ ptr, const int* __restrict__ bsum, int n)
{
    int i = blockIdx.x * 256 + threadIdx.x;
    if (i < n) ptr[i] += bsum[blockIdx.x];
}

__global__ __launch_bounds__(256) void csr_fill(
    const int* __restrict__ idx, int* __restrict__ cursor,
    int* __restrict__ perm, int n)
{
    int i = blockIdx.x * 256 + threadIdx.x;
    if (i >= n) return;
    int pos = atomicAdd(&cursor[idx[i]], 1);
    perm[pos] = i;
}

// ---------------------------------------------------------------------------
// One-time: permuted sbf basis for ALL blocks + permuted idx_kj.
// ---------------------------------------------------------------------------
__global__ __launch_bounds__(256) void permute_s8(
    const float* __restrict__ sbf, const float* __restrict__ W1all,
    const int* __restrict__ idx_kj, const int* __restrict__ tperm,
    u16* __restrict__ ps8, int* __restrict__ pkj, int Tcount)
{
    __shared__ float Ws[NB * SBF_D * BAS];
    for (int i = threadIdx.x; i < NB * SBF_D * BAS; i += 256) Ws[i] = W1all[i];
    __syncthreads();
    int i = blockIdx.x * 256 + threadIdx.x;
    if (i >= Tcount) return;
    int t = tperm[i];
    pkj[i] = idx_kj[t];
    float s[SBF_D];
    {
        const float2* p2 = reinterpret_cast<const float2*>(&sbf[(size_t)t * SBF_D]);
        #pragma unroll
        for (int k = 0; k < SBF_D / 2; ++k) {
            float2 v = p2[k];
            s[2 * k] = v.x; s[2 * k + 1] = v.y;
        }
    }
    #pragma unroll
    for (int b = 0; b < NB; ++b) {
        const float* Wb_ = &Ws[b * SBF_D * BAS];
        float acc[BAS] = {};
        for (int k = 0; k < SBF_D; ++k) {
            float sv = s[k];
            #pragma unroll
            for (int j = 0; j < BAS; ++j)
                acc[j] = fmaf(sv, Wb_[k * BAS + j], acc[j]);
        }
        ushort4 o0 = make_ushort4(f2bf(acc[0]), f2bf(acc[1]), f2bf(acc[2]), f2bf(acc[3]));
        ushort4 o1 = make_ushort4(f2bf(acc[4]), f2bf(acc[5]), f2bf(acc[6]), f2bf(acc[7]));
        u16* op = &ps8[((size_t)b * Tcount + i) * BAS];
        *reinterpret_cast<ushort4*>(op) = o0;
        *reinterpret_cast<ushort4*>(op + 4) = o1;
    }
}

// ---------------------------------------------------------------------------
// Triplet aggregation, permuted sequential stream
// ---------------------------------------------------------------------------
__device__ __forceinline__ float dot8_bf(uint4 r, const float* w2) {
    float s;
    s  = bf2f((u16)(r.x)) * w2[0] + bf2f((u16)(r.x >> 16)) * w2[1];
    s += bf2f((u16)(r.y)) * w2[2] + bf2f((u16)(r.y >> 16)) * w2[3];
    s += bf2f((u16)(r.z)) * w2[4] + bf2f((u16)(r.z >> 16)) * w2[5];
    s += bf2f((u16)(r.w)) * w2[6] + bf2f((u16)(r.w >> 16)) * w2[7];
    return s;
}

__global__ __launch_bounds__(256) void triplet_gather2(
    const u16* __restrict__ ps8b, const float* __restrict__ Wsb2,
    const float* __restrict__ xkj, const int* __restrict__ pkj,
    const int* __restrict__ tptr, const int* __restrict__ tcnt,
    float* __restrict__ agg, int Ecount)
{
    const int lane = threadIdx.x & 63;
    int wid = (blockIdx.x * blockDim.x + threadIdx.x) >> 6;
    const int nw = (gridDim.x * blockDim.x) >> 6;
    float w2[BAS];
    #pragma unroll
    for (int j = 0; j < BAS; ++j) w2[j] = Wsb2[j * INT_DIM + lane];

    for (int e = wid; e < Ecount; e += nw) {
        int start = tptr[e];
        int end   = start + tcnt[e];
        float acc0 = 0.f, acc1 = 0.f;
        int i = start;
        for (; i + 1 < end; i += 2) {
            uint4 ra = *reinterpret_cast<const uint4*>(&ps8b[(size_t)i * BAS]);
            uint4 rb = *reinterpret_cast<const uint4*>(&ps8b[(size_t)(i + 1) * BAS]);
            int e0 = pkj[i], e1 = pkj[i + 1];
            float s0 = dot8_bf(ra, w2);
            float s1 = dot8_bf(rb, w2);
            acc0 = fmaf(xkj[(size_t)e0 * INT_DIM + lane], s0, acc0);
            acc1 = fmaf(xkj[(size_t)e1 * INT_DIM + lane], s1, acc1);
        }
        if (i < end) {
            uint4 ra = *reinterpret_cast<const uint4*>(&ps8b[(size_t)i * BAS]);
            int e0 = pkj[i];
            acc0 = fmaf(xkj[(size_t)e0 * INT_DIM + lane], dot8_bf(ra, w2), acc0);
        }
        agg[(size_t)e * INT_DIM + lane] = acc0 + acc1;
    }
}

// ---------------------------------------------------------------------------
// Output-block node gather
// ---------------------------------------------------------------------------
__global__ __launch_bounds__(256) void out_gather(
    const float* __restrict__ rbf, const float* __restrict__ Wor,
    const float* __restrict__ x,
    const int* __restrict__ eptr, const int* __restrict__ ecnt,
    const int* __restrict__ eperm, float* __restrict__ tN, int Nn)
{
    const int lane = threadIdx.x & 63;
    int wid = (blockIdx.x * blockDim.x + threadIdx.x) >> 6;
    const int nw = (gridDim.x * blockDim.x) >> 6;
    float wr0[NRAD], wr1[NRAD];
    #pragma unroll
    for (int k = 0; k < NRAD; ++k) {
        wr0[k] = Wor[k * H_DIM + lane];
        wr1[k] = Wor[k * H_DIM + lane + 64];
    }
    for (int n = wid; n < Nn; n += nw) {
        int start = eptr[n];
        int end   = start + ecnt[n];
        float a0 = 0.f, a1 = 0.f;
        for (int i = start; i < end; ++i) {
            int e = eperm[i];
            const float2* rp = reinterpret_cast<const float2*>(&rbf[(size_t)e * NRAD]);
            float2 r0 = rp[0], r1 = rp[1], r2 = rp[2];
            float rA = r0.x*wr0[0] + r0.y*wr0[1] + r1.x*wr0[2]
                     + r1.y*wr0[3] + r2.x*wr0[4] + r2.y*wr0[5];
            float rB = r0.x*wr1[0] + r0.y*wr1[1] + r1.x*wr1[2]
                     + r1.y*wr1[3] + r2.x*wr1[4] + r2.y*wr1[5];
            a0 = fmaf(rA, x[(size_t)e * H_DIM + lane], a0);
            a1 = fmaf(rB, x[(size_t)e * H_DIM + lane + 64], a1);
        }
        tN[(size_t)n * H_DIM + lane] = a0;
        tN[(size_t)n * H_DIM + lane + 64] = a1;
    }
}

// ---------------------------------------------------------------------------
extern "C" void kernel_launch(void* const* d_in, const int* in_sizes, int n_in,
                              void* d_out, int out_size, void* d_ws, size_t ws_size,
                              hipStream_t stream)
{
    const float* x_in    = (const float*)d_in[0];
    const float* rbf     = (const float*)d_in[1];
    const float* sbf     = (const float*)d_in[2];
    const float* W_rbf1  = (const float*)d_in[3];
    const float* W_rbf2  = (const float*)d_in[4];
    const float* W_sbf1  = (const float*)d_in[5];
    const float* W_sbf2  = (const float*)d_in[6];
    const float* W_kj    = (const float*)d_in[7];
    const float* b_kj    = (const float*)d_in[8];
    const float* W_ji    = (const float*)d_in[9];
    const float* b_ji    = (const float*)d_in[10];
    const float* W_down  = (const float*)d_in[11];
    const float* W_up    = (const float*)d_in[12];
    const float* Wb      = (const float*)d_in[13];
    const float* bb      = (const float*)d_in[14];
    const float* Wa      = (const float*)d_in[15];
    const float* ba      = (const float*)d_in[16];
    const float* W_lin   = (const float*)d_in[17];
    const float* b_lin   = (const float*)d_in[18];
    const float* Wo_rbf  = (const float*)d_in[19];
    const float* Wo_up   = (const float*)d_in[20];
    const float* bo_up   = (const float*)d_in[21];
    const float* Wo_lins = (const float*)d_in[22];
    const float* bo_lins = (const float*)d_in[23];
    const float* Wo_out  = (const float*)d_in[24];
    const int*   idx_kj  = (const int*)d_in[25];
    const int*   idx_ji  = (const int*)d_in[26];
    const int*   idx_i   = (const int*)d_in[27];

    // workspace carve-up
    char* ws = (char*)d_ws;
    size_t off = 0;
    auto alloc = [&](size_t bytes) -> void* {
        void* p = (void*)(ws + off);
        off += (bytes + 255) & ~(size_t)255;
        return p;
    };
    float* XA = (float*)alloc((size_t)E_EDGES * H_DIM * 4);
    float* XB = (float*)alloc((size_t)E_EDGES * H_DIM * 4);
    float* E1 = (float*)alloc((size_t)E_EDGES * H_DIM * 4);
    float* C1 = (float*)alloc((size_t)E_EDGES * INT_DIM * 4);
    float* C2 = (float*)alloc((size_t)E_EDGES * INT_DIM * 4);
    float* R8 = (float*)alloc((size_t)E_EDGES * BAS * 4);
    float* TN = (float*)alloc((size_t)N_NODES * H_DIM * 4);
    // split-bf16 transposed weights
    u16* HKJ = (u16*)alloc(4  * 16384 * 2); u16* LKJ = (u16*)alloc(4  * 16384 * 2);
    u16* HJI = (u16*)alloc(4  * 16384 * 2); u16* LJI = (u16*)alloc(4  * 16384 * 2);
    u16* HDN = (u16*)alloc(4  * 8192  * 2); u16* LDN = (u16*)alloc(4  * 8192  * 2);
    u16* HUP = (u16*)alloc(4  * 8192  * 2); u16* LUP = (u16*)alloc(4  * 8192  * 2);
    u16* HWB = (u16*)alloc(8  * 16384 * 2); u16* LWB = (u16*)alloc(8  * 16384 * 2);
    u16* HWA = (u16*)alloc(16 * 16384 * 2); u16* LWA = (u16*)alloc(16 * 16384 * 2);
    u16* HLN = (u16*)alloc(4  * 16384 * 2); u16* LLN = (u16*)alloc(4  * 16384 * 2);
    u16* HOU = (u16*)alloc(5  * 32768 * 2); u16* LOU = (u16*)alloc(5  * 32768 * 2);
    u16* HOL = (u16*)alloc(15 * 65536 * 2); u16* LOL = (u16*)alloc(15 * 65536 * 2);
    // CSR structures
    int* tcnt  = (int*)alloc((size_t)E_EDGES * 4);
    int* tptr  = (int*)alloc((size_t)E_EDGES * 4);
    int* tcur  = (int*)alloc((size_t)E_EDGES * 4);
    int* tperm = (int*)alloc((size_t)T_TRIP * 4);
    int* tbsum = (int*)alloc(1024 * 4);
    int* ecnt  = (int*)alloc((size_t)N_NODES * 4);
    int* eptr  = (int*)alloc((size_t)N_NODES * 4);
    int* ecur  = (int*)alloc((size_t)N_NODES * 4);
    int* eperm = (int*)alloc((size_t)E_EDGES * 4);
    int* ebsum = (int*)alloc(1024 * 4);
    // permuted triplet stream
    u16* PS8 = (u16*)alloc((size_t)NB * T_TRIP * BAS * 2);
    int* PKJ = (int*)alloc((size_t)T_TRIP * 4);
    (void)ws_size;

    auto prep = [&](const float* src, u16* hi, u16* lo, int K, int N, int cnt) {
        dim3 g((K * N + 255) / 256, cnt);
        hipLaunchKernelGGL(wprep, g, dim3(256), 0, stream, src, hi, lo, K, N);
    };
    prep(W_kj,    HKJ, LKJ, 128, 128, 4);
    prep(W_ji,    HJI, LJI, 128, 128, 4);
    prep(W_down,  HDN, LDN, 128, 64,  4);
    prep(W_up,    HUP, LUP, 64,  128, 4);
    prep(Wb,      HWB, LWB, 128, 128, 8);
    prep(Wa,      HWA, LWA, 128, 128, 16);
    prep(W_lin,   HLN, LLN, 128, 128, 4);
    prep(Wo_up,   HOU, LOU, 128, 256, 5);
    prep(Wo_lins, HOL, LOL, 256, 256, 15);

    // ---- build triplet CSR (idx_ji: T entries -> E buckets)
    {
        const int nbT = (E_EDGES + 255) / 256;
        hipMemsetAsync(tcnt, 0, (size_t)E_EDGES * 4, stream);
        hipLaunchKernelGGL(csr_count, dim3((T_TRIP + 255) / 256), dim3(256), 0, stream,
                           idx_ji, tcnt, T_TRIP);
        hipLaunchKernelGGL(scan_block, dim3(nbT), dim3(256), 0, stream, tcnt, tptr, tbsum, E_EDGES);
        hipLaunchKernelGGL(scan_aux, dim3(1), dim3(1024), 0, stream, tbsum, nbT);
        hipLaunchKernelGGL(scan_add, dim3(nbT), dim3(256), 0, stream, tptr, tbsum, E_EDGES);
        hipMemcpyAsync(tcur, tptr, (size_t)E_EDGES * 4, hipMemcpyDeviceToDevice, stream);
        hipLaunchKernelGGL(csr_fill, dim3((T_TRIP + 255) / 256), dim3(256), 0, stream,
                           idx_ji, tcur, tperm, T_TRIP);
    }
    // ---- build node CSR (idx_i: E entries -> N buckets)
    {
        const int nbN = (N_NODES + 255) / 256;
        hipMemsetAsync(ecnt, 0, (size_t)N_NODES * 4, stream);
        hipLaunchKernelGGL(csr_count, dim3((E_EDGES + 255) / 256), dim3(256), 0, stream,
                           idx_i, ecnt, E_EDGES);
        hipLaunchKernelGGL(scan_block, dim3(nbN), dim3(256), 0, stream, ecnt, eptr, ebsum, N_NODES);
        hipLaunchKernelGGL(scan_aux, dim3(1), dim3(1024), 0, stream, ebsum, nbN);
        hipLaunchKernelGGL(scan_add, dim3(nbN), dim3(256), 0, stream, eptr, ebsum, N_NODES);
        hipMemcpyAsync(ecur, eptr, (size_t)N_NODES * 4, hipMemcpyDeviceToDevice, stream);
        hipLaunchKernelGGL(csr_fill, dim3((E_EDGES + 255) / 256), dim3(256), 0, stream,
                           idx_i, ecur, eperm, E_EDGES);
    }
    // ---- one-time permuted sbf basis for all blocks
    hipLaunchKernelGGL(permute_s8, dim3((T_TRIP + 255) / 256), dim3(256), 0, stream,
                       sbf, W_sbf1, idx_kj, tperm, PS8, PKJ, T_TRIP);

    float* P = (float*)d_out;
    hipMemsetAsync(P, 0, (size_t)N_NODES * sizeof(float), stream);

    auto out_block = [&](int ob, const float* xcur) {
        hipLaunchKernelGGL(out_gather, dim3(2048), dim3(256), 0, stream,
                           rbf, Wo_rbf + (size_t)ob * NRAD * H_DIM, xcur,
                           eptr, ecnt, eperm, TN, N_NODES);
        hipLaunchKernelGGL(out_chain, dim3(N_NODES / 32), dim3(256), 0, stream,
                           TN,
                           HOU + (size_t)ob * 32768, LOU + (size_t)ob * 32768,
                           bo_up + (size_t)ob * OUT_EMB,
                           HOL + (size_t)(ob * 3 + 0) * 65536, LOL + (size_t)(ob * 3 + 0) * 65536,
                           bo_lins + (size_t)(ob * 3 + 0) * OUT_EMB,
                           HOL + (size_t)(ob * 3 + 1) * 65536, LOL + (size_t)(ob * 3 + 1) * 65536,
                           bo_lins + (size_t)(ob * 3 + 1) * OUT_EMB,
                           HOL + (size_t)(ob * 3 + 2) * 65536, LOL + (size_t)(ob * 3 + 2) * 65536,
                           bo_lins + (size_t)(ob * 3 + 2) * OUT_EMB,
                           Wo_out + (size_t)ob * OUT_EMB, P);
    };

    out_block(0, x_in);

    const float* xcur = x_in;
    const int EB = E_EDGES / 64;  // 3125
    for (int b = 0; b < NB; ++b) {
        float* xnext = (b % 2 == 0) ? XB : XA;
        hipLaunchKernelGGL(rbf8_kernel, dim3((E_EDGES + 255) / 256), dim3(256), 0, stream,
                           rbf, W_rbf1 + (size_t)b * NRAD * BAS, R8, E_EDGES);
        // fused: E1 = silu(x@Wji+bji); C1 = silu((silu(x@Wkj+bkj)*gate)@Wdn)
        hipLaunchKernelGGL(pre_fuse, dim3(EB), dim3(256), 0, stream,
                           xcur, R8,
                           HJI + (size_t)b * 16384, LJI + (size_t)b * 16384, b_ji + (size_t)b * H_DIM,
                           HKJ + (size_t)b * 16384, LKJ + (size_t)b * 16384, b_kj + (size_t)b * H_DIM,
                           W_rbf2 + (size_t)b * BAS * H_DIM,
                           HDN + (size_t)b * 8192, LDN + (size_t)b * 8192,
                           E1, C1);
        // triplet aggregation (permuted stream, atomic-free)
        hipLaunchKernelGGL(triplet_gather2, dim3(2048), dim3(256), 0, stream,
                           PS8 + (size_t)b * T_TRIP * BAS, W_sbf2 + (size_t)b * BAS * INT_DIM,
                           C1, PKJ, tptr, tcnt, C2, E_EDGES);
        // fused chain: UP + pair(Wb) + LIN + pair(Wa0/1) + pair(Wa2/3)
        ChainP cp;
        cp.uph = HUP + (size_t)b * 8192;  cp.upl = LUP + (size_t)b * 8192;
        cp.b0h = HWB + (size_t)(b * 2 + 0) * 16384; cp.b0l = LWB + (size_t)(b * 2 + 0) * 16384;
        cp.b1h = HWB + (size_t)(b * 2 + 1) * 16384; cp.b1l = LWB + (size_t)(b * 2 + 1) * 16384;
        cp.lnh = HLN + (size_t)b * 16384; cp.lnl = LLN + (size_t)b * 16384;
        cp.a0h = HWA + (size_t)(b * 4 + 0) * 16384; cp.a0l = LWA + (size_t)(b * 4 + 0) * 16384;
        cp.a1h = HWA + (size_t)(b * 4 + 1) * 16384; cp.a1l = LWA + (size_t)(b * 4 + 1) * 16384;
        cp.a2h = HWA + (size_t)(b * 4 + 2) * 16384; cp.a2l = LWA + (size_t)(b * 4 + 2) * 16384;
        cp.a3h = HWA + (size_t)(b * 4 + 3) * 16384; cp.a3l = LWA + (size_t)(b * 4 + 3) * 16384;
        cp.bb0 = bb + (size_t)(b * 2 + 0) * H_DIM;
        cp.bb1 = bb + (size_t)(b * 2 + 1) * H_DIM;
        cp.blin = b_lin + (size_t)b * H_DIM;
        cp.ba0 = ba + (size_t)(b * 4 + 0) * H_DIM;
        cp.ba1 = ba + (size_t)(b * 4 + 1) * H_DIM;
        cp.ba2 = ba + (size_t)(b * 4 + 2) * H_DIM;
        cp.ba3 = ba + (size_t)(b * 4 + 3) * H_DIM;
        hipLaunchKernelGGL(post_chain, dim3(EB), dim3(256), 0, stream,
                           C2, E1, xcur, cp, xnext);
        xcur = xnext;
        out_block(b + 1, xcur);
    }
}

// Round 9
// 4372.363 us; speedup vs baseline: 1.3901x; 1.0150x over previous
//
#include <hip/hip_runtime.h>
#include <hip/hip_bf16.h>

// Problem constants (fixed by the reference)
#define E_EDGES 200000
#define T_TRIP  2000000
#define N_NODES 20000
#define H_DIM   128
#define INT_DIM 64
#define BAS     8
#define OUT_EMB 256
#define NRAD    6
#define SBF_D   42
#define NB      4

typedef __attribute__((ext_vector_type(8))) __bf16 bf16x8;
typedef __attribute__((ext_vector_type(4))) float f32x4;
typedef unsigned short u16;

__device__ __forceinline__ float silu_f(float v) { return v / (1.0f + __expf(-v)); }

__device__ __forceinline__ u16 f2bf(float f) {
    unsigned int u = __float_as_uint(f);
    u += 0x7FFF + ((u >> 16) & 1);   // RNE
    return (u16)(u >> 16);
}
__device__ __forceinline__ float bf2f(u16 h) {
    return __uint_as_float(((unsigned int)h) << 16);
}

// Vectorized split-bf16 LDS helpers: 4 consecutive columns per access.
// col0 must be a multiple of 4; swizzle XOR flips bit4 (16B) -> 8B blocks stay intact.
__device__ __forceinline__ void st_split4(char* H, char* L, int row, int col0, int stride,
                                          const float v[4]) {
    ushort4 hh, ll;
    u16 h0 = f2bf(v[0]); ll.x = f2bf(v[0] - bf2f(h0)); hh.x = h0;
    u16 h1 = f2bf(v[1]); ll.y = f2bf(v[1] - bf2f(h1)); hh.y = h1;
    u16 h2 = f2bf(v[2]); ll.z = f2bf(v[2] - bf2f(h2)); hh.z = h2;
    u16 h3 = f2bf(v[3]); ll.w = f2bf(v[3] - bf2f(h3)); hh.w = h3;
    int off = (row * stride + col0 * 2) ^ ((row & 7) << 4);
    *reinterpret_cast<ushort4*>(H + off) = hh;
    *reinterpret_cast<ushort4*>(L + off) = ll;
}
__device__ __forceinline__ void ld_split4(const char* H, const char* L, int row, int col0,
                                          int stride, float v[4]) {
    int off = (row * stride + col0 * 2) ^ ((row & 7) << 4);
    ushort4 hh = *reinterpret_cast<const ushort4*>(H + off);
    ushort4 ll = *reinterpret_cast<const ushort4*>(L + off);
    v[0] = bf2f(hh.x) + bf2f(ll.x);
    v[1] = bf2f(hh.y) + bf2f(ll.y);
    v[2] = bf2f(hh.z) + bf2f(ll.z);
    v[3] = bf2f(hh.w) + bf2f(ll.w);
}

// ---- B-fragment register block: 4 n-tiles (hi+lo) ----
struct BF8x4 { bf16x8 h[4]; bf16x8 l[4]; };

__device__ __forceinline__ BF8x4 loadB128f(const u16* __restrict__ Bh, const u16* __restrict__ Bl,
                                           int k0, int wn, int l15, int khalf)
{
    BF8x4 f;
    #pragma unroll
    for (int n = 0; n < 4; ++n) {
        size_t bo = (size_t)(wn * 64 + n * 16 + l15) * 128 + k0 + khalf;
        f.h[n] = *reinterpret_cast<const bf16x8*>(Bh + bo);
        f.l[n] = *reinterpret_cast<const bf16x8*>(Bl + bo);
    }
    return f;
}
__device__ __forceinline__ BF8x4 loadB64f(const u16* __restrict__ Bh, const u16* __restrict__ Bl,
                                          int k0, int wn, int l15, int khalf)
{
    BF8x4 f;
    #pragma unroll
    for (int n = 0; n < 4; ++n) {
        size_t bo = (size_t)(wn * 64 + n * 16 + l15) * 64 + k0 + khalf;
        f.h[n] = *reinterpret_cast<const bf16x8*>(Bh + bo);
        f.l[n] = *reinterpret_cast<const bf16x8*>(Bl + bo);
    }
    return f;
}
__device__ __forceinline__ BF8x4 loadB256f(const u16* __restrict__ Bh, const u16* __restrict__ Bl,
                                           int k0, int wn, int l15, int khalf)
{
    BF8x4 f;
    #pragma unroll
    for (int n = 0; n < 4; ++n) {
        size_t bo = (size_t)(wn * 64 + n * 16 + l15) * 256 + k0 + khalf;
        f.h[n] = *reinterpret_cast<const bf16x8*>(Bh + bo);
        f.l[n] = *reinterpret_cast<const bf16x8*>(Bl + bo);
    }
    return f;
}

// SWAPPED-OPERAND clusters: mfma(W, A) computes (A·W)^T per 16x16 tile ->
// lane holds output row = l15, cols = (lane>>4)*4 + reg (4 consecutive).
// Products/accumulation order identical to unswapped; bit-identical results.
__device__ __forceinline__ void mfma_cluster(
    const char* AH, const char* AL, int k0, int wm, int l15, int khalf,
    const BF8x4& b, f32x4 acc[2][4])
{
    __builtin_amdgcn_s_setprio(1);
    #pragma unroll
    for (int m = 0; m < 2; ++m) {
        int row = wm * 32 + m * 16 + l15;
        int off = (row * 256 + (k0 + khalf) * 2) ^ ((row & 7) << 4);
        bf16x8 ah = *reinterpret_cast<const bf16x8*>(AH + off);
        bf16x8 al = *reinterpret_cast<const bf16x8*>(AL + off);
        #pragma unroll
        for (int n = 0; n < 4; ++n) {
            acc[m][n] = __builtin_amdgcn_mfma_f32_16x16x32_bf16(b.h[n], ah, acc[m][n], 0, 0, 0);
            acc[m][n] = __builtin_amdgcn_mfma_f32_16x16x32_bf16(b.h[n], al, acc[m][n], 0, 0, 0);
            acc[m][n] = __builtin_amdgcn_mfma_f32_16x16x32_bf16(b.l[n], ah, acc[m][n], 0, 0, 0);
        }
    }
    __builtin_amdgcn_s_setprio(0);
}
__device__ __forceinline__ void mfma_cluster64(
    const char* AH, const char* AL, int k0, int wm, int l15, int khalf,
    const BF8x4& b, f32x4 acc[2][4])
{
    __builtin_amdgcn_s_setprio(1);
    #pragma unroll
    for (int m = 0; m < 2; ++m) {
        int row = wm * 32 + m * 16 + l15;
        int off = (row * 128 + (k0 + khalf) * 2) ^ ((row & 7) << 4);
        bf16x8 ah = *reinterpret_cast<const bf16x8*>(AH + off);
        bf16x8 al = *reinterpret_cast<const bf16x8*>(AL + off);
        #pragma unroll
        for (int n = 0; n < 4; ++n) {
            acc[m][n] = __builtin_amdgcn_mfma_f32_16x16x32_bf16(b.h[n], ah, acc[m][n], 0, 0, 0);
            acc[m][n] = __builtin_amdgcn_mfma_f32_16x16x32_bf16(b.h[n], al, acc[m][n], 0, 0, 0);
            acc[m][n] = __builtin_amdgcn_mfma_f32_16x16x32_bf16(b.l[n], ah, acc[m][n], 0, 0, 0);
        }
    }
    __builtin_amdgcn_s_setprio(0);
}
// A from LDS [32][256] split (stride 512B), rows 0..31
__device__ __forceinline__ void mfma_cluster512(
    const char* AH, const char* AL, int k0, int l15, int khalf,
    const BF8x4& b, f32x4 acc[2][4])
{
    __builtin_amdgcn_s_setprio(1);
    #pragma unroll
    for (int m = 0; m < 2; ++m) {
        int row = m * 16 + l15;
        int off = (row * 512 + (k0 + khalf) * 2) ^ ((row & 7) << 4);
        bf16x8 ah = *reinterpret_cast<const bf16x8*>(AH + off);
        bf16x8 al = *reinterpret_cast<const bf16x8*>(AL + off);
        #pragma unroll
        for (int n = 0; n < 4; ++n) {
            acc[m][n] = __builtin_amdgcn_mfma_f32_16x16x32_bf16(b.h[n], ah, acc[m][n], 0, 0, 0);
            acc[m][n] = __builtin_amdgcn_mfma_f32_16x16x32_bf16(b.h[n], al, acc[m][n], 0, 0, 0);
            acc[m][n] = __builtin_amdgcn_mfma_f32_16x16x32_bf16(b.l[n], ah, acc[m][n], 0, 0, 0);
        }
    }
    __builtin_amdgcn_s_setprio(0);
}

// Pipelined K=128 GEMM: `pre` holds this stage's k0=0 frag; on exit `pre`
// holds NEXT stage's k0=0 frag.
__device__ __forceinline__ void mm128_pipe(
    const char* AH, const char* AL,
    const u16* __restrict__ Bh, const u16* __restrict__ Bl, BF8x4& pre,
    const u16* __restrict__ nBh, const u16* __restrict__ nBl,
    int wm, int wn, int l15, int khalf, f32x4 acc[2][4])
{
    BF8x4 c0 = pre;
    BF8x4 c1 = loadB128f(Bh, Bl, 32, wn, l15, khalf);
    mfma_cluster(AH, AL, 0, wm, l15, khalf, c0, acc);
    BF8x4 c2 = loadB128f(Bh, Bl, 64, wn, l15, khalf);
    mfma_cluster(AH, AL, 32, wm, l15, khalf, c1, acc);
    BF8x4 c3 = loadB128f(Bh, Bl, 96, wn, l15, khalf);
    mfma_cluster(AH, AL, 64, wm, l15, khalf, c2, acc);
    if (nBh) pre = loadB128f(nBh, nBl, 0, wn, l15, khalf);
    mfma_cluster(AH, AL, 96, wm, l15, khalf, c3, acc);
}
__device__ __forceinline__ void mm64_pipe(
    const char* AH, const char* AL,
    const u16* __restrict__ Bh, const u16* __restrict__ Bl, BF8x4& pre,
    const u16* __restrict__ nBh, const u16* __restrict__ nBl,
    int wm, int wn, int l15, int khalf, f32x4 acc[2][4])
{
    BF8x4 c0 = pre;
    BF8x4 c1 = loadB64f(Bh, Bl, 32, wn, l15, khalf);
    mfma_cluster64(AH, AL, 0, wm, l15, khalf, c0, acc);
    if (nBh) pre = loadB128f(nBh, nBl, 0, wn, l15, khalf);
    mfma_cluster64(AH, AL, 32, wm, l15, khalf, c1, acc);
}

// ---------------------------------------------------------------------------
// Weight prep: src [cnt][K][N] f32 row-major -> hi/lo [cnt][N][K] split-bf16
// ---------------------------------------------------------------------------
__global__ __launch_bounds__(256) void wprep(
    const float* __restrict__ src, u16* __restrict__ hi,
    u16* __restrict__ lo, int K, int N)
{
    int e = blockIdx.x * 256 + threadIdx.x;
    int total = K * N;
    if (e >= total) return;
    size_t base = (size_t)blockIdx.y * total;
    float a = src[base + e];
    int k = e / N, n = e - k * N;
    u16 h = f2bf(a);
    u16 l = f2bf(a - bf2f(h));
    hi[base + (size_t)n * K + k] = h;
    lo[base + (size_t)n * K + k] = l;
}

// ---------------------------------------------------------------------------
// pre_fuse (256 threads, 4 waves, wave tile 32x64), swapped layout epilogues
// ---------------------------------------------------------------------------
__global__ __launch_bounds__(256, 2) void pre_fuse(
    const float* __restrict__ X, const float* __restrict__ R8,
    const u16* __restrict__ Wjih, const u16* __restrict__ Wjil, const float* __restrict__ bji,
    const u16* __restrict__ Wkjh, const u16* __restrict__ Wkjl, const float* __restrict__ bkj,
    const float* __restrict__ Wr2,
    const u16* __restrict__ Wdnh, const u16* __restrict__ Wdnl,
    float* __restrict__ E1, float* __restrict__ C1)
{
    __shared__ u16 XH[64 * 128], XL[64 * 128];
    __shared__ u16 IH[64 * 128], IL[64 * 128];

    const int tid  = threadIdx.x;
    const int lane = tid & 63;
    const int w    = tid >> 6;
    const int wm   = w >> 1, wn = w & 1;
    const int bm   = blockIdx.x * 64;
    const int l15  = lane & 15;
    const int khalf = (lane >> 4) * 8;
    const int r4   = (lane >> 4) * 4;

    BF8x4 pre = loadB128f(Wjih, Wjil, 0, wn, l15, khalf);

    // stage X [64][128]
    {
        int r  = tid >> 2;
        int c0 = (tid & 3) * 32;
        const float* p = &X[(size_t)(bm + r) * H_DIM + c0];
        const int swz = (r & 7) << 4;
        #pragma unroll
        for (int q = 0; q < 8; ++q) {
            float4 f = *reinterpret_cast<const float4*>(p + q * 4);
            float vv[4] = {f.x, f.y, f.z, f.w};
            u16 h[4], l[4];
            #pragma unroll
            for (int j = 0; j < 4; ++j) {
                h[j] = f2bf(vv[j]);
                l[j] = f2bf(vv[j] - bf2f(h[j]));
            }
            int off = (r * 256 + c0 * 2 + q * 8) ^ swz;
            *reinterpret_cast<ushort4*>((char*)XH + off) = make_ushort4(h[0], h[1], h[2], h[3]);
            *reinterpret_cast<ushort4*>((char*)XL + off) = make_ushort4(l[0], l[1], l[2], l[3]);
        }
    }
    __syncthreads();

    // JI -> E1  (prefetches KJ k0=0 into pre)
    {
        f32x4 acc[2][4] = {};
        mm128_pipe((char*)XH, (char*)XL, Wjih, Wjil, pre, Wkjh, Wkjl,
                   wm, wn, l15, khalf, acc);
        #pragma unroll
        for (int n = 0; n < 4; ++n) {
            int col0 = wn * 64 + n * 16 + r4;
            float4 bv = *reinterpret_cast<const float4*>(&bji[col0]);
            #pragma unroll
            for (int m = 0; m < 2; ++m) {
                int row = wm * 32 + m * 16 + l15;
                float4 o;
                o.x = silu_f(acc[m][n][0] + bv.x);
                o.y = silu_f(acc[m][n][1] + bv.y);
                o.z = silu_f(acc[m][n][2] + bv.z);
                o.w = silu_f(acc[m][n][3] + bv.w);
                *reinterpret_cast<float4*>(&E1[(size_t)(bm + row) * H_DIM + col0]) = o;
            }
        }
    }
    // KJ * gate -> I (LDS)
    {
        f32x4 acc[2][4] = {};
        mm128_pipe((char*)XH, (char*)XL, Wkjh, Wkjl, pre, nullptr, nullptr,
                   wm, wn, l15, khalf, acc);
        // hoist R8 rows (one per m-block)
        float r8v[2][8];
        #pragma unroll
        for (int m = 0; m < 2; ++m) {
            int grow = bm + wm * 32 + m * 16 + l15;
            const float4* rp = reinterpret_cast<const float4*>(&R8[(size_t)grow * 8]);
            float4 a = rp[0], b2 = rp[1];
            r8v[m][0] = a.x;  r8v[m][1] = a.y;  r8v[m][2] = a.z;  r8v[m][3] = a.w;
            r8v[m][4] = b2.x; r8v[m][5] = b2.y; r8v[m][6] = b2.z; r8v[m][7] = b2.w;
        }
        #pragma unroll
        for (int n = 0; n < 4; ++n) {
            int col0 = wn * 64 + n * 16 + r4;
            float4 bvf = *reinterpret_cast<const float4*>(&bkj[col0]);
            float bv[4] = {bvf.x, bvf.y, bvf.z, bvf.w};
            float wrv[8][4];
            #pragma unroll
            for (int j = 0; j < 8; ++j) {
                float4 wf = *reinterpret_cast<const float4*>(&Wr2[j * H_DIM + col0]);
                wrv[j][0] = wf.x; wrv[j][1] = wf.y; wrv[j][2] = wf.z; wrv[j][3] = wf.w;
            }
            #pragma unroll
            for (int m = 0; m < 2; ++m) {
                int row = wm * 32 + m * 16 + l15;
                float v[4];
                #pragma unroll
                for (int r = 0; r < 4; ++r) {
                    float t = silu_f(acc[m][n][r] + bv[r]);
                    float g = 0.f;
                    #pragma unroll
                    for (int j = 0; j < 8; ++j)
                        g = fmaf(r8v[m][j], wrv[j][r], g);
                    v[r] = t * g;
                }
                st_split4((char*)IH, (char*)IL, row, col0, 256, v);
            }
        }
    }
    __syncthreads();

    // DOWN (N=64) -> C1
    {
        f32x4 acc[2][2] = {};
        #pragma unroll
        for (int k0 = 0; k0 < 128; k0 += 32) {
            bf16x8 bh[2], bl[2];
            #pragma unroll
            for (int n = 0; n < 2; ++n) {
                size_t bo = (size_t)(wn * 32 + n * 16 + l15) * 128 + k0 + khalf;
                bh[n] = *reinterpret_cast<const bf16x8*>(Wdnh + bo);
                bl[n] = *reinterpret_cast<const bf16x8*>(Wdnl + bo);
            }
            __builtin_amdgcn_s_setprio(1);
            #pragma unroll
            for (int m = 0; m < 2; ++m) {
                int row = wm * 32 + m * 16 + l15;
                int off = (row * 256 + (k0 + khalf) * 2) ^ ((row & 7) << 4);
                bf16x8 ah = *reinterpret_cast<const bf16x8*>((const char*)IH + off);
                bf16x8 al = *reinterpret_cast<const bf16x8*>((const char*)IL + off);
                #pragma unroll
                for (int n = 0; n < 2; ++n) {
                    acc[m][n] = __builtin_amdgcn_mfma_f32_16x16x32_bf16(bh[n], ah, acc[m][n], 0, 0, 0);
                    acc[m][n] = __builtin_amdgcn_mfma_f32_16x16x32_bf16(bh[n], al, acc[m][n], 0, 0, 0);
                    acc[m][n] = __builtin_amdgcn_mfma_f32_16x16x32_bf16(bl[n], ah, acc[m][n], 0, 0, 0);
                }
            }
            __builtin_amdgcn_s_setprio(0);
        }
        #pragma unroll
        for (int n = 0; n < 2; ++n) {
            int col0 = wn * 32 + n * 16 + r4;
            #pragma unroll
            for (int m = 0; m < 2; ++m) {
                int row = wm * 32 + m * 16 + l15;
                float4 o;
                o.x = silu_f(acc[m][n][0]);
                o.y = silu_f(acc[m][n][1]);
                o.z = silu_f(acc[m][n][2]);
                o.w = silu_f(acc[m][n][3]);
                *reinterpret_cast<float4*>(&C1[(size_t)(bm + row) * INT_DIM + col0]) = o;
            }
        }
    }
}

// ---------------------------------------------------------------------------
// post_chain (256 threads, 4 waves, wave tile 32x64), swapped layout epilogues
// ---------------------------------------------------------------------------
struct ChainP {
    const u16 *uph, *upl;
    const u16 *b0h, *b0l, *b1h, *b1l;
    const u16 *lnh, *lnl;
    const u16 *a0h, *a0l, *a1h, *a1l, *a2h, *a2l, *a3h, *a3l;
    const float *bb0, *bb1, *blin, *ba0, *ba1, *ba2, *ba3;
};

__global__ __launch_bounds__(256, 2) void post_chain(
    const float* __restrict__ AGG, const float* __restrict__ E1,
    const float* __restrict__ X, ChainP p, float* __restrict__ OUT)
{
    __shared__ u16 GH[64 * 64],  GL[64 * 64];
    __shared__ u16 P0H[64 * 128], P0L[64 * 128];
    __shared__ u16 P1H[64 * 128], P1L[64 * 128];

    const int tid  = threadIdx.x;
    const int lane = tid & 63;
    const int w    = tid >> 6;
    const int wm   = w >> 1, wn = w & 1;
    const int bm   = blockIdx.x * 64;
    const int l15  = lane & 15;
    const int khalf = (lane >> 4) * 8;
    const int r4   = (lane >> 4) * 4;

    BF8x4 pre = loadB64f(p.uph, p.upl, 0, wn, l15, khalf);

    // stage AGG [64][64]
    {
        int r  = tid >> 2;
        int c0 = (tid & 3) * 16;
        const float* pg = &AGG[(size_t)(bm + r) * INT_DIM + c0];
        const int swz = (r & 7) << 4;
        #pragma unroll
        for (int q = 0; q < 4; ++q) {
            float4 f = *reinterpret_cast<const float4*>(pg + q * 4);
            float vv[4] = {f.x, f.y, f.z, f.w};
            u16 h[4], l[4];
            #pragma unroll
            for (int j = 0; j < 4; ++j) {
                h[j] = f2bf(vv[j]);
                l[j] = f2bf(vv[j] - bf2f(h[j]));
            }
            int off = (r * 128 + c0 * 2 + q * 8) ^ swz;
            *reinterpret_cast<ushort4*>((char*)GH + off) = make_ushort4(h[0], h[1], h[2], h[3]);
            *reinterpret_cast<ushort4*>((char*)GL + off) = make_ushort4(l[0], l[1], l[2], l[3]);
        }
    }
    __syncthreads();

    f32x4 acc[2][4];

    // S1: UP (K=64), h0 = E1 + silu(acc) -> P0 ; prefetch Wb0
    #pragma unroll
    for (int m = 0; m < 2; ++m)
        #pragma unroll
        for (int n = 0; n < 4; ++n) acc[m][n] = f32x4{0.f, 0.f, 0.f, 0.f};
    mm64_pipe((char*)GH, (char*)GL, p.uph, p.upl, pre, p.b0h, p.b0l,
              wm, wn, l15, khalf, acc);
    #pragma unroll
    for (int n = 0; n < 4; ++n) {
        int col0 = wn * 64 + n * 16 + r4;
        #pragma unroll
        for (int m = 0; m < 2; ++m) {
            int row = wm * 32 + m * 16 + l15;
            float4 e = *reinterpret_cast<const float4*>(&E1[(size_t)(bm + row) * H_DIM + col0]);
            float v[4];
            v[0] = e.x + silu_f(acc[m][n][0]);
            v[1] = e.y + silu_f(acc[m][n][1]);
            v[2] = e.z + silu_f(acc[m][n][2]);
            v[3] = e.w + silu_f(acc[m][n][3]);
            st_split4((char*)P0H, (char*)P0L, row, col0, 256, v);
        }
    }
    __syncthreads();

    #define STAGE_PLAIN(SRC_H, SRC_L, WH, WL, BIAS, DST_H, DST_L, NWH, NWL)             \
    {                                                                                   \
        _Pragma("unroll")                                                               \
        for (int m = 0; m < 2; ++m)                                                     \
            _Pragma("unroll")                                                           \
            for (int n = 0; n < 4; ++n) acc[m][n] = f32x4{0.f, 0.f, 0.f, 0.f};          \
        mm128_pipe((char*)SRC_H, (char*)SRC_L, WH, WL, pre, NWH, NWL,                   \
                   wm, wn, l15, khalf, acc);                                            \
        _Pragma("unroll")                                                               \
        for (int n = 0; n < 4; ++n) {                                                   \
            int col0 = wn * 64 + n * 16 + r4;                                           \
            float4 bv = *reinterpret_cast<const float4*>(&BIAS[col0]);                  \
            _Pragma("unroll")                                                           \
            for (int m = 0; m < 2; ++m) {                                               \
                int row = wm * 32 + m * 16 + l15;                                       \
                float v[4];                                                             \
                v[0] = silu_f(acc[m][n][0] + bv.x);                                     \
                v[1] = silu_f(acc[m][n][1] + bv.y);                                     \
                v[2] = silu_f(acc[m][n][2] + bv.z);                                     \
                v[3] = silu_f(acc[m][n][3] + bv.w);                                     \
                st_split4((char*)DST_H, (char*)DST_L, row, col0, 256, v);               \
            }                                                                           \
        }                                                                               \
        __syncthreads();                                                                \
    }

    #define STAGE_RES(SRC_H, SRC_L, WH, WL, BIAS, RES_H, RES_L, NWH, NWL)               \
    {                                                                                   \
        _Pragma("unroll")                                                               \
        for (int m = 0; m < 2; ++m)                                                     \
            _Pragma("unroll")                                                           \
            for (int n = 0; n < 4; ++n) acc[m][n] = f32x4{0.f, 0.f, 0.f, 0.f};          \
        mm128_pipe((char*)SRC_H, (char*)SRC_L, WH, WL, pre, NWH, NWL,                   \
                   wm, wn, l15, khalf, acc);                                            \
        _Pragma("unroll")                                                               \
        for (int n = 0; n < 4; ++n) {                                                   \
            int col0 = wn * 64 + n * 16 + r4;                                           \
            float4 bv = *reinterpret_cast<const float4*>(&BIAS[col0]);                  \
            _Pragma("unroll")                                                           \
            for (int m = 0; m < 2; ++m) {                                               \
                int row = wm * 32 + m * 16 + l15;                                       \
                float v[4];                                                             \
                ld_split4((char*)RES_H, (char*)RES_L, row, col0, 256, v);               \
                v[0] += silu_f(acc[m][n][0] + bv.x);                                    \
                v[1] += silu_f(acc[m][n][1] + bv.y);                                    \
                v[2] += silu_f(acc[m][n][2] + bv.z);                                    \
                v[3] += silu_f(acc[m][n][3] + bv.w);                                    \
                st_split4((char*)RES_H, (char*)RES_L, row, col0, 256, v);               \
            }                                                                           \
        }                                                                               \
        __syncthreads();                                                                \
    }

    // S2..S3
    STAGE_PLAIN(P0H, P0L, p.b0h, p.b0l, p.bb0, P1H, P1L, p.b1h, p.b1l)
    STAGE_RES(P1H, P1L, p.b1h, p.b1l, p.bb1, P0H, P0L, p.lnh, p.lnl)

    // S4: x1 = silu(P0@Wlin+blin) + X -> P1 ; prefetch Wa0
    {
        #pragma unroll
        for (int m = 0; m < 2; ++m)
            #pragma unroll
            for (int n = 0; n < 4; ++n) acc[m][n] = f32x4{0.f, 0.f, 0.f, 0.f};
        mm128_pipe((char*)P0H, (char*)P0L, p.lnh, p.lnl, pre, p.a0h, p.a0l,
                   wm, wn, l15, khalf, acc);
        #pragma unroll
        for (int n = 0; n < 4; ++n) {
            int col0 = wn * 64 + n * 16 + r4;
            float4 bv = *reinterpret_cast<const float4*>(&p.blin[col0]);
            #pragma unroll
            for (int m = 0; m < 2; ++m) {
                int row = wm * 32 + m * 16 + l15;
                float4 xv = *reinterpret_cast<const float4*>(&X[(size_t)(bm + row) * H_DIM + col0]);
                float v[4];
                v[0] = silu_f(acc[m][n][0] + bv.x) + xv.x;
                v[1] = silu_f(acc[m][n][1] + bv.y) + xv.y;
                v[2] = silu_f(acc[m][n][2] + bv.z) + xv.z;
                v[3] = silu_f(acc[m][n][3] + bv.w) + xv.w;
                st_split4((char*)P1H, (char*)P1L, row, col0, 256, v);
            }
        }
        __syncthreads();
    }

    STAGE_PLAIN(P1H, P1L, p.a0h, p.a0l, p.ba0, P0H, P0L, p.a1h, p.a1l)
    STAGE_RES(P0H, P0L, p.a1h, p.a1l, p.ba1, P1H, P1L, p.a2h, p.a2l)
    STAGE_PLAIN(P1H, P1L, p.a2h, p.a2l, p.ba2, P0H, P0L, p.a3h, p.a3l)

    // S8: OUT = P1 + silu(P0@Wa3+ba3)
    {
        #pragma unroll
        for (int m = 0; m < 2; ++m)
            #pragma unroll
            for (int n = 0; n < 4; ++n) acc[m][n] = f32x4{0.f, 0.f, 0.f, 0.f};
        mm128_pipe((char*)P0H, (char*)P0L, p.a3h, p.a3l, pre, nullptr, nullptr,
                   wm, wn, l15, khalf, acc);
        #pragma unroll
        for (int n = 0; n < 4; ++n) {
            int col0 = wn * 64 + n * 16 + r4;
            float4 bv = *reinterpret_cast<const float4*>(&p.ba3[col0]);
            #pragma unroll
            for (int m = 0; m < 2; ++m) {
                int row = wm * 32 + m * 16 + l15;
                float v[4];
                ld_split4((char*)P1H, (char*)P1L, row, col0, 256, v);
                float4 o;
                o.x = v[0] + silu_f(acc[m][n][0] + bv.x);
                o.y = v[1] + silu_f(acc[m][n][1] + bv.y);
                o.z = v[2] + silu_f(acc[m][n][2] + bv.z);
                o.w = v[3] + silu_f(acc[m][n][3] + bv.w);
                *reinterpret_cast<float4*>(&OUT[(size_t)(bm + row) * H_DIM + col0]) = o;
            }
        }
    }
    #undef STAGE_PLAIN
    #undef STAGE_RES
}

// ---------------------------------------------------------------------------
// out_chain (256 threads, 4 waves; 32 rows/block), swapped layout epilogues
// ---------------------------------------------------------------------------
__global__ __launch_bounds__(256, 2) void out_chain(
    const float* __restrict__ TN,
    const u16* __restrict__ Uh, const u16* __restrict__ Ul, const float* __restrict__ bu,
    const u16* __restrict__ L0h, const u16* __restrict__ L0l, const float* __restrict__ b0,
    const u16* __restrict__ L1h, const u16* __restrict__ L1l, const float* __restrict__ b1,
    const u16* __restrict__ L2h, const u16* __restrict__ L2l, const float* __restrict__ b2,
    const float* __restrict__ Wo, float* __restrict__ P)
{
    __shared__ u16 XH[32 * 128], XL[32 * 128];
    __shared__ u16 T0H[32 * 256], T0L[32 * 256];
    __shared__ u16 T1H[32 * 256], T1L[32 * 256];

    const int tid  = threadIdx.x;
    const int lane = tid & 63;
    const int wn   = tid >> 6;      // 0..3, wave covers cols wn*64..+64
    const int bm   = blockIdx.x * 32;
    const int l15  = lane & 15;
    const int khalf = (lane >> 4) * 8;
    const int r4   = (lane >> 4) * 4;

    // stage TN tile [32][128] f32 -> split LDS (stride 256B)
    {
        int r  = tid >> 3;
        int c0 = (tid & 7) * 16;
        const float* p = &TN[(size_t)(bm + r) * H_DIM + c0];
        const int swz = (r & 7) << 4;
        #pragma unroll
        for (int q = 0; q < 4; ++q) {
            float4 f = *reinterpret_cast<const float4*>(p + q * 4);
            float vv[4] = {f.x, f.y, f.z, f.w};
            u16 h[4], l[4];
            #pragma unroll
            for (int j = 0; j < 4; ++j) {
                h[j] = f2bf(vv[j]);
                l[j] = f2bf(vv[j] - bf2f(h[j]));
            }
            int off = (r * 256 + c0 * 2 + q * 8) ^ swz;
            *reinterpret_cast<ushort4*>((char*)XH + off) = make_ushort4(h[0], h[1], h[2], h[3]);
            *reinterpret_cast<ushort4*>((char*)XL + off) = make_ushort4(l[0], l[1], l[2], l[3]);
        }
    }
    __syncthreads();

    f32x4 acc[2][4];

    // up: K=128, bias only -> T0
    {
        #pragma unroll
        for (int m = 0; m < 2; ++m)
            #pragma unroll
            for (int n = 0; n < 4; ++n) acc[m][n] = f32x4{0.f, 0.f, 0.f, 0.f};
        BF8x4 cur = loadB128f(Uh, Ul, 0, wn, l15, khalf);
        #pragma unroll
        for (int k = 0; k < 4; ++k) {
            BF8x4 nxt;
            if (k < 3) nxt = loadB128f(Uh, Ul, 32 * (k + 1), wn, l15, khalf);
            mfma_cluster((char*)XH, (char*)XL, 32 * k, 0, l15, khalf, cur, acc);
            if (k < 3) cur = nxt;
        }
        #pragma unroll
        for (int n = 0; n < 4; ++n) {
            int col0 = wn * 64 + n * 16 + r4;
            float4 bv = *reinterpret_cast<const float4*>(&bu[col0]);
            #pragma unroll
            for (int m = 0; m < 2; ++m) {
                int row = m * 16 + l15;
                float v[4] = {acc[m][n][0] + bv.x, acc[m][n][1] + bv.y,
                              acc[m][n][2] + bv.z, acc[m][n][3] + bv.w};
                st_split4((char*)T0H, (char*)T0L, row, col0, 512, v);
            }
        }
        __syncthreads();
    }

    #define OLIN(SRC_H, SRC_L, WH, WL, BIAS, DST_H, DST_L)                              \
    {                                                                                   \
        _Pragma("unroll")                                                               \
        for (int m = 0; m < 2; ++m)                                                     \
            _Pragma("unroll")                                                           \
            for (int n = 0; n < 4; ++n) acc[m][n] = f32x4{0.f, 0.f, 0.f, 0.f};          \
        BF8x4 cur = loadB256f(WH, WL, 0, wn, l15, khalf);                               \
        _Pragma("unroll")                                                               \
        for (int k = 0; k < 8; ++k) {                                                   \
            BF8x4 nxt;                                                                  \
            if (k < 7) nxt = loadB256f(WH, WL, 32 * (k + 1), wn, l15, khalf);           \
            mfma_cluster512((char*)SRC_H, (char*)SRC_L, 32 * k, l15, khalf, cur, acc);  \
            if (k < 7) cur = nxt;                                                       \
        }                                                                               \
        _Pragma("unroll")                                                               \
        for (int n = 0; n < 4; ++n) {                                                   \
            int col0 = wn * 64 + n * 16 + r4;                                           \
            float4 bv = *reinterpret_cast<const float4*>(&BIAS[col0]);                  \
            _Pragma("unroll")                                                           \
            for (int m = 0; m < 2; ++m) {                                               \
                int row = m * 16 + l15;                                                 \
                float v[4];                                                             \
                v[0] = silu_f(acc[m][n][0] + bv.x);                                     \
                v[1] = silu_f(acc[m][n][1] + bv.y);                                     \
                v[2] = silu_f(acc[m][n][2] + bv.z);                                     \
                v[3] = silu_f(acc[m][n][3] + bv.w);                                     \
                st_split4((char*)DST_H, (char*)DST_L, row, col0, 512, v);               \
            }                                                                           \
        }                                                                               \
        __syncthreads();                                                                \
    }

    OLIN(T0H, T0L, L0h, L0l, b0, T1H, T1L)
    OLIN(T1H, T1L, L1h, L1l, b1, T0H, T0L)
    OLIN(T0H, T0L, L2h, L2l, b2, T1H, T1L)
    #undef OLIN

    // final: P[bm+row] += dot(T1[row][:256], Wo[:256]); 8 threads per row
    {
        int row  = tid >> 3;
        int part = tid & 7;
        float s = 0.f;
        int cbase = part * 32;
        #pragma unroll
        for (int c4 = 0; c4 < 32; c4 += 4) {
            float v[4];
            ld_split4((char*)T1H, (char*)T1L, row, cbase + c4, 512, v);
            float4 wv = *reinterpret_cast<const float4*>(&Wo[cbase + c4]);
            s = fmaf(v[0], wv.x, s);
            s = fmaf(v[1], wv.y, s);
            s = fmaf(v[2], wv.z, s);
            s = fmaf(v[3], wv.w, s);
        }
        s += __shfl_xor(s, 1);
        s += __shfl_xor(s, 2);
        s += __shfl_xor(s, 4);
        if (part == 0) P[bm + row] += s;
    }
}

// rbf8[e][j] = rbf[e] @ W_rbf1[b]   [E,8]
__global__ __launch_bounds__(256) void rbf8_kernel(
    const float* __restrict__ rbf, const float* __restrict__ W1,
    float* __restrict__ r8, int Ecount)
{
    int e = blockIdx.x * blockDim.x + threadIdx.x;
    if (e >= Ecount) return;
    float rv[NRAD];
    #pragma unroll
    for (int k = 0; k < NRAD; ++k) rv[k] = rbf[(size_t)e * NRAD + k];
    float acc[BAS] = {};
    #pragma unroll
    for (int k = 0; k < NRAD; ++k)
        #pragma unroll
        for (int j = 0; j < BAS; ++j)
            acc[j] = fmaf(rv[k], W1[k * BAS + j], acc[j]);
    float4* o = reinterpret_cast<float4*>(&r8[(size_t)e * BAS]);
    o[0] = make_float4(acc[0], acc[1], acc[2], acc[3]);
    o[1] = make_float4(acc[4], acc[5], acc[6], acc[7]);
}

// ---------------------------------------------------------------------------
// CSR build kernels
// ---------------------------------------------------------------------------
__global__ __launch_bounds__(256) void csr_count(
    const int* __restrict__ idx, int* __restrict__ cnt, int n)
{
    int i = blockIdx.x * 256 + threadIdx.x;
    if (i < n) atomicAdd(&cnt[idx[i]], 1);
}

__global__ __launch_bounds__(256) void scan_block(
    const int* __restrict__ cnt, int* __restrict__ ptr, int* __restrict__ bsum, int n)
{
    __shared__ int s[256];
    int i = blockIdx.x * 256 + threadIdx.x;
    int v = (i < n) ? cnt[i] : 0;
    s[threadIdx.x] = v;
    __syncthreads();
    #pragma unroll
    for (int off = 1; off < 256; off <<= 1) {
        int t = (threadIdx.x >= off) ? s[threadIdx.x - off] : 0;
        __syncthreads();
        s[threadIdx.x] += t;
        __syncthreads();
    }
    if (i < n) ptr[i] = s[threadIdx.x] - v;   // exclusive
    if (threadIdx.x == 255) bsum[blockIdx.x] = s[255];
}

__global__ __launch_bounds__(1024) void scan_aux(int* __restrict__ bsum, int nb)
{
    __shared__ int s[1024];
    int v = (threadIdx.x < nb) ? bsum[threadIdx.x] : 0;
    s[threadIdx.x] = v;
    __syncthreads();
    #pragma unroll
    for (int off = 1; off < 1024; off <<= 1) {
        int t = (threadIdx.x >= off) ? s[threadIdx.x - off] : 0;
        __syncthreads();
        s[threadIdx.x] += t;
        __syncthreads();
    }
    if (threadIdx.x < nb) bsum[threadIdx.x] = s[threadIdx.x] - v;
}

__global__ __launch_bounds__(256) void scan_add(
    int* __restrict__ ptr, const int* __restrict__ bsum, int n)
{
    int i = blockIdx.x * 256 + threadIdx.x;
    if (i < n) ptr[i] += bsum[blockIdx.x];
}

__global__ __launch_bounds__(256) void csr_fill(
    const int* __restrict__ idx, int* __restrict__ cursor,
    int* __restrict__ perm, int n)
{
    int i = blockIdx.x * 256 + threadIdx.x;
    if (i >= n) return;
    int pos = atomicAdd(&cursor[idx[i]], 1);
    perm[pos] = i;
}

// ---------------------------------------------------------------------------
// One-time: permuted sbf basis for ALL blocks + permuted idx_kj.
// ---------------------------------------------------------------------------
__global__ __launch_bounds__(256) void permute_s8(
    const float* __restrict__ sbf, const float* __restrict__ W1all,
    const int* __restrict__ idx_kj, const int* __restrict__ tperm,
    u16* __restrict__ ps8, int* __restrict__ pkj, int Tcount)
{
    __shared__ float Ws[NB * SBF_D * BAS];
    for (int i = threadIdx.x; i < NB * SBF_D * BAS; i += 256) Ws[i] = W1all[i];
    __syncthreads();
    int i = blockIdx.x * 256 + threadIdx.x;
    if (i >= Tcount) return;
    int t = tperm[i];
    pkj[i] = idx_kj[t];
    float s[SBF_D];
    {
        const float2* p2 = reinterpret_cast<const float2*>(&sbf[(size_t)t * SBF_D]);
        #pragma unroll
        for (int k = 0; k < SBF_D / 2; ++k) {
            float2 v = p2[k];
            s[2 * k] = v.x; s[2 * k + 1] = v.y;
        }
    }
    #pragma unroll
    for (int b = 0; b < NB; ++b) {
        const float* Wb_ = &Ws[b * SBF_D * BAS];
        float acc[BAS] = {};
        for (int k = 0; k < SBF_D; ++k) {
            float sv = s[k];
            #pragma unroll
            for (int j = 0; j < BAS; ++j)
                acc[j] = fmaf(sv, Wb_[k * BAS + j], acc[j]);
        }
        ushort4 o0 = make_ushort4(f2bf(acc[0]), f2bf(acc[1]), f2bf(acc[2]), f2bf(acc[3]));
        ushort4 o1 = make_ushort4(f2bf(acc[4]), f2bf(acc[5]), f2bf(acc[6]), f2bf(acc[7]));
        u16* op = &ps8[((size_t)b * Tcount + i) * BAS];
        *reinterpret_cast<ushort4*>(op) = o0;
        *reinterpret_cast<ushort4*>(op + 4) = o1;
    }
}

// ---------------------------------------------------------------------------
// Triplet aggregation, permuted sequential stream
// ---------------------------------------------------------------------------
__device__ __forceinline__ float dot8_bf(uint4 r, const float* w2) {
    float s;
    s  = bf2f((u16)(r.x)) * w2[0] + bf2f((u16)(r.x >> 16)) * w2[1];
    s += bf2f((u16)(r.y)) * w2[2] + bf2f((u16)(r.y >> 16)) * w2[3];
    s += bf2f((u16)(r.z)) * w2[4] + bf2f((u16)(r.z >> 16)) * w2[5];
    s += bf2f((u16)(r.w)) * w2[6] + bf2f((u16)(r.w >> 16)) * w2[7];
    return s;
}

__global__ __launch_bounds__(256) void triplet_gather2(
    const u16* __restrict__ ps8b, const float* __restrict__ Wsb2,
    const float* __restrict__ xkj, const int* __restrict__ pkj,
    const int* __restrict__ tptr, const int* __restrict__ tcnt,
    float* __restrict__ agg, int Ecount)
{
    const int lane = threadIdx.x & 63;
    int wid = (blockIdx.x * blockDim.x + threadIdx.x) >> 6;
    const int nw = (gridDim.x * blockDim.x) >> 6;
    float w2[BAS];
    #pragma unroll
    for (int j = 0; j < BAS; ++j) w2[j] = Wsb2[j * INT_DIM + lane];

    for (int e = wid; e < Ecount; e += nw) {
        int start = tptr[e];
        int end   = start + tcnt[e];
        float acc0 = 0.f, acc1 = 0.f;
        int i = start;
        for (; i + 1 < end; i += 2) {
            uint4 ra = *reinterpret_cast<const uint4*>(&ps8b[(size_t)i * BAS]);
            uint4 rb = *reinterpret_cast<const uint4*>(&ps8b[(size_t)(i + 1) * BAS]);
            int e0 = pkj[i], e1 = pkj[i + 1];
            float s0 = dot8_bf(ra, w2);
            float s1 = dot8_bf(rb, w2);
            acc0 = fmaf(xkj[(size_t)e0 * INT_DIM + lane], s0, acc0);
            acc1 = fmaf(xkj[(size_t)e1 * INT_DIM + lane], s1, acc1);
        }
        if (i < end) {
            uint4 ra = *reinterpret_cast<const uint4*>(&ps8b[(size_t)i * BAS]);
            int e0 = pkj[i];
            acc0 = fmaf(xkj[(size_t)e0 * INT_DIM + lane], dot8_bf(ra, w2), acc0);
        }
        agg[(size_t)e * INT_DIM + lane] = acc0 + acc1;
    }
}

// ---------------------------------------------------------------------------
// Output-block node gather
// ---------------------------------------------------------------------------
__global__ __launch_bounds__(256) void out_gather(
    const float* __restrict__ rbf, const float* __restrict__ Wor,
    const float* __restrict__ x,
    const int* __restrict__ eptr, const int* __restrict__ ecnt,
    const int* __restrict__ eperm, float* __restrict__ tN, int Nn)
{
    const int lane = threadIdx.x & 63;
    int wid = (blockIdx.x * blockDim.x + threadIdx.x) >> 6;
    const int nw = (gridDim.x * blockDim.x) >> 6;
    float wr0[NRAD], wr1[NRAD];
    #pragma unroll
    for (int k = 0; k < NRAD; ++k) {
        wr0[k] = Wor[k * H_DIM + lane];
        wr1[k] = Wor[k * H_DIM + lane + 64];
    }
    for (int n = wid; n < Nn; n += nw) {
        int start = eptr[n];
        int end   = start + ecnt[n];
        float a0 = 0.f, a1 = 0.f;
        for (int i = start; i < end; ++i) {
            int e = eperm[i];
            const float2* rp = reinterpret_cast<const float2*>(&rbf[(size_t)e * NRAD]);
            float2 r0 = rp[0], r1 = rp[1], r2 = rp[2];
            float rA = r0.x*wr0[0] + r0.y*wr0[1] + r1.x*wr0[2]
                     + r1.y*wr0[3] + r2.x*wr0[4] + r2.y*wr0[5];
            float rB = r0.x*wr1[0] + r0.y*wr1[1] + r1.x*wr1[2]
                     + r1.y*wr1[3] + r2.x*wr1[4] + r2.y*wr1[5];
            a0 = fmaf(rA, x[(size_t)e * H_DIM + lane], a0);
            a1 = fmaf(rB, x[(size_t)e * H_DIM + lane + 64], a1);
        }
        tN[(size_t)n * H_DIM + lane] = a0;
        tN[(size_t)n * H_DIM + lane + 64] = a1;
    }
}

// ---------------------------------------------------------------------------
extern "C" void kernel_launch(void* const* d_in, const int* in_sizes, int n_in,
                              void* d_out, int out_size, void* d_ws, size_t ws_size,
                              hipStream_t stream)
{
    const float* x_in    = (const float*)d_in[0];
    const float* rbf     = (const float*)d_in[1];
    const float* sbf     = (const float*)d_in[2];
    const float* W_rbf1  = (const float*)d_in[3];
    const float* W_rbf2  = (const float*)d_in[4];
    const float* W_sbf1  = (const float*)d_in[5];
    const float* W_sbf2  = (const float*)d_in[6];
    const float* W_kj    = (const float*)d_in[7];
    const float* b_kj    = (const float*)d_in[8];
    const float* W_ji    = (const float*)d_in[9];
    const float* b_ji    = (const float*)d_in[10];
    const float* W_down  = (const float*)d_in[11];
    const float* W_up    = (const float*)d_in[12];
    const float* Wb      = (const float*)d_in[13];
    const float* bb      = (const float*)d_in[14];
    const float* Wa      = (const float*)d_in[15];
    const float* ba      = (const float*)d_in[16];
    const float* W_lin   = (const float*)d_in[17];
    const float* b_lin   = (const float*)d_in[18];
    const float* Wo_rbf  = (const float*)d_in[19];
    const float* Wo_up   = (const float*)d_in[20];
    const float* bo_up   = (const float*)d_in[21];
    const float* Wo_lins = (const float*)d_in[22];
    const float* bo_lins = (const float*)d_in[23];
    const float* Wo_out  = (const float*)d_in[24];
    const int*   idx_kj  = (const int*)d_in[25];
    const int*   idx_ji  = (const int*)d_in[26];
    const int*   idx_i   = (const int*)d_in[27];

    // workspace carve-up
    char* ws = (char*)d_ws;
    size_t off = 0;
    auto alloc = [&](size_t bytes) -> void* {
        void* p = (void*)(ws + off);
        off += (bytes + 255) & ~(size_t)255;
        return p;
    };
    float* XA = (float*)alloc((size_t)E_EDGES * H_DIM * 4);
    float* XB = (float*)alloc((size_t)E_EDGES * H_DIM * 4);
    float* E1 = (float*)alloc((size_t)E_EDGES * H_DIM * 4);
    float* C1 = (float*)alloc((size_t)E_EDGES * INT_DIM * 4);
    float* C2 = (float*)alloc((size_t)E_EDGES * INT_DIM * 4);
    float* R8 = (float*)alloc((size_t)E_EDGES * BAS * 4);
    float* TN = (float*)alloc((size_t)N_NODES * H_DIM * 4);
    // split-bf16 transposed weights
    u16* HKJ = (u16*)alloc(4  * 16384 * 2); u16* LKJ = (u16*)alloc(4  * 16384 * 2);
    u16* HJI = (u16*)alloc(4  * 16384 * 2); u16* LJI = (u16*)alloc(4  * 16384 * 2);
    u16* HDN = (u16*)alloc(4  * 8192  * 2); u16* LDN = (u16*)alloc(4  * 8192  * 2);
    u16* HUP = (u16*)alloc(4  * 8192  * 2); u16* LUP = (u16*)alloc(4  * 8192  * 2);
    u16* HWB = (u16*)alloc(8  * 16384 * 2); u16* LWB = (u16*)alloc(8  * 16384 * 2);
    u16* HWA = (u16*)alloc(16 * 16384 * 2); u16* LWA = (u16*)alloc(16 * 16384 * 2);
    u16* HLN = (u16*)alloc(4  * 16384 * 2); u16* LLN = (u16*)alloc(4  * 16384 * 2);
    u16* HOU = (u16*)alloc(5  * 32768 * 2); u16* LOU = (u16*)alloc(5  * 32768 * 2);
    u16* HOL = (u16*)alloc(15 * 65536 * 2); u16* LOL = (u16*)alloc(15 * 65536 * 2);
    // CSR structures
    int* tcnt  = (int*)alloc((size_t)E_EDGES * 4);
    int* tptr  = (int*)alloc((size_t)E_EDGES * 4);
    int* tcur  = (int*)alloc((size_t)E_EDGES * 4);
    int* tperm = (int*)alloc((size_t)T_TRIP * 4);
    int* tbsum = (int*)alloc(1024 * 4);
    int* ecnt  = (int*)alloc((size_t)N_NODES * 4);
    int* eptr  = (int*)alloc((size_t)N_NODES * 4);
    int* ecur  = (int*)alloc((size_t)N_NODES * 4);
    int* eperm = (int*)alloc((size_t)E_EDGES * 4);
    int* ebsum = (int*)alloc(1024 * 4);
    // permuted triplet stream
    u16* PS8 = (u16*)alloc((size_t)NB * T_TRIP * BAS * 2);
    int* PKJ = (int*)alloc((size_t)T_TRIP * 4);
    (void)ws_size;

    auto prep = [&](const float* src, u16* hi, u16* lo, int K, int N, int cnt) {
        dim3 g((K * N + 255) / 256, cnt);
        hipLaunchKernelGGL(wprep, g, dim3(256), 0, stream, src, hi, lo, K, N);
    };
    prep(W_kj,    HKJ, LKJ, 128, 128, 4);
    prep(W_ji,    HJI, LJI, 128, 128, 4);
    prep(W_down,  HDN, LDN, 128, 64,  4);
    prep(W_up,    HUP, LUP, 64,  128, 4);
    prep(Wb,      HWB, LWB, 128, 128, 8);
    prep(Wa,      HWA, LWA, 128, 128, 16);
    prep(W_lin,   HLN, LLN, 128, 128, 4);
    prep(Wo_up,   HOU, LOU, 128, 256, 5);
    prep(Wo_lins, HOL, LOL, 256, 256, 15);

    // ---- build triplet CSR (idx_ji: T entries -> E buckets)
    {
        const int nbT = (E_EDGES + 255) / 256;
        hipMemsetAsync(tcnt, 0, (size_t)E_EDGES * 4, stream);
        hipLaunchKernelGGL(csr_count, dim3((T_TRIP + 255) / 256), dim3(256), 0, stream,
                           idx_ji, tcnt, T_TRIP);
        hipLaunchKernelGGL(scan_block, dim3(nbT), dim3(256), 0, stream, tcnt, tptr, tbsum, E_EDGES);
        hipLaunchKernelGGL(scan_aux, dim3(1), dim3(1024), 0, stream, tbsum, nbT);
        hipLaunchKernelGGL(scan_add, dim3(nbT), dim3(256), 0, stream, tptr, tbsum, E_EDGES);
        hipMemcpyAsync(tcur, tptr, (size_t)E_EDGES * 4, hipMemcpyDeviceToDevice, stream);
        hipLaunchKernelGGL(csr_fill, dim3((T_TRIP + 255) / 256), dim3(256), 0, stream,
                           idx_ji, tcur, tperm, T_TRIP);
    }
    // ---- build node CSR (idx_i: E entries -> N buckets)
    {
        const int nbN = (N_NODES + 255) / 256;
        hipMemsetAsync(ecnt, 0, (size_t)N_NODES * 4, stream);
        hipLaunchKernelGGL(csr_count, dim3((E_EDGES + 255) / 256), dim3(256), 0, stream,
                           idx_i, ecnt, E_EDGES);
        hipLaunchKernelGGL(scan_block, dim3(nbN), dim3(256), 0, stream, ecnt, eptr, ebsum, N_NODES);
        hipLaunchKernelGGL(scan_aux, dim3(1), dim3(1024), 0, stream, ebsum, nbN);
        hipLaunchKernelGGL(scan_add, dim3(nbN), dim3(256), 0, stream, eptr, ebsum, N_NODES);
        hipMemcpyAsync(ecur, eptr, (size_t)N_NODES * 4, hipMemcpyDeviceToDevice, stream);
        hipLaunchKernelGGL(csr_fill, dim3((E_EDGES + 255) / 256), dim3(256), 0, stream,
                           idx_i, ecur, eperm, E_EDGES);
    }
    // ---- one-time permuted sbf basis for all blocks
    hipLaunchKernelGGL(permute_s8, dim3((T_TRIP + 255) / 256), dim3(256), 0, stream,
                       sbf, W_sbf1, idx_kj, tperm, PS8, PKJ, T_TRIP);

    float* P = (float*)d_out;
    hipMemsetAsync(P, 0, (size_t)N_NODES * sizeof(float), stream);

    auto out_block = [&](int ob, const float* xcur) {
        hipLaunchKernelGGL(out_gather, dim3(2048), dim3(256), 0, stream,
                           rbf, Wo_rbf + (size_t)ob * NRAD * H_DIM, xcur,
                           eptr, ecnt, eperm, TN, N_NODES);
        hipLaunchKernelGGL(out_chain, dim3(N_NODES / 32), dim3(256), 0, stream,
                           TN,
                           HOU + (size_t)ob * 32768, LOU + (size_t)ob * 32768,
                           bo_up + (size_t)ob * OUT_EMB,
                           HOL + (size_t)(ob * 3 + 0) * 65536, LOL + (size_t)(ob * 3 + 0) * 65536,
                           bo_lins + (size_t)(ob * 3 + 0) * OUT_EMB,
                           HOL + (size_t)(ob * 3 + 1) * 65536, LOL + (size_t)(ob * 3 + 1) * 65536,
                           bo_lins + (size_t)(ob * 3 + 1) * OUT_EMB,
                           HOL + (size_t)(ob * 3 + 2) * 65536, LOL + (size_t)(ob * 3 + 2) * 65536,
                           bo_lins + (size_t)(ob * 3 + 2) * OUT_EMB,
                           Wo_out + (size_t)ob * OUT_EMB, P);
    };

    out_block(0, x_in);

    const float* xcur = x_in;
    const int EB = E_EDGES / 64;  // 3125
    for (int b = 0; b < NB; ++b) {
        float* xnext = (b % 2 == 0) ? XB : XA;
        hipLaunchKernelGGL(rbf8_kernel, dim3((E_EDGES + 255) / 256), dim3(256), 0, stream,
                           rbf, W_rbf1 + (size_t)b * NRAD * BAS, R8, E_EDGES);
        // fused: E1 = silu(x@Wji+bji); C1 = silu((silu(x@Wkj+bkj)*gate)@Wdn)
        hipLaunchKernelGGL(pre_fuse, dim3(EB), dim3(256), 0, stream,
                           xcur, R8,
                           HJI + (size_t)b * 16384, LJI + (size_t)b * 16384, b_ji + (size_t)b * H_DIM,
                           HKJ + (size_t)b * 16384, LKJ + (size_t)b * 16384, b_kj + (size_t)b * H_DIM,
                           W_rbf2 + (size_t)b * BAS * H_DIM,
                           HDN + (size_t)b * 8192, LDN + (size_t)b * 8192,
                           E1, C1);
        // triplet aggregation (permuted stream, atomic-free)
        hipLaunchKernelGGL(triplet_gather2, dim3(2048), dim3(256), 0, stream,
                           PS8 + (size_t)b * T_TRIP * BAS, W_sbf2 + (size_t)b * BAS * INT_DIM,
                           C1, PKJ, tptr, tcnt, C2, E_EDGES);
        // fused chain: UP + pair(Wb) + LIN + pair(Wa0/1) + pair(Wa2/3)
        ChainP cp;
        cp.uph = HUP + (size_t)b * 8192;  cp.upl = LUP + (size_t)b * 8192;
        cp.b0h = HWB + (size_t)(b * 2 + 0) * 16384; cp.b0l = LWB + (size_t)(b * 2 + 0) * 16384;
        cp.b1h = HWB + (size_t)(b * 2 + 1) * 16384; cp.b1l = LWB + (size_t)(b * 2 + 1) * 16384;
        cp.lnh = HLN + (size_t)b * 16384; cp.lnl = LLN + (size_t)b * 16384;
        cp.a0h = HWA + (size_t)(b * 4 + 0) * 16384; cp.a0l = LWA + (size_t)(b * 4 + 0) * 16384;
        cp.a1h = HWA + (size_t)(b * 4 + 1) * 16384; cp.a1l = LWA + (size_t)(b * 4 + 1) * 16384;
        cp.a2h = HWA + (size_t)(b * 4 + 2) * 16384; cp.a2l = LWA + (size_t)(b * 4 + 2) * 16384;
        cp.a3h = HWA + (size_t)(b * 4 + 3) * 16384; cp.a3l = LWA + (size_t)(b * 4 + 3) * 16384;
        cp.bb0 = bb + (size_t)(b * 2 + 0) * H_DIM;
        cp.bb1 = bb + (size_t)(b * 2 + 1) * H_DIM;
        cp.blin = b_lin + (size_t)b * H_DIM;
        cp.ba0 = ba + (size_t)(b * 4 + 0) * H_DIM;
        cp.ba1 = ba + (size_t)(b * 4 + 1) * H_DIM;
        cp.ba2 = ba + (size_t)(b * 4 + 2) * H_DIM;
        cp.ba3 = ba + (size_t)(b * 4 + 3) * H_DIM;
        hipLaunchKernelGGL(post_chain, dim3(EB), dim3(256), 0, stream,
                           C2, E1, xcur, cp, xnext);
        xcur = xnext;
        out_block(b + 1, xcur);
    }
}

// Round 10
// 4168.479 us; speedup vs baseline: 1.4581x; 1.0489x over previous
//
#include <hip/hip_runtime.h>
#include <hip/hip_bf16.h>

// Problem constants (fixed by the reference)
#define E_EDGES 200000
#define T_TRIP  2000000
#define N_NODES 20000
#define H_DIM   128
#define INT_DIM 64
#define BAS     8
#define OUT_EMB 256
#define NRAD    6
#define SBF_D   42
#define NB      4

typedef __attribute__((ext_vector_type(8))) __bf16 bf16x8;
typedef __attribute__((ext_vector_type(4))) float f32x4;
typedef unsigned short u16;

__device__ __forceinline__ float silu_f(float v) { return v / (1.0f + __expf(-v)); }

__device__ __forceinline__ u16 f2bf(float f) {
    unsigned int u = __float_as_uint(f);
    u += 0x7FFF + ((u >> 16) & 1);   // RNE
    return (u16)(u >> 16);
}
__device__ __forceinline__ float bf2f(u16 h) {
    return __uint_as_float(((unsigned int)h) << 16);
}

// Vectorized split-bf16 LDS helpers: 4 consecutive columns per access.
__device__ __forceinline__ void st_split4(char* H, char* L, int row, int col0, int stride,
                                          const float v[4]) {
    ushort4 hh, ll;
    u16 h0 = f2bf(v[0]); ll.x = f2bf(v[0] - bf2f(h0)); hh.x = h0;
    u16 h1 = f2bf(v[1]); ll.y = f2bf(v[1] - bf2f(h1)); hh.y = h1;
    u16 h2 = f2bf(v[2]); ll.z = f2bf(v[2] - bf2f(h2)); hh.z = h2;
    u16 h3 = f2bf(v[3]); ll.w = f2bf(v[3] - bf2f(h3)); hh.w = h3;
    int off = (row * stride + col0 * 2) ^ ((row & 7) << 4);
    *reinterpret_cast<ushort4*>(H + off) = hh;
    *reinterpret_cast<ushort4*>(L + off) = ll;
}
__device__ __forceinline__ void ld_split4(const char* H, const char* L, int row, int col0,
                                          int stride, float v[4]) {
    int off = (row * stride + col0 * 2) ^ ((row & 7) << 4);
    ushort4 hh = *reinterpret_cast<const ushort4*>(H + off);
    ushort4 ll = *reinterpret_cast<const ushort4*>(L + off);
    v[0] = bf2f(hh.x) + bf2f(ll.x);
    v[1] = bf2f(hh.y) + bf2f(ll.y);
    v[2] = bf2f(hh.z) + bf2f(ll.z);
    v[3] = bf2f(hh.w) + bf2f(ll.w);
}

// ---- B-fragment register block: 4 n-tiles (hi+lo) ----
struct BF8x4 { bf16x8 h[4]; bf16x8 l[4]; };

__device__ __forceinline__ BF8x4 loadB128f(const u16* __restrict__ Bh, const u16* __restrict__ Bl,
                                           int k0, int wn, int l15, int khalf)
{
    BF8x4 f;
    #pragma unroll
    for (int n = 0; n < 4; ++n) {
        size_t bo = (size_t)(wn * 64 + n * 16 + l15) * 128 + k0 + khalf;
        f.h[n] = *reinterpret_cast<const bf16x8*>(Bh + bo);
        f.l[n] = *reinterpret_cast<const bf16x8*>(Bl + bo);
    }
    return f;
}
__device__ __forceinline__ BF8x4 loadB64f(const u16* __restrict__ Bh, const u16* __restrict__ Bl,
                                          int k0, int wn, int l15, int khalf)
{
    BF8x4 f;
    #pragma unroll
    for (int n = 0; n < 4; ++n) {
        size_t bo = (size_t)(wn * 64 + n * 16 + l15) * 64 + k0 + khalf;
        f.h[n] = *reinterpret_cast<const bf16x8*>(Bh + bo);
        f.l[n] = *reinterpret_cast<const bf16x8*>(Bl + bo);
    }
    return f;
}
__device__ __forceinline__ BF8x4 loadB256f(const u16* __restrict__ Bh, const u16* __restrict__ Bl,
                                           int k0, int wn, int l15, int khalf)
{
    BF8x4 f;
    #pragma unroll
    for (int n = 0; n < 4; ++n) {
        size_t bo = (size_t)(wn * 64 + n * 16 + l15) * 256 + k0 + khalf;
        f.h[n] = *reinterpret_cast<const bf16x8*>(Bh + bo);
        f.l[n] = *reinterpret_cast<const bf16x8*>(Bl + bo);
    }
    return f;
}

// SWAPPED-OPERAND clusters: mfma(W, A) -> lane holds output row=l15,
// cols (lane>>4)*4+reg (4 consecutive). Bit-identical products/accum order.
__device__ __forceinline__ void mfma_cluster(
    const char* AH, const char* AL, int k0, int wm, int l15, int khalf,
    const BF8x4& b, f32x4 acc[2][4])
{
    __builtin_amdgcn_s_setprio(1);
    #pragma unroll
    for (int m = 0; m < 2; ++m) {
        int row = wm * 32 + m * 16 + l15;
        int off = (row * 256 + (k0 + khalf) * 2) ^ ((row & 7) << 4);
        bf16x8 ah = *reinterpret_cast<const bf16x8*>(AH + off);
        bf16x8 al = *reinterpret_cast<const bf16x8*>(AL + off);
        #pragma unroll
        for (int n = 0; n < 4; ++n) {
            acc[m][n] = __builtin_amdgcn_mfma_f32_16x16x32_bf16(b.h[n], ah, acc[m][n], 0, 0, 0);
            acc[m][n] = __builtin_amdgcn_mfma_f32_16x16x32_bf16(b.h[n], al, acc[m][n], 0, 0, 0);
            acc[m][n] = __builtin_amdgcn_mfma_f32_16x16x32_bf16(b.l[n], ah, acc[m][n], 0, 0, 0);
        }
    }
    __builtin_amdgcn_s_setprio(0);
}
__device__ __forceinline__ void mfma_cluster64(
    const char* AH, const char* AL, int k0, int wm, int l15, int khalf,
    const BF8x4& b, f32x4 acc[2][4])
{
    __builtin_amdgcn_s_setprio(1);
    #pragma unroll
    for (int m = 0; m < 2; ++m) {
        int row = wm * 32 + m * 16 + l15;
        int off = (row * 128 + (k0 + khalf) * 2) ^ ((row & 7) << 4);
        bf16x8 ah = *reinterpret_cast<const bf16x8*>(AH + off);
        bf16x8 al = *reinterpret_cast<const bf16x8*>(AL + off);
        #pragma unroll
        for (int n = 0; n < 4; ++n) {
            acc[m][n] = __builtin_amdgcn_mfma_f32_16x16x32_bf16(b.h[n], ah, acc[m][n], 0, 0, 0);
            acc[m][n] = __builtin_amdgcn_mfma_f32_16x16x32_bf16(b.h[n], al, acc[m][n], 0, 0, 0);
            acc[m][n] = __builtin_amdgcn_mfma_f32_16x16x32_bf16(b.l[n], ah, acc[m][n], 0, 0, 0);
        }
    }
    __builtin_amdgcn_s_setprio(0);
}
__device__ __forceinline__ void mfma_cluster512(
    const char* AH, const char* AL, int k0, int l15, int khalf,
    const BF8x4& b, f32x4 acc[2][4])
{
    __builtin_amdgcn_s_setprio(1);
    #pragma unroll
    for (int m = 0; m < 2; ++m) {
        int row = m * 16 + l15;
        int off = (row * 512 + (k0 + khalf) * 2) ^ ((row & 7) << 4);
        bf16x8 ah = *reinterpret_cast<const bf16x8*>(AH + off);
        bf16x8 al = *reinterpret_cast<const bf16x8*>(AL + off);
        #pragma unroll
        for (int n = 0; n < 4; ++n) {
            acc[m][n] = __builtin_amdgcn_mfma_f32_16x16x32_bf16(b.h[n], ah, acc[m][n], 0, 0, 0);
            acc[m][n] = __builtin_amdgcn_mfma_f32_16x16x32_bf16(b.h[n], al, acc[m][n], 0, 0, 0);
            acc[m][n] = __builtin_amdgcn_mfma_f32_16x16x32_bf16(b.l[n], ah, acc[m][n], 0, 0, 0);
        }
    }
    __builtin_amdgcn_s_setprio(0);
}

__device__ __forceinline__ void mm128_pipe(
    const char* AH, const char* AL,
    const u16* __restrict__ Bh, const u16* __restrict__ Bl, BF8x4& pre,
    const u16* __restrict__ nBh, const u16* __restrict__ nBl,
    int wm, int wn, int l15, int khalf, f32x4 acc[2][4])
{
    BF8x4 c0 = pre;
    BF8x4 c1 = loadB128f(Bh, Bl, 32, wn, l15, khalf);
    mfma_cluster(AH, AL, 0, wm, l15, khalf, c0, acc);
    BF8x4 c2 = loadB128f(Bh, Bl, 64, wn, l15, khalf);
    mfma_cluster(AH, AL, 32, wm, l15, khalf, c1, acc);
    BF8x4 c3 = loadB128f(Bh, Bl, 96, wn, l15, khalf);
    mfma_cluster(AH, AL, 64, wm, l15, khalf, c2, acc);
    if (nBh) pre = loadB128f(nBh, nBl, 0, wn, l15, khalf);
    mfma_cluster(AH, AL, 96, wm, l15, khalf, c3, acc);
}
__device__ __forceinline__ void mm64_pipe(
    const char* AH, const char* AL,
    const u16* __restrict__ Bh, const u16* __restrict__ Bl, BF8x4& pre,
    const u16* __restrict__ nBh, const u16* __restrict__ nBl,
    int wm, int wn, int l15, int khalf, f32x4 acc[2][4])
{
    BF8x4 c0 = pre;
    BF8x4 c1 = loadB64f(Bh, Bl, 32, wn, l15, khalf);
    mfma_cluster64(AH, AL, 0, wm, l15, khalf, c0, acc);
    if (nBh) pre = loadB128f(nBh, nBl, 0, wn, l15, khalf);
    mfma_cluster64(AH, AL, 32, wm, l15, khalf, c1, acc);
}

// ---------------------------------------------------------------------------
// Weight prep
// ---------------------------------------------------------------------------
__global__ __launch_bounds__(256) void wprep(
    const float* __restrict__ src, u16* __restrict__ hi,
    u16* __restrict__ lo, int K, int N)
{
    int e = blockIdx.x * 256 + threadIdx.x;
    int total = K * N;
    if (e >= total) return;
    size_t base = (size_t)blockIdx.y * total;
    float a = src[base + e];
    int k = e / N, n = e - k * N;
    u16 h = f2bf(a);
    u16 l = f2bf(a - bf2f(h));
    hi[base + (size_t)n * K + k] = h;
    lo[base + (size_t)n * K + k] = l;
}

// ---------------------------------------------------------------------------
// pre_fuse (256 threads, 4 waves, wave tile 32x64), rbf8 inlined
// ---------------------------------------------------------------------------
__global__ __launch_bounds__(256, 2) void pre_fuse(
    const float* __restrict__ X, const float* __restrict__ rbf,
    const float* __restrict__ W1,
    const u16* __restrict__ Wjih, const u16* __restrict__ Wjil, const float* __restrict__ bji,
    const u16* __restrict__ Wkjh, const u16* __restrict__ Wkjl, const float* __restrict__ bkj,
    const float* __restrict__ Wr2,
    const u16* __restrict__ Wdnh, const u16* __restrict__ Wdnl,
    float* __restrict__ E1, float* __restrict__ C1)
{
    __shared__ u16 XH[64 * 128], XL[64 * 128];
    __shared__ u16 IH[64 * 128], IL[64 * 128];

    const int tid  = threadIdx.x;
    const int lane = tid & 63;
    const int w    = tid >> 6;
    const int wm   = w >> 1, wn = w & 1;
    const int bm   = blockIdx.x * 64;
    const int l15  = lane & 15;
    const int khalf = (lane >> 4) * 8;
    const int r4   = (lane >> 4) * 4;

    BF8x4 pre = loadB128f(Wjih, Wjil, 0, wn, l15, khalf);

    // stage X [64][128]
    {
        int r  = tid >> 2;
        int c0 = (tid & 3) * 32;
        const float* p = &X[(size_t)(bm + r) * H_DIM + c0];
        const int swz = (r & 7) << 4;
        #pragma unroll
        for (int q = 0; q < 8; ++q) {
            float4 f = *reinterpret_cast<const float4*>(p + q * 4);
            float vv[4] = {f.x, f.y, f.z, f.w};
            u16 h[4], l[4];
            #pragma unroll
            for (int j = 0; j < 4; ++j) {
                h[j] = f2bf(vv[j]);
                l[j] = f2bf(vv[j] - bf2f(h[j]));
            }
            int off = (r * 256 + c0 * 2 + q * 8) ^ swz;
            *reinterpret_cast<ushort4*>((char*)XH + off) = make_ushort4(h[0], h[1], h[2], h[3]);
            *reinterpret_cast<ushort4*>((char*)XL + off) = make_ushort4(l[0], l[1], l[2], l[3]);
        }
    }
    __syncthreads();

    // JI -> E1  (prefetches KJ k0=0 into pre)
    {
        f32x4 acc[2][4] = {};
        mm128_pipe((char*)XH, (char*)XL, Wjih, Wjil, pre, Wkjh, Wkjl,
                   wm, wn, l15, khalf, acc);
        #pragma unroll
        for (int n = 0; n < 4; ++n) {
            int col0 = wn * 64 + n * 16 + r4;
            float4 bv = *reinterpret_cast<const float4*>(&bji[col0]);
            #pragma unroll
            for (int m = 0; m < 2; ++m) {
                int row = wm * 32 + m * 16 + l15;
                float4 o;
                o.x = silu_f(acc[m][n][0] + bv.x);
                o.y = silu_f(acc[m][n][1] + bv.y);
                o.z = silu_f(acc[m][n][2] + bv.z);
                o.w = silu_f(acc[m][n][3] + bv.w);
                *reinterpret_cast<float4*>(&E1[(size_t)(bm + row) * H_DIM + col0]) = o;
            }
        }
    }
    // KJ * gate -> I (LDS), rbf8 computed inline (identical fma order)
    {
        f32x4 acc[2][4] = {};
        mm128_pipe((char*)XH, (char*)XL, Wkjh, Wkjl, pre, nullptr, nullptr,
                   wm, wn, l15, khalf, acc);
        float r8v[2][8];
        #pragma unroll
        for (int m = 0; m < 2; ++m) {
            int grow = bm + wm * 32 + m * 16 + l15;
            const float2* rp = reinterpret_cast<const float2*>(&rbf[(size_t)grow * NRAD]);
            float2 q0 = rp[0], q1 = rp[1], q2 = rp[2];
            float rv[NRAD] = {q0.x, q0.y, q1.x, q1.y, q2.x, q2.y};
            #pragma unroll
            for (int j = 0; j < 8; ++j) r8v[m][j] = 0.f;
            #pragma unroll
            for (int k = 0; k < NRAD; ++k)
                #pragma unroll
                for (int j = 0; j < 8; ++j)
                    r8v[m][j] = fmaf(rv[k], W1[k * BAS + j], r8v[m][j]);
        }
        #pragma unroll
        for (int n = 0; n < 4; ++n) {
            int col0 = wn * 64 + n * 16 + r4;
            float4 bvf = *reinterpret_cast<const float4*>(&bkj[col0]);
            float bv[4] = {bvf.x, bvf.y, bvf.z, bvf.w};
            float wrv[8][4];
            #pragma unroll
            for (int j = 0; j < 8; ++j) {
                float4 wf = *reinterpret_cast<const float4*>(&Wr2[j * H_DIM + col0]);
                wrv[j][0] = wf.x; wrv[j][1] = wf.y; wrv[j][2] = wf.z; wrv[j][3] = wf.w;
            }
            #pragma unroll
            for (int m = 0; m < 2; ++m) {
                int row = wm * 32 + m * 16 + l15;
                float v[4];
                #pragma unroll
                for (int r = 0; r < 4; ++r) {
                    float t = silu_f(acc[m][n][r] + bv[r]);
                    float g = 0.f;
                    #pragma unroll
                    for (int j = 0; j < 8; ++j)
                        g = fmaf(r8v[m][j], wrv[j][r], g);
                    v[r] = t * g;
                }
                st_split4((char*)IH, (char*)IL, row, col0, 256, v);
            }
        }
    }
    __syncthreads();

    // DOWN (N=64) -> C1
    {
        f32x4 acc[2][2] = {};
        #pragma unroll
        for (int k0 = 0; k0 < 128; k0 += 32) {
            bf16x8 bh[2], bl[2];
            #pragma unroll
            for (int n = 0; n < 2; ++n) {
                size_t bo = (size_t)(wn * 32 + n * 16 + l15) * 128 + k0 + khalf;
                bh[n] = *reinterpret_cast<const bf16x8*>(Wdnh + bo);
                bl[n] = *reinterpret_cast<const bf16x8*>(Wdnl + bo);
            }
            __builtin_amdgcn_s_setprio(1);
            #pragma unroll
            for (int m = 0; m < 2; ++m) {
                int row = wm * 32 + m * 16 + l15;
                int off = (row * 256 + (k0 + khalf) * 2) ^ ((row & 7) << 4);
                bf16x8 ah = *reinterpret_cast<const bf16x8*>((const char*)IH + off);
                bf16x8 al = *reinterpret_cast<const bf16x8*>((const char*)IL + off);
                #pragma unroll
                for (int n = 0; n < 2; ++n) {
                    acc[m][n] = __builtin_amdgcn_mfma_f32_16x16x32_bf16(bh[n], ah, acc[m][n], 0, 0, 0);
                    acc[m][n] = __builtin_amdgcn_mfma_f32_16x16x32_bf16(bh[n], al, acc[m][n], 0, 0, 0);
                    acc[m][n] = __builtin_amdgcn_mfma_f32_16x16x32_bf16(bl[n], ah, acc[m][n], 0, 0, 0);
                }
            }
            __builtin_amdgcn_s_setprio(0);
        }
        #pragma unroll
        for (int n = 0; n < 2; ++n) {
            int col0 = wn * 32 + n * 16 + r4;
            #pragma unroll
            for (int m = 0; m < 2; ++m) {
                int row = wm * 32 + m * 16 + l15;
                float4 o;
                o.x = silu_f(acc[m][n][0]);
                o.y = silu_f(acc[m][n][1]);
                o.z = silu_f(acc[m][n][2]);
                o.w = silu_f(acc[m][n][3]);
                *reinterpret_cast<float4*>(&C1[(size_t)(bm + row) * INT_DIM + col0]) = o;
            }
        }
    }
}

// ---------------------------------------------------------------------------
// post_chain body (smem-carved) + out_chain body, fused kernel
// ---------------------------------------------------------------------------
struct ChainP {
    const u16 *uph, *upl;
    const u16 *b0h, *b0l, *b1h, *b1l;
    const u16 *lnh, *lnl;
    const u16 *a0h, *a0l, *a1h, *a1l, *a2h, *a2l, *a3h, *a3l;
    const float *bb0, *bb1, *blin, *ba0, *ba1, *ba2, *ba3;
};
struct OutP {
    const float* TN;
    const u16 *Uh, *Ul; const float* bu;
    const u16 *L0h, *L0l; const float* b0;
    const u16 *L1h, *L1l; const float* b1;
    const u16 *L2h, *L2l; const float* b2;
    const float* Wo; float* P;
};

__device__ __forceinline__ void post_chain_body(
    char* smem, int bx,
    const float* __restrict__ AGG, const float* __restrict__ E1,
    const float* __restrict__ X, const ChainP& p, float* __restrict__ OUT)
{
    char* GH  = smem;
    char* GL  = smem + 8192;
    char* P0H = smem + 16384;
    char* P0L = smem + 32768;
    char* P1H = smem + 49152;
    char* P1L = smem + 65536;

    const int tid  = threadIdx.x;
    const int lane = tid & 63;
    const int w    = tid >> 6;
    const int wm   = w >> 1, wn = w & 1;
    const int bm   = bx * 64;
    const int l15  = lane & 15;
    const int khalf = (lane >> 4) * 8;
    const int r4   = (lane >> 4) * 4;

    BF8x4 pre = loadB64f(p.uph, p.upl, 0, wn, l15, khalf);

    // stage AGG [64][64]
    {
        int r  = tid >> 2;
        int c0 = (tid & 3) * 16;
        const float* pg = &AGG[(size_t)(bm + r) * INT_DIM + c0];
        const int swz = (r & 7) << 4;
        #pragma unroll
        for (int q = 0; q < 4; ++q) {
            float4 f = *reinterpret_cast<const float4*>(pg + q * 4);
            float vv[4] = {f.x, f.y, f.z, f.w};
            u16 h[4], l[4];
            #pragma unroll
            for (int j = 0; j < 4; ++j) {
                h[j] = f2bf(vv[j]);
                l[j] = f2bf(vv[j] - bf2f(h[j]));
            }
            int off = (r * 128 + c0 * 2 + q * 8) ^ swz;
            *reinterpret_cast<ushort4*>(GH + off) = make_ushort4(h[0], h[1], h[2], h[3]);
            *reinterpret_cast<ushort4*>(GL + off) = make_ushort4(l[0], l[1], l[2], l[3]);
        }
    }
    __syncthreads();

    f32x4 acc[2][4];

    // S1: UP (K=64), h0 = E1 + silu -> P0 ; prefetch Wb0
    #pragma unroll
    for (int m = 0; m < 2; ++m)
        #pragma unroll
        for (int n = 0; n < 4; ++n) acc[m][n] = f32x4{0.f, 0.f, 0.f, 0.f};
    mm64_pipe(GH, GL, p.uph, p.upl, pre, p.b0h, p.b0l, wm, wn, l15, khalf, acc);
    #pragma unroll
    for (int n = 0; n < 4; ++n) {
        int col0 = wn * 64 + n * 16 + r4;
        #pragma unroll
        for (int m = 0; m < 2; ++m) {
            int row = wm * 32 + m * 16 + l15;
            float4 e = *reinterpret_cast<const float4*>(&E1[(size_t)(bm + row) * H_DIM + col0]);
            float v[4];
            v[0] = e.x + silu_f(acc[m][n][0]);
            v[1] = e.y + silu_f(acc[m][n][1]);
            v[2] = e.z + silu_f(acc[m][n][2]);
            v[3] = e.w + silu_f(acc[m][n][3]);
            st_split4(P0H, P0L, row, col0, 256, v);
        }
    }
    __syncthreads();

    #define STAGE_PLAIN(SRC_H, SRC_L, WH, WL, BIAS, DST_H, DST_L, NWH, NWL)             \
    {                                                                                   \
        _Pragma("unroll")                                                               \
        for (int m = 0; m < 2; ++m)                                                     \
            _Pragma("unroll")                                                           \
            for (int n = 0; n < 4; ++n) acc[m][n] = f32x4{0.f, 0.f, 0.f, 0.f};          \
        mm128_pipe(SRC_H, SRC_L, WH, WL, pre, NWH, NWL, wm, wn, l15, khalf, acc);       \
        _Pragma("unroll")                                                               \
        for (int n = 0; n < 4; ++n) {                                                   \
            int col0 = wn * 64 + n * 16 + r4;                                           \
            float4 bv = *reinterpret_cast<const float4*>(&BIAS[col0]);                  \
            _Pragma("unroll")                                                           \
            for (int m = 0; m < 2; ++m) {                                               \
                int row = wm * 32 + m * 16 + l15;                                       \
                float v[4];                                                             \
                v[0] = silu_f(acc[m][n][0] + bv.x);                                     \
                v[1] = silu_f(acc[m][n][1] + bv.y);                                     \
                v[2] = silu_f(acc[m][n][2] + bv.z);                                     \
                v[3] = silu_f(acc[m][n][3] + bv.w);                                     \
                st_split4(DST_H, DST_L, row, col0, 256, v);                             \
            }                                                                           \
        }                                                                               \
        __syncthreads();                                                                \
    }

    #define STAGE_RES(SRC_H, SRC_L, WH, WL, BIAS, RES_H, RES_L, NWH, NWL)               \
    {                                                                                   \
        _Pragma("unroll")                                                               \
        for (int m = 0; m < 2; ++m)                                                     \
            _Pragma("unroll")                                                           \
            for (int n = 0; n < 4; ++n) acc[m][n] = f32x4{0.f, 0.f, 0.f, 0.f};          \
        mm128_pipe(SRC_H, SRC_L, WH, WL, pre, NWH, NWL, wm, wn, l15, khalf, acc);       \
        _Pragma("unroll")                                                               \
        for (int n = 0; n < 4; ++n) {                                                   \
            int col0 = wn * 64 + n * 16 + r4;                                           \
            float4 bv = *reinterpret_cast<const float4*>(&BIAS[col0]);                  \
            _Pragma("unroll")                                                           \
            for (int m = 0; m < 2; ++m) {                                               \
                int row = wm * 32 + m * 16 + l15;                                       \
                float v[4];                                                             \
                ld_split4(RES_H, RES_L, row, col0, 256, v);                             \
                v[0] += silu_f(acc[m][n][0] + bv.x);                                    \
                v[1] += silu_f(acc[m][n][1] + bv.y);                                    \
                v[2] += silu_f(acc[m][n][2] + bv.z);                                    \
                v[3] += silu_f(acc[m][n][3] + bv.w);                                    \
                st_split4(RES_H, RES_L, row, col0, 256, v);                             \
            }                                                                           \
        }                                                                               \
        __syncthreads();                                                                \
    }

    STAGE_PLAIN(P0H, P0L, p.b0h, p.b0l, p.bb0, P1H, P1L, p.b1h, p.b1l)
    STAGE_RES(P1H, P1L, p.b1h, p.b1l, p.bb1, P0H, P0L, p.lnh, p.lnl)

    // S4: x1 = silu(P0@Wlin+blin) + X -> P1 ; prefetch Wa0
    {
        #pragma unroll
        for (int m = 0; m < 2; ++m)
            #pragma unroll
            for (int n = 0; n < 4; ++n) acc[m][n] = f32x4{0.f, 0.f, 0.f, 0.f};
        mm128_pipe(P0H, P0L, p.lnh, p.lnl, pre, p.a0h, p.a0l, wm, wn, l15, khalf, acc);
        #pragma unroll
        for (int n = 0; n < 4; ++n) {
            int col0 = wn * 64 + n * 16 + r4;
            float4 bv = *reinterpret_cast<const float4*>(&p.blin[col0]);
            #pragma unroll
            for (int m = 0; m < 2; ++m) {
                int row = wm * 32 + m * 16 + l15;
                float4 xv = *reinterpret_cast<const float4*>(&X[(size_t)(bm + row) * H_DIM + col0]);
                float v[4];
                v[0] = silu_f(acc[m][n][0] + bv.x) + xv.x;
                v[1] = silu_f(acc[m][n][1] + bv.y) + xv.y;
                v[2] = silu_f(acc[m][n][2] + bv.z) + xv.z;
                v[3] = silu_f(acc[m][n][3] + bv.w) + xv.w;
                st_split4(P1H, P1L, row, col0, 256, v);
            }
        }
        __syncthreads();
    }

    STAGE_PLAIN(P1H, P1L, p.a0h, p.a0l, p.ba0, P0H, P0L, p.a1h, p.a1l)
    STAGE_RES(P0H, P0L, p.a1h, p.a1l, p.ba1, P1H, P1L, p.a2h, p.a2l)
    STAGE_PLAIN(P1H, P1L, p.a2h, p.a2l, p.ba2, P0H, P0L, p.a3h, p.a3l)

    // S8: OUT = P1 + silu(P0@Wa3+ba3)
    {
        #pragma unroll
        for (int m = 0; m < 2; ++m)
            #pragma unroll
            for (int n = 0; n < 4; ++n) acc[m][n] = f32x4{0.f, 0.f, 0.f, 0.f};
        mm128_pipe(P0H, P0L, p.a3h, p.a3l, pre, nullptr, nullptr, wm, wn, l15, khalf, acc);
        #pragma unroll
        for (int n = 0; n < 4; ++n) {
            int col0 = wn * 64 + n * 16 + r4;
            float4 bv = *reinterpret_cast<const float4*>(&p.ba3[col0]);
            #pragma unroll
            for (int m = 0; m < 2; ++m) {
                int row = wm * 32 + m * 16 + l15;
                float v[4];
                ld_split4(P1H, P1L, row, col0, 256, v);
                float4 o;
                o.x = v[0] + silu_f(acc[m][n][0] + bv.x);
                o.y = v[1] + silu_f(acc[m][n][1] + bv.y);
                o.z = v[2] + silu_f(acc[m][n][2] + bv.z);
                o.w = v[3] + silu_f(acc[m][n][3] + bv.w);
                *reinterpret_cast<float4*>(&OUT[(size_t)(bm + row) * H_DIM + col0]) = o;
            }
        }
    }
    #undef STAGE_PLAIN
    #undef STAGE_RES
}

__device__ __forceinline__ void out_chain_body(char* smem, int bx, const OutP& o)
{
    char* XH  = smem;
    char* XL  = smem + 8192;
    char* T0H = smem + 16384;
    char* T0L = smem + 32768;
    char* T1H = smem + 49152;
    char* T1L = smem + 65536;

    const int tid  = threadIdx.x;
    const int lane = tid & 63;
    const int wn   = tid >> 6;
    const int bm   = bx * 32;
    const int l15  = lane & 15;
    const int khalf = (lane >> 4) * 8;
    const int r4   = (lane >> 4) * 4;

    // stage TN tile [32][128]
    {
        int r  = tid >> 3;
        int c0 = (tid & 7) * 16;
        const float* p = &o.TN[(size_t)(bm + r) * H_DIM + c0];
        const int swz = (r & 7) << 4;
        #pragma unroll
        for (int q = 0; q < 4; ++q) {
            float4 f = *reinterpret_cast<const float4*>(p + q * 4);
            float vv[4] = {f.x, f.y, f.z, f.w};
            u16 h[4], l[4];
            #pragma unroll
            for (int j = 0; j < 4; ++j) {
                h[j] = f2bf(vv[j]);
                l[j] = f2bf(vv[j] - bf2f(h[j]));
            }
            int off = (r * 256 + c0 * 2 + q * 8) ^ swz;
            *reinterpret_cast<ushort4*>(XH + off) = make_ushort4(h[0], h[1], h[2], h[3]);
            *reinterpret_cast<ushort4*>(XL + off) = make_ushort4(l[0], l[1], l[2], l[3]);
        }
    }
    __syncthreads();

    f32x4 acc[2][4];

    // up: K=128, bias only -> T0
    {
        #pragma unroll
        for (int m = 0; m < 2; ++m)
            #pragma unroll
            for (int n = 0; n < 4; ++n) acc[m][n] = f32x4{0.f, 0.f, 0.f, 0.f};
        BF8x4 cur = loadB128f(o.Uh, o.Ul, 0, wn, l15, khalf);
        #pragma unroll
        for (int k = 0; k < 4; ++k) {
            BF8x4 nxt;
            if (k < 3) nxt = loadB128f(o.Uh, o.Ul, 32 * (k + 1), wn, l15, khalf);
            mfma_cluster(XH, XL, 32 * k, 0, l15, khalf, cur, acc);
            if (k < 3) cur = nxt;
        }
        #pragma unroll
        for (int n = 0; n < 4; ++n) {
            int col0 = wn * 64 + n * 16 + r4;
            float4 bv = *reinterpret_cast<const float4*>(&o.bu[col0]);
            #pragma unroll
            for (int m = 0; m < 2; ++m) {
                int row = m * 16 + l15;
                float v[4] = {acc[m][n][0] + bv.x, acc[m][n][1] + bv.y,
                              acc[m][n][2] + bv.z, acc[m][n][3] + bv.w};
                st_split4(T0H, T0L, row, col0, 512, v);
            }
        }
        __syncthreads();
    }

    #define OLIN(SRC_H, SRC_L, WH, WL, BIAS, DST_H, DST_L)                              \
    {                                                                                   \
        _Pragma("unroll")                                                               \
        for (int m = 0; m < 2; ++m)                                                     \
            _Pragma("unroll")                                                           \
            for (int n = 0; n < 4; ++n) acc[m][n] = f32x4{0.f, 0.f, 0.f, 0.f};          \
        BF8x4 cur = loadB256f(WH, WL, 0, wn, l15, khalf);                               \
        _Pragma("unroll")                                                               \
        for (int k = 0; k < 8; ++k) {                                                   \
            BF8x4 nxt;                                                                  \
            if (k < 7) nxt = loadB256f(WH, WL, 32 * (k + 1), wn, l15, khalf);           \
            mfma_cluster512(SRC_H, SRC_L, 32 * k, l15, khalf, cur, acc);                \
            if (k < 7) cur = nxt;                                                       \
        }                                                                               \
        _Pragma("unroll")                                                               \
        for (int n = 0; n < 4; ++n) {                                                   \
            int col0 = wn * 64 + n * 16 + r4;                                           \
            float4 bv = *reinterpret_cast<const float4*>(&BIAS[col0]);                  \
            _Pragma("unroll")                                                           \
            for (int m = 0; m < 2; ++m) {                                               \
                int row = m * 16 + l15;                                                 \
                float v[4];                                                             \
                v[0] = silu_f(acc[m][n][0] + bv.x);                                     \
                v[1] = silu_f(acc[m][n][1] + bv.y);                                     \
                v[2] = silu_f(acc[m][n][2] + bv.z);                                     \
                v[3] = silu_f(acc[m][n][3] + bv.w);                                     \
                st_split4(DST_H, DST_L, row, col0, 512, v);                             \
            }                                                                           \
        }                                                                               \
        __syncthreads();                                                                \
    }

    OLIN(T0H, T0L, o.L0h, o.L0l, o.b0, T1H, T1L)
    OLIN(T1H, T1L, o.L1h, o.L1l, o.b1, T0H, T0L)
    OLIN(T0H, T0L, o.L2h, o.L2l, o.b2, T1H, T1L)
    #undef OLIN

    // final: P[bm+row] += dot(T1[row][:256], Wo[:256]); 8 threads per row
    {
        int row  = tid >> 3;
        int part = tid & 7;
        float s = 0.f;
        int cbase = part * 32;
        #pragma unroll
        for (int c4 = 0; c4 < 32; c4 += 4) {
            float v[4];
            ld_split4(T1H, T1L, row, cbase + c4, 512, v);
            float4 wv = *reinterpret_cast<const float4*>(&o.Wo[cbase + c4]);
            s = fmaf(v[0], wv.x, s);
            s = fmaf(v[1], wv.y, s);
            s = fmaf(v[2], wv.z, s);
            s = fmaf(v[3], wv.w, s);
        }
        s += __shfl_xor(s, 1);
        s += __shfl_xor(s, 2);
        s += __shfl_xor(s, 4);
        if (part == 0) o.P[bm + row] += s;
    }
}

__global__ __launch_bounds__(256, 2) void post_fused(
    int npost,
    const float* __restrict__ AGG, const float* __restrict__ E1,
    const float* __restrict__ X, ChainP p, float* __restrict__ OUT, OutP o)
{
    __shared__ char smem[81920];
    if ((int)blockIdx.x < npost)
        post_chain_body(smem, blockIdx.x, AGG, E1, X, p, OUT);
    else
        out_chain_body(smem, blockIdx.x - npost, o);
}

// ---------------------------------------------------------------------------
// Fused gather: blocks < GT do triplet aggregation, rest do out_gather.
// ---------------------------------------------------------------------------
__device__ __forceinline__ float dot8_bf(uint4 r, const float* w2) {
    float s;
    s  = bf2f((u16)(r.x)) * w2[0] + bf2f((u16)(r.x >> 16)) * w2[1];
    s += bf2f((u16)(r.y)) * w2[2] + bf2f((u16)(r.y >> 16)) * w2[3];
    s += bf2f((u16)(r.z)) * w2[4] + bf2f((u16)(r.z >> 16)) * w2[5];
    s += bf2f((u16)(r.w)) * w2[6] + bf2f((u16)(r.w >> 16)) * w2[7];
    return s;
}

__device__ __forceinline__ void triplet_body(
    int bx, int nblk,
    const u16* __restrict__ ps8b, const float* __restrict__ Wsb2,
    const float* __restrict__ xkj, const int* __restrict__ pkj,
    const int* __restrict__ tptr, const int* __restrict__ tcnt,
    float* __restrict__ agg)
{
    const int lane = threadIdx.x & 63;
    int wid = bx * 4 + (threadIdx.x >> 6);
    const int nw = nblk * 4;
    float w2[BAS];
    #pragma unroll
    for (int j = 0; j < BAS; ++j) w2[j] = Wsb2[j * INT_DIM + lane];

    for (int e = wid; e < E_EDGES; e += nw) {
        int start = tptr[e];
        int end   = start + tcnt[e];
        float acc0 = 0.f, acc1 = 0.f;
        int i = start;
        for (; i + 1 < end; i += 2) {
            uint4 ra = *reinterpret_cast<const uint4*>(&ps8b[(size_t)i * BAS]);
            uint4 rb = *reinterpret_cast<const uint4*>(&ps8b[(size_t)(i + 1) * BAS]);
            int e0 = pkj[i], e1 = pkj[i + 1];
            float s0 = dot8_bf(ra, w2);
            float s1 = dot8_bf(rb, w2);
            acc0 = fmaf(xkj[(size_t)e0 * INT_DIM + lane], s0, acc0);
            acc1 = fmaf(xkj[(size_t)e1 * INT_DIM + lane], s1, acc1);
        }
        if (i < end) {
            uint4 ra = *reinterpret_cast<const uint4*>(&ps8b[(size_t)i * BAS]);
            int e0 = pkj[i];
            acc0 = fmaf(xkj[(size_t)e0 * INT_DIM + lane], dot8_bf(ra, w2), acc0);
        }
        agg[(size_t)e * INT_DIM + lane] = acc0 + acc1;
    }
}

__device__ __forceinline__ void out_gather_body(
    int bx, int nblk,
    const float* __restrict__ rbf, const float* __restrict__ Wor,
    const float* __restrict__ x,
    const int* __restrict__ eptr, const int* __restrict__ ecnt,
    const int* __restrict__ eperm, float* __restrict__ tN)
{
    const int lane = threadIdx.x & 63;
    int wid = bx * 4 + (threadIdx.x >> 6);
    const int nw = nblk * 4;
    float wr0[NRAD], wr1[NRAD];
    #pragma unroll
    for (int k = 0; k < NRAD; ++k) {
        wr0[k] = Wor[k * H_DIM + lane];
        wr1[k] = Wor[k * H_DIM + lane + 64];
    }
    for (int n = wid; n < N_NODES; n += nw) {
        int start = eptr[n];
        int end   = start + ecnt[n];
        float a0 = 0.f, a1 = 0.f;
        for (int i = start; i < end; ++i) {
            int e = eperm[i];
            const float2* rp = reinterpret_cast<const float2*>(&rbf[(size_t)e * NRAD]);
            float2 r0 = rp[0], r1 = rp[1], r2 = rp[2];
            float rA = r0.x*wr0[0] + r0.y*wr0[1] + r1.x*wr0[2]
                     + r1.y*wr0[3] + r2.x*wr0[4] + r2.y*wr0[5];
            float rB = r0.x*wr1[0] + r0.y*wr1[1] + r1.x*wr1[2]
                     + r1.y*wr1[3] + r2.x*wr1[4] + r2.y*wr1[5];
            a0 = fmaf(rA, x[(size_t)e * H_DIM + lane], a0);
            a1 = fmaf(rB, x[(size_t)e * H_DIM + lane + 64], a1);
        }
        tN[(size_t)n * H_DIM + lane] = a0;
        tN[(size_t)n * H_DIM + lane + 64] = a1;
    }
}

__global__ __launch_bounds__(256) void gather_fused(
    int GT,
    const u16* __restrict__ ps8b, const float* __restrict__ Wsb2,
    const float* __restrict__ xkj, const int* __restrict__ pkj,
    const int* __restrict__ tptr, const int* __restrict__ tcnt,
    float* __restrict__ agg,
    const float* __restrict__ rbf, const float* __restrict__ Wor,
    const float* __restrict__ x,
    const int* __restrict__ eptr, const int* __restrict__ ecnt,
    const int* __restrict__ eperm, float* __restrict__ tN)
{
    int bx = blockIdx.x;
    if (bx < GT)
        triplet_body(bx, GT, ps8b, Wsb2, xkj, pkj, tptr, tcnt, agg);
    else
        out_gather_body(bx - GT, gridDim.x - GT, rbf, Wor, x, eptr, ecnt, eperm, tN);
}

// ---------------------------------------------------------------------------
// CSR build kernels
// ---------------------------------------------------------------------------
__global__ __launch_bounds__(256) void csr_count(
    const int* __restrict__ idx, int* __restrict__ cnt, int n)
{
    int i = blockIdx.x * 256 + threadIdx.x;
    if (i < n) atomicAdd(&cnt[idx[i]], 1);
}

__global__ __launch_bounds__(256) void scan_block(
    const int* __restrict__ cnt, int* __restrict__ ptr, int* __restrict__ bsum, int n)
{
    __shared__ int s[256];
    int i = blockIdx.x * 256 + threadIdx.x;
    int v = (i < n) ? cnt[i] : 0;
    s[threadIdx.x] = v;
    __syncthreads();
    #pragma unroll
    for (int off = 1; off < 256; off <<= 1) {
        int t = (threadIdx.x >= off) ? s[threadIdx.x - off] : 0;
        __syncthreads();
        s[threadIdx.x] += t;
        __syncthreads();
    }
    if (i < n) ptr[i] = s[threadIdx.x] - v;   // exclusive
    if (threadIdx.x == 255) bsum[blockIdx.x] = s[255];
}

__global__ __launch_bounds__(1024) void scan_aux(int* __restrict__ bsum, int nb)
{
    __shared__ int s[1024];
    int v = (threadIdx.x < nb) ? bsum[threadIdx.x] : 0;
    s[threadIdx.x] = v;
    __syncthreads();
    #pragma unroll
    for (int off = 1; off < 1024; off <<= 1) {
        int t = (threadIdx.x >= off) ? s[threadIdx.x - off] : 0;
        __syncthreads();
        s[threadIdx.x] += t;
        __syncthreads();
    }
    if (threadIdx.x < nb) bsum[threadIdx.x] = s[threadIdx.x] - v;
}

__global__ __launch_bounds__(256) void scan_add(
    int* __restrict__ ptr, const int* __restrict__ bsum, int n)
{
    int i = blockIdx.x * 256 + threadIdx.x;
    if (i < n) ptr[i] += bsum[blockIdx.x];
}

__global__ __launch_bounds__(256) void csr_fill(
    const int* __restrict__ idx, int* __restrict__ cursor,
    int* __restrict__ perm, int n)
{
    int i = blockIdx.x * 256 + threadIdx.x;
    if (i >= n) return;
    int pos = atomicAdd(&cursor[idx[i]], 1);
    perm[pos] = i;
}

// ---------------------------------------------------------------------------
// One-time: permuted sbf basis for ALL blocks + permuted idx_kj.
// ---------------------------------------------------------------------------
__global__ __launch_bounds__(256) void permute_s8(
    const float* __restrict__ sbf, const float* __restrict__ W1all,
    const int* __restrict__ idx_kj, const int* __restrict__ tperm,
    u16* __restrict__ ps8, int* __restrict__ pkj, int Tcount)
{
    __shared__ float Ws[NB * SBF_D * BAS];
    for (int i = threadIdx.x; i < NB * SBF_D * BAS; i += 256) Ws[i] = W1all[i];
    __syncthreads();
    int i = blockIdx.x * 256 + threadIdx.x;
    if (i >= Tcount) return;
    int t = tperm[i];
    pkj[i] = idx_kj[t];
    float s[SBF_D];
    {
        const float2* p2 = reinterpret_cast<const float2*>(&sbf[(size_t)t * SBF_D]);
        #pragma unroll
        for (int k = 0; k < SBF_D / 2; ++k) {
            float2 v = p2[k];
            s[2 * k] = v.x; s[2 * k + 1] = v.y;
        }
    }
    #pragma unroll
    for (int b = 0; b < NB; ++b) {
        const float* Wb_ = &Ws[b * SBF_D * BAS];
        float acc[BAS] = {};
        for (int k = 0; k < SBF_D; ++k) {
            float sv = s[k];
            #pragma unroll
            for (int j = 0; j < BAS; ++j)
                acc[j] = fmaf(sv, Wb_[k * BAS + j], acc[j]);
        }
        ushort4 o0 = make_ushort4(f2bf(acc[0]), f2bf(acc[1]), f2bf(acc[2]), f2bf(acc[3]));
        ushort4 o1 = make_ushort4(f2bf(acc[4]), f2bf(acc[5]), f2bf(acc[6]), f2bf(acc[7]));
        u16* op = &ps8[((size_t)b * Tcount + i) * BAS];
        *reinterpret_cast<ushort4*>(op) = o0;
        *reinterpret_cast<ushort4*>(op + 4) = o1;
    }
}

// ---------------------------------------------------------------------------
extern "C" void kernel_launch(void* const* d_in, const int* in_sizes, int n_in,
                              void* d_out, int out_size, void* d_ws, size_t ws_size,
                              hipStream_t stream)
{
    const float* x_in    = (const float*)d_in[0];
    const float* rbf     = (const float*)d_in[1];
    const float* sbf     = (const float*)d_in[2];
    const float* W_rbf1  = (const float*)d_in[3];
    const float* W_rbf2  = (const float*)d_in[4];
    const float* W_sbf1  = (const float*)d_in[5];
    const float* W_sbf2  = (const float*)d_in[6];
    const float* W_kj    = (const float*)d_in[7];
    const float* b_kj    = (const float*)d_in[8];
    const float* W_ji    = (const float*)d_in[9];
    const float* b_ji    = (const float*)d_in[10];
    const float* W_down  = (const float*)d_in[11];
    const float* W_up    = (const float*)d_in[12];
    const float* Wb      = (const float*)d_in[13];
    const float* bb      = (const float*)d_in[14];
    const float* Wa      = (const float*)d_in[15];
    const float* ba      = (const float*)d_in[16];
    const float* W_lin   = (const float*)d_in[17];
    const float* b_lin   = (const float*)d_in[18];
    const float* Wo_rbf  = (const float*)d_in[19];
    const float* Wo_up   = (const float*)d_in[20];
    const float* bo_up   = (const float*)d_in[21];
    const float* Wo_lins = (const float*)d_in[22];
    const float* bo_lins = (const float*)d_in[23];
    const float* Wo_out  = (const float*)d_in[24];
    const int*   idx_kj  = (const int*)d_in[25];
    const int*   idx_ji  = (const int*)d_in[26];
    const int*   idx_i   = (const int*)d_in[27];

    // workspace carve-up
    char* ws = (char*)d_ws;
    size_t off = 0;
    auto alloc = [&](size_t bytes) -> void* {
        void* p = (void*)(ws + off);
        off += (bytes + 255) & ~(size_t)255;
        return p;
    };
    float* XA = (float*)alloc((size_t)E_EDGES * H_DIM * 4);
    float* XB = (float*)alloc((size_t)E_EDGES * H_DIM * 4);
    float* E1 = (float*)alloc((size_t)E_EDGES * H_DIM * 4);
    float* C1 = (float*)alloc((size_t)E_EDGES * INT_DIM * 4);
    float* C2 = (float*)alloc((size_t)E_EDGES * INT_DIM * 4);
    float* TN = (float*)alloc((size_t)N_NODES * H_DIM * 4);
    // split-bf16 transposed weights
    u16* HKJ = (u16*)alloc(4  * 16384 * 2); u16* LKJ = (u16*)alloc(4  * 16384 * 2);
    u16* HJI = (u16*)alloc(4  * 16384 * 2); u16* LJI = (u16*)alloc(4  * 16384 * 2);
    u16* HDN = (u16*)alloc(4  * 8192  * 2); u16* LDN = (u16*)alloc(4  * 8192  * 2);
    u16* HUP = (u16*)alloc(4  * 8192  * 2); u16* LUP = (u16*)alloc(4  * 8192  * 2);
    u16* HWB = (u16*)alloc(8  * 16384 * 2); u16* LWB = (u16*)alloc(8  * 16384 * 2);
    u16* HWA = (u16*)alloc(16 * 16384 * 2); u16* LWA = (u16*)alloc(16 * 16384 * 2);
    u16* HLN = (u16*)alloc(4  * 16384 * 2); u16* LLN = (u16*)alloc(4  * 16384 * 2);
    u16* HOU = (u16*)alloc(5  * 32768 * 2); u16* LOU = (u16*)alloc(5  * 32768 * 2);
    u16* HOL = (u16*)alloc(15 * 65536 * 2); u16* LOL = (u16*)alloc(15 * 65536 * 2);
    // CSR structures
    int* tcnt  = (int*)alloc((size_t)E_EDGES * 4);
    int* tptr  = (int*)alloc((size_t)E_EDGES * 4);
    int* tcur  = (int*)alloc((size_t)E_EDGES * 4);
    int* tperm = (int*)alloc((size_t)T_TRIP * 4);
    int* tbsum = (int*)alloc(1024 * 4);
    int* ecnt  = (int*)alloc((size_t)N_NODES * 4);
    int* eptr  = (int*)alloc((size_t)N_NODES * 4);
    int* ecur  = (int*)alloc((size_t)N_NODES * 4);
    int* eperm = (int*)alloc((size_t)E_EDGES * 4);
    int* ebsum = (int*)alloc(1024 * 4);
    // permuted triplet stream
    u16* PS8 = (u16*)alloc((size_t)NB * T_TRIP * BAS * 2);
    int* PKJ = (int*)alloc((size_t)T_TRIP * 4);
    (void)ws_size;

    auto prep = [&](const float* src, u16* hi, u16* lo, int K, int N, int cnt) {
        dim3 g((K * N + 255) / 256, cnt);
        hipLaunchKernelGGL(wprep, g, dim3(256), 0, stream, src, hi, lo, K, N);
    };
    prep(W_kj,    HKJ, LKJ, 128, 128, 4);
    prep(W_ji,    HJI, LJI, 128, 128, 4);
    prep(W_down,  HDN, LDN, 128, 64,  4);
    prep(W_up,    HUP, LUP, 64,  128, 4);
    prep(Wb,      HWB, LWB, 128, 128, 8);
    prep(Wa,      HWA, LWA, 128, 128, 16);
    prep(W_lin,   HLN, LLN, 128, 128, 4);
    prep(Wo_up,   HOU, LOU, 128, 256, 5);
    prep(Wo_lins, HOL, LOL, 256, 256, 15);

    // ---- build triplet CSR (idx_ji: T entries -> E buckets)
    {
        const int nbT = (E_EDGES + 255) / 256;
        hipMemsetAsync(tcnt, 0, (size_t)E_EDGES * 4, stream);
        hipLaunchKernelGGL(csr_count, dim3((T_TRIP + 255) / 256), dim3(256), 0, stream,
                           idx_ji, tcnt, T_TRIP);
        hipLaunchKernelGGL(scan_block, dim3(nbT), dim3(256), 0, stream, tcnt, tptr, tbsum, E_EDGES);
        hipLaunchKernelGGL(scan_aux, dim3(1), dim3(1024), 0, stream, tbsum, nbT);
        hipLaunchKernelGGL(scan_add, dim3(nbT), dim3(256), 0, stream, tptr, tbsum, E_EDGES);
        hipMemcpyAsync(tcur, tptr, (size_t)E_EDGES * 4, hipMemcpyDeviceToDevice, stream);
        hipLaunchKernelGGL(csr_fill, dim3((T_TRIP + 255) / 256), dim3(256), 0, stream,
                           idx_ji, tcur, tperm, T_TRIP);
    }
    // ---- build node CSR (idx_i: E entries -> N buckets)
    {
        const int nbN = (N_NODES + 255) / 256;
        hipMemsetAsync(ecnt, 0, (size_t)N_NODES * 4, stream);
        hipLaunchKernelGGL(csr_count, dim3((E_EDGES + 255) / 256), dim3(256), 0, stream,
                           idx_i, ecnt, E_EDGES);
        hipLaunchKernelGGL(scan_block, dim3(nbN), dim3(256), 0, stream, ecnt, eptr, ebsum, N_NODES);
        hipLaunchKernelGGL(scan_aux, dim3(1), dim3(1024), 0, stream, ebsum, nbN);
        hipLaunchKernelGGL(scan_add, dim3(nbN), dim3(256), 0, stream, eptr, ebsum, N_NODES);
        hipMemcpyAsync(ecur, eptr, (size_t)N_NODES * 4, hipMemcpyDeviceToDevice, stream);
        hipLaunchKernelGGL(csr_fill, dim3((E_EDGES + 255) / 256), dim3(256), 0, stream,
                           idx_i, ecur, eperm, E_EDGES);
    }
    // ---- one-time permuted sbf basis for all blocks
    hipLaunchKernelGGL(permute_s8, dim3((T_TRIP + 255) / 256), dim3(256), 0, stream,
                       sbf, W_sbf1, idx_kj, tperm, PS8, PKJ, T_TRIP);

    float* P = (float*)d_out;
    hipMemsetAsync(P, 0, (size_t)N_NODES * sizeof(float), stream);

    auto make_outp = [&](int ob) {
        OutP o;
        o.TN = TN;
        o.Uh = HOU + (size_t)ob * 32768; o.Ul = LOU + (size_t)ob * 32768;
        o.bu = bo_up + (size_t)ob * OUT_EMB;
        o.L0h = HOL + (size_t)(ob * 3 + 0) * 65536; o.L0l = LOL + (size_t)(ob * 3 + 0) * 65536;
        o.b0 = bo_lins + (size_t)(ob * 3 + 0) * OUT_EMB;
        o.L1h = HOL + (size_t)(ob * 3 + 1) * 65536; o.L1l = LOL + (size_t)(ob * 3 + 1) * 65536;
        o.b1 = bo_lins + (size_t)(ob * 3 + 1) * OUT_EMB;
        o.L2h = HOL + (size_t)(ob * 3 + 2) * 65536; o.L2l = LOL + (size_t)(ob * 3 + 2) * 65536;
        o.b2 = bo_lins + (size_t)(ob * 3 + 2) * OUT_EMB;
        o.Wo = Wo_out + (size_t)ob * OUT_EMB;
        o.P = P;
        return o;
    };

    const float* xcur = x_in;
    const int EB = E_EDGES / 64;  // 3125
    const int GT = 2048;
    for (int b = 0; b < NB; ++b) {
        float* xnext = (b % 2 == 0) ? XB : XA;
        // 1) pre_fuse (rbf8 inlined)
        hipLaunchKernelGGL(pre_fuse, dim3(EB), dim3(256), 0, stream,
                           xcur, rbf, W_rbf1 + (size_t)b * NRAD * BAS,
                           HJI + (size_t)b * 16384, LJI + (size_t)b * 16384, b_ji + (size_t)b * H_DIM,
                           HKJ + (size_t)b * 16384, LKJ + (size_t)b * 16384, b_kj + (size_t)b * H_DIM,
                           W_rbf2 + (size_t)b * BAS * H_DIM,
                           HDN + (size_t)b * 8192, LDN + (size_t)b * 8192,
                           E1, C1);
        // 2) triplet aggregation || out_gather(ob=b, xcur)
        hipLaunchKernelGGL(gather_fused, dim3(GT + 2048), dim3(256), 0, stream,
                           GT,
                           PS8 + (size_t)b * T_TRIP * BAS, W_sbf2 + (size_t)b * BAS * INT_DIM,
                           C1, PKJ, tptr, tcnt, C2,
                           rbf, Wo_rbf + (size_t)b * NRAD * H_DIM, xcur,
                           eptr, ecnt, eperm, TN);
        // 3) post_chain || out_chain(ob=b)
        ChainP cp;
        cp.uph = HUP + (size_t)b * 8192;  cp.upl = LUP + (size_t)b * 8192;
        cp.b0h = HWB + (size_t)(b * 2 + 0) * 16384; cp.b0l = LWB + (size_t)(b * 2 + 0) * 16384;
        cp.b1h = HWB + (size_t)(b * 2 + 1) * 16384; cp.b1l = LWB + (size_t)(b * 2 + 1) * 16384;
        cp.lnh = HLN + (size_t)b * 16384; cp.lnl = LLN + (size_t)b * 16384;
        cp.a0h = HWA + (size_t)(b * 4 + 0) * 16384; cp.a0l = LWA + (size_t)(b * 4 + 0) * 16384;
        cp.a1h = HWA + (size_t)(b * 4 + 1) * 16384; cp.a1l = LWA + (size_t)(b * 4 + 1) * 16384;
        cp.a2h = HWA + (size_t)(b * 4 + 2) * 16384; cp.a2l = LWA + (size_t)(b * 4 + 2) * 16384;
        cp.a3h = HWA + (size_t)(b * 4 + 3) * 16384; cp.a3l = LWA + (size_t)(b * 4 + 3) * 16384;
        cp.bb0 = bb + (size_t)(b * 2 + 0) * H_DIM;
        cp.bb1 = bb + (size_t)(b * 2 + 1) * H_DIM;
        cp.blin = b_lin + (size_t)b * H_DIM;
        cp.ba0 = ba + (size_t)(b * 4 + 0) * H_DIM;
        cp.ba1 = ba + (size_t)(b * 4 + 1) * H_DIM;
        cp.ba2 = ba + (size_t)(b * 4 + 2) * H_DIM;
        cp.ba3 = ba + (size_t)(b * 4 + 3) * H_DIM;
        OutP op = make_outp(b);
        hipLaunchKernelGGL(post_fused, dim3(EB + N_NODES / 32), dim3(256), 0, stream,
                           EB, C2, E1, xcur, cp, xnext, op);
        xcur = xnext;
    }
    // final output block ob=NB: out_gather(x_NB) then out_chain
    {
        OutP op = make_outp(NB);
        ChainP cp = {};  // unused
        hipLaunchKernelGGL(gather_fused, dim3(2048), dim3(256), 0, stream,
                           0,
                           PS8, W_sbf2, C1, PKJ, tptr, tcnt, C2,
                           rbf, Wo_rbf + (size_t)NB * NRAD * H_DIM, xcur,
                           eptr, ecnt, eperm, TN);
        hipLaunchKernelGGL(post_fused, dim3(N_NODES / 32), dim3(256), 0, stream,
                           0, C2, E1, xcur, cp, (float*)XA, op);
    }
}